// Round 15
// baseline (311.790 us; speedup 1.0000x reference)
//
#include <hip/hip_runtime.h>
#include <hip/hip_bf16.h>
#include <math.h>

// Problem constants
constexpr int B_ = 4;
constexpr int N_ = 20000;
constexpr int E_ = 320000;
constexpr int HEADS_ = 4;
constexpr int NCH = 64;                       // attention chunks per (b,head)
constexpr int CS = (N_ + NCH - 1) / NCH;      // 313
constexpr int NT_ = (B_ * N_) / 16;           // 5000 node tiles
constexpr int NWIN = 1250;                    // 16-dst windows per batch
constexpr int HWIN = 625;                     // windows per XCD half
constexpr int WCAP = 512;                     // bucket capacity (mean 256, +16 sigma)
constexpr int TPAD = 16;                      // tails padding (ints) -> 1 counter/line

typedef __attribute__((ext_vector_type(8))) short short8;   // 8 bf16
typedef __attribute__((ext_vector_type(4))) float f32x4;

// Workspace layout (bytes). ~57 MB.
constexpr size_t SZ_TDB   = (size_t)B_ * N_ * 64 * 2;     // 10,240,000
constexpr size_t SZ_AGG   = (size_t)B_ * N_ * 64 * 4;     // 20,480,000
constexpr size_t SZ_EBUCK = (size_t)B_ * NWIN * WCAP * 4; // 10,240,000 (packed int)
constexpr size_t SZ_EPAIR = (size_t)B_ * E_ * 4;          // 5,120,000 (packed int)
constexpr size_t OFF_TDB  = 0;                            // tdb bf16; later kb16
constexpr size_t OFF_AGG  = SZ_TDB;                       // agg f32; later vb16
constexpr size_t OFF_EBUCK= OFF_AGG + SZ_AGG;
constexpr size_t OFF_EPAIR= OFF_EBUCK + SZ_EBUCK;
constexpr size_t OFF_HB16 = OFF_EPAIR + SZ_EPAIR;
constexpr size_t OFF_AVEC = OFF_HB16 + SZ_TDB;
constexpr size_t OFF_Q    = OFF_AVEC + 1024;
constexpr size_t OFF_CTX  = OFF_Q + 1024;
constexpr size_t OFF_WCMB = OFF_CTX + 1024;
constexpr size_t OFF_FLAG = OFF_WCMB + 1024;
constexpr size_t OFF_PART = OFF_FLAG + 64;                // 1024*18 f partials
constexpr size_t OFF_TAILS= OFF_PART + 1024 * 18 * 4 + 64;   // B*NWIN*TPAD ints
constexpr size_t OFF_WBASE= OFF_TAILS + (size_t)B_ * NWIN * TPAD * 4; // B*NWIN ints

static __device__ __forceinline__ unsigned short f2bf(float f) {
    union { float f; unsigned u; } v; v.f = f;
    unsigned r = v.u + 0x7fffu + ((v.u >> 16) & 1u);
    return (unsigned short)(r >> 16);
}
static __device__ __forceinline__ float bf2f(unsigned short u) {
    union { unsigned u; float f; } v; v.u = (unsigned)u << 16;
    return v.f;
}

// ---------------- mask dtype detection ----------------
__global__ void k_maskdetect(const unsigned int* __restrict__ m, int* __restrict__ flag) {
    if (blockIdx.x == 0 && threadIdx.x == 0) {
        bool alli = true, allf = true;
        for (int i = 0; i < 256; ++i) {
            unsigned v = m[i];
            alli = alli && (v <= 1u);
            allf = allf && (v == 0u || v == 0x3f800000u);
        }
        *flag = alli ? 1 : (allf ? 2 : 0);
    }
}

// ---------------- fused: embed (1/5 of groups) + XCD-partitioned bucket build ----------------
// Streaming reads (links, gn) are non-temporal so they don't evict the bucket
// frontier / hb16 working set from the XCD L2.
__global__ __launch_bounds__(256) void k_embed_bucket(const float* __restrict__ gn,
                                                      const float* __restrict__ wnod,
                                                      const float* __restrict__ bias,
                                                      unsigned short* __restrict__ hb16,
                                                      const int* __restrict__ links,
                                                      int* __restrict__ tails,
                                                      unsigned* __restrict__ ebuck) {
    int i = blockIdx.x;
    int g = i >> 3, r = i & 7;
    if (g % 5 == 4) {
        // ---- embed role ----
        int eb = (g / 5) * 8 + r;             // 0..1247
        int lane = threadIdx.x & 63;
        float wc[16];
#pragma unroll
        for (int k = 0; k < 16; ++k) wc[k] = wnod[k * 64 + lane];
        float bb = bias[lane];
        int gw = eb * 4 + (threadIdx.x >> 6);
        for (int node = gw; node < B_ * N_; node += 1248 * 4) {
            const float* rr = gn + (size_t)node * 16;
            float a0 = 0.f, a1 = 0.f, a2 = 0.f, a3 = 0.f;
#pragma unroll
            for (int k = 0; k < 16; k += 4) {
                a0 = fmaf(__builtin_nontemporal_load(rr + k + 0), wc[k + 0], a0);
                a1 = fmaf(__builtin_nontemporal_load(rr + k + 1), wc[k + 1], a1);
                a2 = fmaf(__builtin_nontemporal_load(rr + k + 2), wc[k + 2], a2);
                a3 = fmaf(__builtin_nontemporal_load(rr + k + 3), wc[k + 3], a3);
            }
            float v = fmaxf(bb + ((a0 + a1) + (a2 + a3)), 0.f);
            hb16[(size_t)node * 64 + lane] = f2bf(v);
        }
    } else {
        // ---- bucket role ----
        int og = g - (g + 1) / 5;             // bucket-group ordinal 0..624
        int b = r >> 1;
        int half = r & 1;
        int e0 = og * 512 + threadIdx.x;
        const int* lsrc = links + (size_t)b * 2 * E_;
#pragma unroll
        for (int ch = 0; ch < 2; ++ch) {
            int e = e0 + ch * 256;
            unsigned src = (unsigned)__builtin_nontemporal_load(lsrc + e);
            unsigned dst = (unsigned)__builtin_nontemporal_load(lsrc + E_ + e);
            int w = dst >> 4;                 // 0..1249
            if ((w >= HWIN) == (half == 1)) {
                int slot = atomicAdd(&tails[(b * NWIN + w) * TPAD], 1);
                if (slot < WCAP)
                    ebuck[(size_t)(b * NWIN + w) * WCAP + slot] = (dst << 16) | src;
            }
        }
    }
}

// ---------------- exclusive scan of (padded) window tails -> epair bases ----------------
__global__ __launch_bounds__(1024) void k_scan_tails(const int* __restrict__ tails,
                                                     int* __restrict__ wbase) {
    __shared__ int wsum[16];
    __shared__ int sbase;
    int b = blockIdx.x, t = threadIdx.x;
    int lane = t & 63, wv = t >> 6;
    if (t == 0) sbase = 0;
    __syncthreads();
    for (int base = 0; base < NWIN; base += 1024) {
        int idx = base + t;
        int c = 0;
        if (idx < NWIN) { c = tails[(b * NWIN + idx) * TPAD]; if (c > WCAP) c = WCAP; }
        int x = c;
#pragma unroll
        for (int o = 1; o < 64; o <<= 1) {
            int y = __shfl_up(x, o);
            if (lane >= o) x += y;
        }
        if (lane == 63) wsum[wv] = x;
        __syncthreads();
        if (wv == 0) {
            int s = (lane < 16) ? wsum[lane] : 0;
#pragma unroll
            for (int o = 1; o < 16; o <<= 1) {
                int y = __shfl_up(s, o);
                if (lane >= o) s += y;
            }
            if (lane < 16) wsum[lane] = s;
        }
        __syncthreads();
        int wpre = (wv > 0) ? wsum[wv - 1] : 0;
        int incl = x + wpre + sbase;
        if (idx < NWIN) wbase[b * NWIN + idx] = incl - c;   // exclusive
        __syncthreads();
        if (t == 1023) sbase = incl;
        __syncthreads();
    }
}

// ---------------- per-window 16-bin counting sort (LDS) -> sorted packed epair ----------------
__global__ __launch_bounds__(256) void k_sortwin(const unsigned* __restrict__ ebuck,
                                                 const int* __restrict__ tails,
                                                 const int* __restrict__ wbase,
                                                 unsigned* __restrict__ epair) {
    __shared__ int hist[16], hbase[16];
    __shared__ unsigned sbuf[WCAP];
    int i = blockIdx.x;                   // 0..4999
    int r = i & 7;
    int b = r >> 1;
    int w = (i >> 3) + HWIN * (r & 1);    // 0..1249, XCD-matched
    int cntw = tails[(b * NWIN + w) * TPAD];
    if (cntw > WCAP) cntw = WCAP;
    if (threadIdx.x < 16) hist[threadIdx.x] = 0;
    __syncthreads();
    const unsigned* src = ebuck + (size_t)(b * NWIN + w) * WCAP;
    int idx0 = threadIdx.x, idx1 = threadIdx.x + 256;
    bool v0 = idx0 < cntw, v1 = idx1 < cntw;
    unsigned e0 = 0, e1 = 0;
    if (v0) { e0 = __builtin_nontemporal_load(src + idx0); atomicAdd(&hist[(e0 >> 16) & 15], 1); }
    if (v1) { e1 = __builtin_nontemporal_load(src + idx1); atomicAdd(&hist[(e1 >> 16) & 15], 1); }
    __syncthreads();
    if (threadIdx.x == 0) {
        int run = 0;
#pragma unroll
        for (int p = 0; p < 16; ++p) { hbase[p] = run; run += hist[p]; }
    }
    __syncthreads();
    if (threadIdx.x < 16) hist[threadIdx.x] = 0;
    __syncthreads();
    if (v0) { int bn = (e0 >> 16) & 15; sbuf[hbase[bn] + atomicAdd(&hist[bn], 1)] = e0; }
    if (v1) { int bn = (e1 >> 16) & 15; sbuf[hbase[bn] + atomicAdd(&hist[bn], 1)] = e1; }
    __syncthreads();
    int gb = wbase[b * NWIN + w];
    unsigned* dst = epair + (size_t)b * E_ + gb;
    for (int idx = threadIdx.x; idx < cntw; idx += 256)
        __builtin_nontemporal_store(sbuf[idx], dst + idx);
}

// ---------------- tdst = W2^T h + msg_b (MFMA node GEMM, bf16 out) ----------------
__global__ __launch_bounds__(256) void k_tdst_mfma(const unsigned short* __restrict__ hb16,
                                                   const float* __restrict__ mw,
                                                   const float* __restrict__ mb,
                                                   unsigned short* __restrict__ tdb) {
    int lane = threadIdx.x & 63;
    int g = lane >> 4, c = lane & 15;
    short8 bf[4][2];
#pragma unroll
    for (int nt = 0; nt < 4; ++nt)
#pragma unroll
        for (int ks = 0; ks < 2; ++ks)
#pragma unroll
            for (int j = 0; j < 8; ++j)
                bf[nt][ks][j] = (short)f2bf(mw[(64 + ks * 32 + g * 8 + j) * 64 + nt * 16 + c]);
    float mbv[4];
#pragma unroll
    for (int nt = 0; nt < 4; ++nt) mbv[nt] = mb[nt * 16 + c];

    int wid = blockIdx.x * 4 + (threadIdx.x >> 6);
    int nw = gridDim.x * 4;
    f32x4 zero = {0.f, 0.f, 0.f, 0.f};
    for (int t = wid; t < NT_; t += nw) {
        const unsigned short* ap = hb16 + ((size_t)t * 16 + c) * 64;
        short8 a0 = *(const short8*)(ap + g * 8);
        short8 a1 = *(const short8*)(ap + 32 + g * 8);
        f32x4 acc[4];
#pragma unroll
        for (int nt = 0; nt < 4; ++nt) {
            acc[nt] = __builtin_amdgcn_mfma_f32_16x16x32_bf16(a0, bf[nt][0], zero, 0, 0, 0);
            acc[nt] = __builtin_amdgcn_mfma_f32_16x16x32_bf16(a1, bf[nt][1], acc[nt], 0, 0, 0);
        }
#pragma unroll
        for (int r = 0; r < 4; ++r) {
            size_t row = (size_t)t * 16 + 4 * g + r;
#pragma unroll
            for (int nt = 0; nt < 4; ++nt)
                tdb[row * 64 + nt * 16 + c] = f2bf(acc[nt][r] + mbv[nt]);
        }
    }
}

// ---------------- fused MFMA edge kernel (XCD-pinned, hoisted gathers) ----------------
__global__ __launch_bounds__(256) void k_edge_mfma(const unsigned short* __restrict__ hb16,
                                                   const unsigned short* __restrict__ tdb,
                                                   const unsigned* __restrict__ epair,
                                                   const float* __restrict__ mw,
                                                   float* __restrict__ agg) {
    int lane = threadIdx.x & 63;
    int g = lane >> 4, c = lane & 15;
    short8 bf[4][2];
#pragma unroll
    for (int nt = 0; nt < 4; ++nt)
#pragma unroll
        for (int ks = 0; ks < 2; ++ks)
#pragma unroll
            for (int j = 0; j < 8; ++j)
                bf[nt][ks][j] = (short)f2bf(mw[(ks * 32 + g * 8 + j) * 64 + nt * 16 + c]);

    int i = blockIdx.x;                       // 0..4999
    int b = (i & 7) >> 1;                     // batch (XCD-pinned pair)
    int o = ((i >> 3) << 1) | (i & 1);        // per-batch block ordinal 0..1249
    int w = threadIdx.x >> 6;
    const unsigned* pp = epair + (size_t)b * E_;
    const unsigned short* hbase = hb16 + (size_t)(b * N_) * 64;
    const unsigned short* tbase = tdb + (size_t)(b * N_) * 64;
    float* abase = agg + (size_t)(b * N_) * 64;

    bool hi1 = (lane & 32) != 0;
    bool hi0 = (lane & 16) != 0;

    unsigned pr[4];
#pragma unroll
    for (int k = 0; k < 4; ++k) {
        int t0 = (o * 4 + w) + k * 5000;
        pr[k] = __builtin_nontemporal_load(pp + t0 * 16 + c);
    }
    short8 a0[4], a1[4];
#pragma unroll
    for (int k = 0; k < 4; ++k) {
        const unsigned short* hrow = hbase + (size_t)(pr[k] & 0xFFFFu) * 64;
        a0[k] = *(const short8*)(hrow + g * 8);
        a1[k] = *(const short8*)(hrow + 32 + g * 8);
    }

    f32x4 zero = {0.f, 0.f, 0.f, 0.f};
#pragma unroll
    for (int k = 0; k < 4; ++k) {
        int dval = (int)(pr[k] >> 16);
        f32x4 acc[4];
#pragma unroll
        for (int nt = 0; nt < 4; ++nt) {
            acc[nt] = __builtin_amdgcn_mfma_f32_16x16x32_bf16(a0[k], bf[nt][0], zero, 0, 0, 0);
            acc[nt] = __builtin_amdgcn_mfma_f32_16x16x32_bf16(a1[k], bf[nt][1], acc[nt], 0, 0, 0);
        }

        int prev = __shfl(dval, (lane + 63) & 63);
        bool head = (c == 0) || (dval != prev);
        unsigned long long bal = __ballot(head);
        unsigned m16 = (unsigned)(bal & 0xFFFFu);

        while (m16) {
            int ii = __ffs(m16) - 1;
            unsigned rest = m16 & (m16 - 1);
            int jj = rest ? (__ffs(rest) - 1) : 16;
            m16 = rest;
            int d = __shfl(dval, ii);

            const unsigned short* trow = tbase + (size_t)d * 64;
            float t0v = bf2f(trow[c]);
            float t1v = bf2f(trow[16 + c]);
            float t2v = bf2f(trow[32 + c]);
            float t3v = bf2f(trow[48 + c]);

            float v0 = 0.f, v1 = 0.f, v2 = 0.f, v3 = 0.f;
#pragma unroll
            for (int r = 0; r < 4; ++r) {
                int rr = 4 * g + r;
                bool in = (rr >= ii) && (rr < jj);
                v0 += in ? fmaxf(acc[0][r] + t0v, 0.f) : 0.f;
                v1 += in ? fmaxf(acc[1][r] + t1v, 0.f) : 0.f;
                v2 += in ? fmaxf(acc[2][r] + t2v, 0.f) : 0.f;
                v3 += in ? fmaxf(acc[3][r] + t3v, 0.f) : 0.f;
            }
            float sA0 = hi1 ? v0 : v2;
            float sA1 = hi1 ? v1 : v3;
            float rA0 = __shfl_xor(sA0, 32);
            float rA1 = __shfl_xor(sA1, 32);
            float w0 = (hi1 ? v2 : v0) + rA0;
            float w1 = (hi1 ? v3 : v1) + rA1;
            float sB = hi0 ? w0 : w1;
            float rB = __shfl_xor(sB, 16);
            float outv = (hi0 ? w1 : w0) + rB;

            atomicAdd(&abase[(size_t)d * 64 + lane], outv);
        }
    }
}

// ---------------- h(bf16) += relu([h,agg] @ upd_w + upd_b) (MFMA) ----------------
__global__ __launch_bounds__(256) void k_upd_mfma(unsigned short* __restrict__ hb16,
                                                  const float* __restrict__ agg,
                                                  const float* __restrict__ uw,
                                                  const float* __restrict__ ub) {
    int lane = threadIdx.x & 63;
    int g = lane >> 4, c = lane & 15;
    short8 bh[4][2], ba[4][2];
#pragma unroll
    for (int nt = 0; nt < 4; ++nt)
#pragma unroll
        for (int ks = 0; ks < 2; ++ks)
#pragma unroll
            for (int j = 0; j < 8; ++j) {
                bh[nt][ks][j] = (short)f2bf(uw[(ks * 32 + g * 8 + j) * 64 + nt * 16 + c]);
                ba[nt][ks][j] = (short)f2bf(uw[(64 + ks * 32 + g * 8 + j) * 64 + nt * 16 + c]);
            }
    float ubv[4];
#pragma unroll
    for (int nt = 0; nt < 4; ++nt) ubv[nt] = ub[nt * 16 + c];

    int wid = blockIdx.x * 4 + (threadIdx.x >> 6);
    int nw = gridDim.x * 4;
    f32x4 zero = {0.f, 0.f, 0.f, 0.f};
    for (int t = wid; t < NT_; t += nw) {
        unsigned short* ap = hb16 + ((size_t)t * 16 + c) * 64;
        short8 a0 = *(const short8*)(ap + g * 8);
        short8 a1 = *(const short8*)(ap + 32 + g * 8);

        const float* gp = agg + ((size_t)t * 16 + c) * 64;
        float4 q0 = *(const float4*)(gp + g * 8);
        float4 q1 = *(const float4*)(gp + g * 8 + 4);
        float4 q2 = *(const float4*)(gp + 32 + g * 8);
        float4 q3 = *(const float4*)(gp + 32 + g * 8 + 4);
        short8 s0, s1;
        s0[0] = (short)f2bf(q0.x); s0[1] = (short)f2bf(q0.y);
        s0[2] = (short)f2bf(q0.z); s0[3] = (short)f2bf(q0.w);
        s0[4] = (short)f2bf(q1.x); s0[5] = (short)f2bf(q1.y);
        s0[6] = (short)f2bf(q1.z); s0[7] = (short)f2bf(q1.w);
        s1[0] = (short)f2bf(q2.x); s1[1] = (short)f2bf(q2.y);
        s1[2] = (short)f2bf(q2.z); s1[3] = (short)f2bf(q2.w);
        s1[4] = (short)f2bf(q3.x); s1[5] = (short)f2bf(q3.y);
        s1[6] = (short)f2bf(q3.z); s1[7] = (short)f2bf(q3.w);

        f32x4 acc[4];
#pragma unroll
        for (int nt = 0; nt < 4; ++nt) {
            acc[nt] = __builtin_amdgcn_mfma_f32_16x16x32_bf16(a0, bh[nt][0], zero, 0, 0, 0);
            acc[nt] = __builtin_amdgcn_mfma_f32_16x16x32_bf16(a1, bh[nt][1], acc[nt], 0, 0, 0);
            acc[nt] = __builtin_amdgcn_mfma_f32_16x16x32_bf16(s0, ba[nt][0], acc[nt], 0, 0, 0);
            acc[nt] = __builtin_amdgcn_mfma_f32_16x16x32_bf16(s1, ba[nt][1], acc[nt], 0, 0, 0);
        }
#pragma unroll
        for (int r = 0; r < 4; ++r) {
            size_t row = (size_t)t * 16 + 4 * g + r;
#pragma unroll
            for (int nt = 0; nt < 4; ++nt) {
                size_t idx = row * 64 + nt * 16 + c;
                float v = bf2f(hb16[idx]) + fmaxf(acc[nt][r] + ubv[nt], 0.f);
                hb16[idx] = f2bf(v);
            }
        }
    }
}

// ---------------- k/v projections (MFMA, bf16 out) ----------------
__global__ __launch_bounds__(256) void k_kv_mfma(const unsigned short* __restrict__ hb16,
                                                 const float* __restrict__ wk,
                                                 const float* __restrict__ bk,
                                                 const float* __restrict__ wv,
                                                 const float* __restrict__ bv,
                                                 unsigned short* __restrict__ kb16,
                                                 unsigned short* __restrict__ vb16) {
    int lane = threadIdx.x & 63;
    int g = lane >> 4, c = lane & 15;
    short8 bkf[4][2], bvf[4][2];
#pragma unroll
    for (int nt = 0; nt < 4; ++nt)
#pragma unroll
        for (int ks = 0; ks < 2; ++ks)
#pragma unroll
            for (int j = 0; j < 8; ++j) {
                bkf[nt][ks][j] = (short)f2bf(wk[(ks * 32 + g * 8 + j) * 64 + nt * 16 + c]);
                bvf[nt][ks][j] = (short)f2bf(wv[(ks * 32 + g * 8 + j) * 64 + nt * 16 + c]);
            }
    float bkv[4], bvv[4];
#pragma unroll
    for (int nt = 0; nt < 4; ++nt) { bkv[nt] = bk[nt * 16 + c]; bvv[nt] = bv[nt * 16 + c]; }

    int wid = blockIdx.x * 4 + (threadIdx.x >> 6);
    int nw = gridDim.x * 4;
    f32x4 zero = {0.f, 0.f, 0.f, 0.f};
    for (int t = wid; t < NT_; t += nw) {
        const unsigned short* ap = hb16 + ((size_t)t * 16 + c) * 64;
        short8 a0 = *(const short8*)(ap + g * 8);
        short8 a1 = *(const short8*)(ap + 32 + g * 8);
        f32x4 ak[4], av[4];
#pragma unroll
        for (int nt = 0; nt < 4; ++nt) {
            ak[nt] = __builtin_amdgcn_mfma_f32_16x16x32_bf16(a0, bkf[nt][0], zero, 0, 0, 0);
            ak[nt] = __builtin_amdgcn_mfma_f32_16x16x32_bf16(a1, bkf[nt][1], ak[nt], 0, 0, 0);
            av[nt] = __builtin_amdgcn_mfma_f32_16x16x32_bf16(a0, bvf[nt][0], zero, 0, 0, 0);
            av[nt] = __builtin_amdgcn_mfma_f32_16x16x32_bf16(a1, bvf[nt][1], av[nt], 0, 0, 0);
        }
#pragma unroll
        for (int r = 0; r < 4; ++r) {
            size_t row = (size_t)t * 16 + 4 * g + r;
#pragma unroll
            for (int nt = 0; nt < 4; ++nt) {
                kb16[row * 64 + nt * 16 + c] = f2bf(ak[nt][r] + bkv[nt]);
                vb16[row * 64 + nt * 16 + c] = f2bf(av[nt][r] + bvv[nt]);
            }
        }
    }
}

// ---------------- a = relu(ad @ w_ad + b_ad); q = a @ wq + bq ----------------
__global__ __launch_bounds__(64) void k_aq(const float* __restrict__ ad,
                                           const float* __restrict__ wad,
                                           const float* __restrict__ bad,
                                           const float* __restrict__ wq,
                                           const float* __restrict__ bq,
                                           float* __restrict__ a_out,
                                           float* __restrict__ q_out) {
    int b = blockIdx.x, t = threadIdx.x;
    __shared__ float sa[64];
    float acc = bad[t];
#pragma unroll
    for (int i = 0; i < 8; ++i) acc = fmaf(ad[b * 8 + i], wad[i * 64 + t], acc);
    float av = fmaxf(acc, 0.f);
    sa[t] = av;
    a_out[b * 64 + t] = av;
    __syncthreads();
    float qa = bq[t];
    for (int i = 0; i < 64; ++i) qa = fmaf(sa[i], wq[i * 64 + t], qa);
    q_out[b * 64 + t] = qa;
}

// ---------------- attention: chunked online softmax partials (bf16 k/v) ----------------
__global__ __launch_bounds__(256) void k_attn(const float* __restrict__ q,
                                              const unsigned short* __restrict__ kb16,
                                              const unsigned short* __restrict__ vb16,
                                              float* __restrict__ part) {
    int id = blockIdx.x;
    int ch = id % NCH;
    int bh = id / NCH;
    int b = bh / HEADS_, hd = bh % HEADS_;
    float qv[16];
#pragma unroll
    for (int d = 0; d < 16; ++d) qv[d] = q[b * 64 + hd * 16 + d];
    float m = -1e30f, s = 0.f, c[16];
#pragma unroll
    for (int d = 0; d < 16; ++d) c[d] = 0.f;
    int n0 = ch * CS;
    int n1 = n0 + CS; if (n1 > N_) n1 = N_;
    for (int n = n0 + threadIdx.x; n < n1; n += 256) {
        const short8* kr = (const short8*)(kb16 + ((size_t)b * N_ + n) * 64 + hd * 16);
        short8 k0 = kr[0], k1 = kr[1];
        float dot = 0.f;
#pragma unroll
        for (int d = 0; d < 8; ++d) {
            dot = fmaf(qv[d], bf2f((unsigned short)k0[d]), dot);
            dot = fmaf(qv[8 + d], bf2f((unsigned short)k1[d]), dot);
        }
        dot *= 0.25f;
        float nm = fmaxf(m, dot);
        float p = __expf(dot - nm);
        float cor = __expf(m - nm);
        const short8* vr = (const short8*)(vb16 + ((size_t)b * N_ + n) * 64 + hd * 16);
        short8 v0 = vr[0], v1 = vr[1];
        s = s * cor + p;
#pragma unroll
        for (int d = 0; d < 8; ++d) {
            c[d] = c[d] * cor + p * bf2f((unsigned short)v0[d]);
            c[8 + d] = c[8 + d] * cor + p * bf2f((unsigned short)v1[d]);
        }
        m = nm;
    }
#pragma unroll
    for (int o = 1; o < 64; o <<= 1) {
        float m2 = __shfl_xor(m, o);
        float s2 = __shfl_xor(s, o);
        float nm = fmaxf(m, m2);
        float w1 = __expf(m - nm), w2 = __expf(m2 - nm);
        s = s * w1 + s2 * w2;
#pragma unroll
        for (int d = 0; d < 16; ++d) {
            float c2 = __shfl_xor(c[d], o);
            c[d] = c[d] * w1 + c2 * w2;
        }
        m = nm;
    }
    __shared__ float red[4][18];
    int wv_ = threadIdx.x >> 6, lane = threadIdx.x & 63;
    if (lane == 0) {
        red[wv_][0] = m; red[wv_][1] = s;
#pragma unroll
        for (int d = 0; d < 16; ++d) red[wv_][2 + d] = c[d];
    }
    __syncthreads();
    if (threadIdx.x == 0) {
        float gm = red[0][0];
        for (int w = 1; w < 4; ++w) gm = fmaxf(gm, red[w][0]);
        float gs = 0.f, gc[16];
#pragma unroll
        for (int d = 0; d < 16; ++d) gc[d] = 0.f;
        for (int w = 0; w < 4; ++w) {
            float ww = __expf(red[w][0] - gm);
            gs += red[w][1] * ww;
#pragma unroll
            for (int d = 0; d < 16; ++d) gc[d] += red[w][2 + d] * ww;
        }
        float* p = part + (size_t)id * 18;
        p[0] = gm; p[1] = gs;
#pragma unroll
        for (int d = 0; d < 16; ++d) p[2 + d] = gc[d];
    }
}

__global__ __launch_bounds__(64) void k_comb(const float* __restrict__ part,
                                             float* __restrict__ ctx) {
    int bh = blockIdx.x, t = threadIdx.x;
    int b = bh / HEADS_, hd = bh % HEADS_;
    const float* p = part + ((size_t)bh * NCH + t) * 18;
    float m = p[0], s = p[1], c[16];
#pragma unroll
    for (int d = 0; d < 16; ++d) c[d] = p[2 + d];
    float gm = m;
#pragma unroll
    for (int o = 1; o < 64; o <<= 1) gm = fmaxf(gm, __shfl_xor(gm, o));
    float w = __expf(m - gm);
    float sw = s * w;
#pragma unroll
    for (int o = 1; o < 64; o <<= 1) sw += __shfl_xor(sw, o);
    float cg[16];
#pragma unroll
    for (int d = 0; d < 16; ++d) {
        float x = c[d] * w;
#pragma unroll
        for (int o = 1; o < 64; o <<= 1) x += __shfl_xor(x, o);
        cg[d] = x;
    }
    if (t == 0) {
#pragma unroll
        for (int d = 0; d < 16; ++d) ctx[b * 64 + hd * 16 + d] = cg[d] / sw;
    }
}

// ---------------- g = LN(a + ctx@wo + bo); wcomb = g/8 + policy_w ----------------
__global__ __launch_bounds__(64) void k_g(const float* __restrict__ a,
                                          const float* __restrict__ ctx,
                                          const float* __restrict__ wo,
                                          const float* __restrict__ bo,
                                          const float* __restrict__ lng,
                                          const float* __restrict__ lnb,
                                          const float* __restrict__ pw,
                                          float* __restrict__ wcomb) {
    int b = blockIdx.x, t = threadIdx.x;
    __shared__ float sc[64];
    sc[t] = ctx[b * 64 + t];
    __syncthreads();
    float o = bo[t];
    for (int i = 0; i < 64; ++i) o = fmaf(sc[i], wo[i * 64 + t], o);
    float y = a[b * 64 + t] + o;
    float mu = y;
#pragma unroll
    for (int oo = 1; oo < 64; oo <<= 1) mu += __shfl_xor(mu, oo);
    mu *= (1.f / 64.f);
    float d = y - mu;
    float var = d * d;
#pragma unroll
    for (int oo = 1; oo < 64; oo <<= 1) var += __shfl_xor(var, oo);
    var *= (1.f / 64.f);
    float g = d * rsqrtf(var + 1e-5f) * lng[t] + lnb[t];
    wcomb[b * 64 + t] = g * 0.125f + pw[t];
}

// ---------------- logits (bf16 h) ----------------
__global__ __launch_bounds__(256) void k_final(const unsigned short* __restrict__ hb16,
                                               const float* __restrict__ wcomb,
                                               const float* __restrict__ pb,
                                               const void* __restrict__ mask,
                                               const int* __restrict__ flagp,
                                               float* __restrict__ out) {
    int idx = blockIdx.x * 256 + threadIdx.x;
    if (idx >= B_ * N_) return;
    int b = idx / N_;
    const float* wr = wcomb + b * 64;
    const short8* hr = (const short8*)(hb16 + (size_t)idx * 64);
    float acc = pb[0];
#pragma unroll
    for (int i = 0; i < 8; ++i) {
        short8 hv = hr[i];
#pragma unroll
        for (int j = 0; j < 8; ++j)
            acc = fmaf(bf2f((unsigned short)hv[j]), wr[i * 8 + j], acc);
    }
    int flag = *flagp;
    bool mv;
    if (flag == 1)      mv = ((const int*)mask)[idx] != 0;
    else if (flag == 2) mv = ((const float*)mask)[idx] != 0.f;
    else                mv = ((const unsigned char*)mask)[idx] != 0;
    out[idx] = mv ? acc : -1.0e9f;
}

extern "C" void kernel_launch(void* const* d_in, const int* in_sizes, int n_in,
                              void* d_out, int out_size, void* d_ws, size_t ws_size,
                              hipStream_t stream) {
    const float* gn   = (const float*)d_in[0];
    const float* ad   = (const float*)d_in[1];
    const float* wnod = (const float*)d_in[2];
    const float* bnod = (const float*)d_in[3];
    const float* msgw = (const float*)d_in[4];
    const float* msgb = (const float*)d_in[5];
    const float* updw = (const float*)d_in[6];
    const float* updb = (const float*)d_in[7];
    const float* wad  = (const float*)d_in[8];
    const float* bad  = (const float*)d_in[9];
    const float* wq   = (const float*)d_in[10];
    const float* bq   = (const float*)d_in[11];
    const float* wk   = (const float*)d_in[12];
    const float* bk   = (const float*)d_in[13];
    const float* wv   = (const float*)d_in[14];
    const float* bv   = (const float*)d_in[15];
    const float* wo   = (const float*)d_in[16];
    const float* bo   = (const float*)d_in[17];
    const float* lng  = (const float*)d_in[18];
    const float* lnb  = (const float*)d_in[19];
    const float* pw   = (const float*)d_in[20];
    const float* pb   = (const float*)d_in[21];
    const int*   links= (const int*)d_in[22];
    const void*  mask = d_in[23];

    char* ws = (char*)d_ws;
    unsigned short* tdb  = (unsigned short*)(ws + OFF_TDB);
    unsigned short* kb16 = (unsigned short*)(ws + OFF_TDB);
    float* agg  = (float*)(ws + OFF_AGG);
    unsigned short* vb16 = (unsigned short*)(ws + OFF_AGG);
    unsigned* ebuck = (unsigned*)(ws + OFF_EBUCK);
    unsigned* epair = (unsigned*)(ws + OFF_EPAIR);
    unsigned short* hb16 = (unsigned short*)(ws + OFF_HB16);
    float* avec = (float*)(ws + OFF_AVEC);
    float* qvec = (float*)(ws + OFF_Q);
    float* ctx  = (float*)(ws + OFF_CTX);
    float* wcmb = (float*)(ws + OFF_WCMB);
    int*   flag = (int*)(ws + OFF_FLAG);
    float* part = (float*)(ws + OFF_PART);
    int*   tails= (int*)(ws + OFF_TAILS);
    int*   wbase= (int*)(ws + OFF_WBASE);
    float* out  = (float*)d_out;

    hipMemsetAsync(tails, 0, (size_t)B_ * NWIN * TPAD * 4, stream);
    k_maskdetect<<<1, 1, 0, stream>>>((const unsigned int*)mask, flag);
    k_embed_bucket<<<6248, 256, 0, stream>>>(gn, wnod, bnod, hb16, links, tails, ebuck);
    k_scan_tails<<<B_, 1024, 0, stream>>>(tails, wbase);
    k_sortwin<<<5000, 256, 0, stream>>>(ebuck, tails, wbase, epair);

    for (int l = 0; l < 2; ++l) {
        const float* mwl = msgw + (size_t)l * 128 * 64;
        const float* mbl = msgb + (size_t)l * 64;
        const float* uwl = updw + (size_t)l * 128 * 64;
        const float* ubl = updb + (size_t)l * 64;
        k_tdst_mfma<<<512, 256, 0, stream>>>(hb16, mwl, mbl, tdb);
        hipMemsetAsync(agg, 0, SZ_AGG, stream);
        k_edge_mfma<<<5000, 256, 0, stream>>>(hb16, tdb, epair, mwl, agg);
        k_upd_mfma<<<512, 256, 0, stream>>>(hb16, agg, uwl, ubl);
    }

    k_aq<<<B_, 64, 0, stream>>>(ad, wad, bad, wq, bq, avec, qvec);
    k_kv_mfma<<<512, 256, 0, stream>>>(hb16, wk, bk, wv, bv, kb16, vb16);
    k_attn<<<B_ * HEADS_ * NCH, 256, 0, stream>>>(qvec, kb16, vb16, part);
    k_comb<<<B_ * HEADS_, 64, 0, stream>>>(part, ctx);
    k_g<<<B_, 64, 0, stream>>>(avec, ctx, wo, bo, lng, lnb, pw, wcmb);
    k_final<<<(B_ * N_ + 255) / 256, 256, 0, stream>>>(hb16, wcmb, pb, mask, flag, out);
}

// Round 16
// 272.090 us; speedup vs baseline: 1.1459x; 1.1459x over previous
//
#include <hip/hip_runtime.h>
#include <hip/hip_bf16.h>
#include <math.h>

// Problem constants
constexpr int B_ = 4;
constexpr int N_ = 20000;
constexpr int E_ = 320000;
constexpr int HEADS_ = 4;
constexpr int NCH = 64;                       // attention chunks per (b,head)
constexpr int CS = (N_ + NCH - 1) / NCH;      // 313
constexpr int NT_ = (B_ * N_) / 16;           // 5000 node tiles
constexpr int NWIN = 1250;                    // 16-dst windows per batch
constexpr int HWIN = 625;                     // windows per XCD half
constexpr int WCAP = 512;                     // bucket capacity (mean 256, +16 sigma)
constexpr int TPAD = 16;                      // tails padding -> 1 counter/line

typedef __attribute__((ext_vector_type(8))) short short8;   // 8 bf16
typedef __attribute__((ext_vector_type(4))) float f32x4;

// Workspace layout (bytes). ~67 MB.
constexpr size_t SZ_TDB   = (size_t)B_ * N_ * 64 * 2;     // 10,240,000
constexpr size_t SZ_AGG   = (size_t)B_ * N_ * 64 * 4;     // 20,480,000
constexpr size_t SZ_EBUCK = (size_t)B_ * NWIN * WCAP * 4; // 10,240,000 (packed int)
constexpr size_t SZ_EPAIR = (size_t)B_ * E_ * 4;          // 5,120,000 (packed int)
constexpr size_t OFF_TDB  = 0;                            // tdb bf16; later kb16
constexpr size_t OFF_AGG  = SZ_TDB;                       // agg f32
constexpr size_t OFF_EBUCK= OFF_AGG + SZ_AGG;
constexpr size_t OFF_EPAIR= OFF_EBUCK + SZ_EBUCK;
constexpr size_t OFF_HB16 = OFF_EPAIR + SZ_EPAIR;
constexpr size_t OFF_AVEC = OFF_HB16 + SZ_TDB;
constexpr size_t OFF_Q    = OFF_AVEC + 1024;
constexpr size_t OFF_CTX  = OFF_Q + 1024;
constexpr size_t OFF_WCMB = OFF_CTX + 1024;
constexpr size_t OFF_FLAG = OFF_WCMB + 1024;
constexpr size_t OFF_PART = OFF_FLAG + 64;                // 1024*18 f partials
constexpr size_t OFF_TAILS= OFF_PART + 1024 * 18 * 4 + 64;   // B*NWIN*TPAD ints
constexpr size_t OFF_WBASE= OFF_TAILS + (size_t)B_ * NWIN * TPAD * 4; // B*NWIN ints
constexpr size_t OFF_VB16 = OFF_WBASE + (size_t)B_ * NWIN * 4 + 64;   // v bf16 (own region)

static __device__ __forceinline__ unsigned short f2bf(float f) {
    union { float f; unsigned u; } v; v.f = f;
    unsigned r = v.u + 0x7fffu + ((v.u >> 16) & 1u);
    return (unsigned short)(r >> 16);
}
static __device__ __forceinline__ float bf2f(unsigned short u) {
    union { unsigned u; float f; } v; v.u = (unsigned)u << 16;
    return v.f;
}

// ---------------- mask dtype detection ----------------
__global__ void k_maskdetect(const unsigned int* __restrict__ m, int* __restrict__ flag) {
    if (blockIdx.x == 0 && threadIdx.x == 0) {
        bool alli = true, allf = true;
        for (int i = 0; i < 256; ++i) {
            unsigned v = m[i];
            alli = alli && (v <= 1u);
            allf = allf && (v == 0u || v == 0x3f800000u);
        }
        *flag = alli ? 1 : (allf ? 2 : 0);
    }
}

// ---------------- fused: embed (1/5 of groups) + XCD-partitioned bucket build ----------------
__global__ __launch_bounds__(256) void k_embed_bucket(const float* __restrict__ gn,
                                                      const float* __restrict__ wnod,
                                                      const float* __restrict__ bias,
                                                      unsigned short* __restrict__ hb16,
                                                      const int* __restrict__ links,
                                                      int* __restrict__ tails,
                                                      unsigned* __restrict__ ebuck) {
    int i = blockIdx.x;
    int g = i >> 3, r = i & 7;
    if (g % 5 == 4) {
        int eb = (g / 5) * 8 + r;             // 0..1247
        int lane = threadIdx.x & 63;
        float wc[16];
#pragma unroll
        for (int k = 0; k < 16; ++k) wc[k] = wnod[k * 64 + lane];
        float bb = bias[lane];
        int gw = eb * 4 + (threadIdx.x >> 6);
        for (int node = gw; node < B_ * N_; node += 1248 * 4) {
            const float* rr = gn + (size_t)node * 16;
            float a0 = 0.f, a1 = 0.f, a2 = 0.f, a3 = 0.f;
#pragma unroll
            for (int k = 0; k < 16; k += 4) {
                a0 = fmaf(rr[k + 0], wc[k + 0], a0);
                a1 = fmaf(rr[k + 1], wc[k + 1], a1);
                a2 = fmaf(rr[k + 2], wc[k + 2], a2);
                a3 = fmaf(rr[k + 3], wc[k + 3], a3);
            }
            float v = fmaxf(bb + ((a0 + a1) + (a2 + a3)), 0.f);
            hb16[(size_t)node * 64 + lane] = f2bf(v);
        }
    } else {
        int og = g - (g + 1) / 5;             // 0..624
        int b = r >> 1;
        int half = r & 1;
        int e0 = og * 512 + threadIdx.x;
        const int* lsrc = links + (size_t)b * 2 * E_;
#pragma unroll
        for (int ch = 0; ch < 2; ++ch) {
            int e = e0 + ch * 256;
            unsigned src = (unsigned)lsrc[e];
            unsigned dst = (unsigned)lsrc[E_ + e];
            int w = dst >> 4;                 // 0..1249
            if ((w >= HWIN) == (half == 1)) {
                int slot = atomicAdd(&tails[(b * NWIN + w) * TPAD], 1);
                if (slot < WCAP)
                    ebuck[(size_t)(b * NWIN + w) * WCAP + slot] = (dst << 16) | src;
            }
        }
    }
}

// ---------------- exclusive scan of (padded) window tails -> epair bases ----------------
__global__ __launch_bounds__(1024) void k_scan_tails(const int* __restrict__ tails,
                                                     int* __restrict__ wbase) {
    __shared__ int wsum[16];
    __shared__ int sbase;
    int b = blockIdx.x, t = threadIdx.x;
    int lane = t & 63, wv = t >> 6;
    if (t == 0) sbase = 0;
    __syncthreads();
    for (int base = 0; base < NWIN; base += 1024) {
        int idx = base + t;
        int c = 0;
        if (idx < NWIN) { c = tails[(b * NWIN + idx) * TPAD]; if (c > WCAP) c = WCAP; }
        int x = c;
#pragma unroll
        for (int o = 1; o < 64; o <<= 1) {
            int y = __shfl_up(x, o);
            if (lane >= o) x += y;
        }
        if (lane == 63) wsum[wv] = x;
        __syncthreads();
        if (wv == 0) {
            int s = (lane < 16) ? wsum[lane] : 0;
#pragma unroll
            for (int o = 1; o < 16; o <<= 1) {
                int y = __shfl_up(s, o);
                if (lane >= o) s += y;
            }
            if (lane < 16) wsum[lane] = s;
        }
        __syncthreads();
        int wpre = (wv > 0) ? wsum[wv - 1] : 0;
        int incl = x + wpre + sbase;
        if (idx < NWIN) wbase[b * NWIN + idx] = incl - c;   // exclusive
        __syncthreads();
        if (t == 1023) sbase = incl;
        __syncthreads();
    }
}

// ---------------- per-window 16-bin counting sort (LDS) -> sorted packed epair ----------------
__global__ __launch_bounds__(256) void k_sortwin(const unsigned* __restrict__ ebuck,
                                                 const int* __restrict__ tails,
                                                 const int* __restrict__ wbase,
                                                 unsigned* __restrict__ epair) {
    __shared__ int hist[16], hbase[16];
    __shared__ unsigned sbuf[WCAP];
    int i = blockIdx.x;                   // 0..4999
    int r = i & 7;
    int b = r >> 1;
    int w = (i >> 3) + HWIN * (r & 1);    // XCD-matched
    int cntw = tails[(b * NWIN + w) * TPAD];
    if (cntw > WCAP) cntw = WCAP;
    if (threadIdx.x < 16) hist[threadIdx.x] = 0;
    __syncthreads();
    const unsigned* src = ebuck + (size_t)(b * NWIN + w) * WCAP;
    int idx0 = threadIdx.x, idx1 = threadIdx.x + 256;
    bool v0 = idx0 < cntw, v1 = idx1 < cntw;
    unsigned e0 = 0, e1 = 0;
    if (v0) { e0 = src[idx0]; atomicAdd(&hist[(e0 >> 16) & 15], 1); }
    if (v1) { e1 = src[idx1]; atomicAdd(&hist[(e1 >> 16) & 15], 1); }
    __syncthreads();
    if (threadIdx.x == 0) {
        int run = 0;
#pragma unroll
        for (int p = 0; p < 16; ++p) { hbase[p] = run; run += hist[p]; }
    }
    __syncthreads();
    if (threadIdx.x < 16) hist[threadIdx.x] = 0;
    __syncthreads();
    if (v0) { int bn = (e0 >> 16) & 15; sbuf[hbase[bn] + atomicAdd(&hist[bn], 1)] = e0; }
    if (v1) { int bn = (e1 >> 16) & 15; sbuf[hbase[bn] + atomicAdd(&hist[bn], 1)] = e1; }
    __syncthreads();
    int gb = wbase[b * NWIN + w];
    unsigned* dst = epair + (size_t)b * E_ + gb;
    for (int idx = threadIdx.x; idx < cntw; idx += 256) dst[idx] = sbuf[idx];
}

// ---------------- tdst = W2^T h + msg_b (standalone, layer 0 only) ----------------
__global__ __launch_bounds__(256) void k_tdst_mfma(const unsigned short* __restrict__ hb16,
                                                   const float* __restrict__ mw,
                                                   const float* __restrict__ mb,
                                                   unsigned short* __restrict__ tdb) {
    int lane = threadIdx.x & 63;
    int g = lane >> 4, c = lane & 15;
    short8 bf[4][2];
#pragma unroll
    for (int nt = 0; nt < 4; ++nt)
#pragma unroll
        for (int ks = 0; ks < 2; ++ks)
#pragma unroll
            for (int j = 0; j < 8; ++j)
                bf[nt][ks][j] = (short)f2bf(mw[(64 + ks * 32 + g * 8 + j) * 64 + nt * 16 + c]);
    float mbv[4];
#pragma unroll
    for (int nt = 0; nt < 4; ++nt) mbv[nt] = mb[nt * 16 + c];

    int wid = blockIdx.x * 4 + (threadIdx.x >> 6);
    int nw = gridDim.x * 4;
    f32x4 zero = {0.f, 0.f, 0.f, 0.f};
    for (int t = wid; t < NT_; t += nw) {
        const unsigned short* ap = hb16 + ((size_t)t * 16 + c) * 64;
        short8 a0 = *(const short8*)(ap + g * 8);
        short8 a1 = *(const short8*)(ap + 32 + g * 8);
        f32x4 acc[4];
#pragma unroll
        for (int nt = 0; nt < 4; ++nt) {
            acc[nt] = __builtin_amdgcn_mfma_f32_16x16x32_bf16(a0, bf[nt][0], zero, 0, 0, 0);
            acc[nt] = __builtin_amdgcn_mfma_f32_16x16x32_bf16(a1, bf[nt][1], acc[nt], 0, 0, 0);
        }
#pragma unroll
        for (int r = 0; r < 4; ++r) {
            size_t row = (size_t)t * 16 + 4 * g + r;
#pragma unroll
            for (int nt = 0; nt < 4; ++nt)
                tdb[row * 64 + nt * 16 + c] = f2bf(acc[nt][r] + mbv[nt]);
        }
    }
}

// ---------------- fused MFMA edge kernel (XCD-pinned, hoisted gathers) ----------------
__global__ __launch_bounds__(256) void k_edge_mfma(const unsigned short* __restrict__ hb16,
                                                   const unsigned short* __restrict__ tdb,
                                                   const unsigned* __restrict__ epair,
                                                   const float* __restrict__ mw,
                                                   float* __restrict__ agg) {
    int lane = threadIdx.x & 63;
    int g = lane >> 4, c = lane & 15;
    short8 bf[4][2];
#pragma unroll
    for (int nt = 0; nt < 4; ++nt)
#pragma unroll
        for (int ks = 0; ks < 2; ++ks)
#pragma unroll
            for (int j = 0; j < 8; ++j)
                bf[nt][ks][j] = (short)f2bf(mw[(ks * 32 + g * 8 + j) * 64 + nt * 16 + c]);

    int i = blockIdx.x;                       // 0..4999
    int b = (i & 7) >> 1;                     // batch (XCD-pinned pair)
    int o = ((i >> 3) << 1) | (i & 1);        // per-batch block ordinal 0..1249
    int w = threadIdx.x >> 6;
    const unsigned* pp = epair + (size_t)b * E_;
    const unsigned short* hbase = hb16 + (size_t)(b * N_) * 64;
    const unsigned short* tbase = tdb + (size_t)(b * N_) * 64;
    float* abase = agg + (size_t)(b * N_) * 64;

    bool hi1 = (lane & 32) != 0;
    bool hi0 = (lane & 16) != 0;

    unsigned pr[4];
#pragma unroll
    for (int k = 0; k < 4; ++k) {
        int t0 = (o * 4 + w) + k * 5000;
        pr[k] = pp[t0 * 16 + c];
    }
    short8 a0[4], a1[4];
#pragma unroll
    for (int k = 0; k < 4; ++k) {
        const unsigned short* hrow = hbase + (size_t)(pr[k] & 0xFFFFu) * 64;
        a0[k] = *(const short8*)(hrow + g * 8);
        a1[k] = *(const short8*)(hrow + 32 + g * 8);
    }

    f32x4 zero = {0.f, 0.f, 0.f, 0.f};
#pragma unroll
    for (int k = 0; k < 4; ++k) {
        int dval = (int)(pr[k] >> 16);
        f32x4 acc[4];
#pragma unroll
        for (int nt = 0; nt < 4; ++nt) {
            acc[nt] = __builtin_amdgcn_mfma_f32_16x16x32_bf16(a0[k], bf[nt][0], zero, 0, 0, 0);
            acc[nt] = __builtin_amdgcn_mfma_f32_16x16x32_bf16(a1[k], bf[nt][1], acc[nt], 0, 0, 0);
        }

        int prev = __shfl(dval, (lane + 63) & 63);
        bool head = (c == 0) || (dval != prev);
        unsigned long long bal = __ballot(head);
        unsigned m16 = (unsigned)(bal & 0xFFFFu);

        while (m16) {
            int ii = __ffs(m16) - 1;
            unsigned rest = m16 & (m16 - 1);
            int jj = rest ? (__ffs(rest) - 1) : 16;
            m16 = rest;
            int d = __shfl(dval, ii);

            const unsigned short* trow = tbase + (size_t)d * 64;
            float t0v = bf2f(trow[c]);
            float t1v = bf2f(trow[16 + c]);
            float t2v = bf2f(trow[32 + c]);
            float t3v = bf2f(trow[48 + c]);

            float v0 = 0.f, v1 = 0.f, v2 = 0.f, v3 = 0.f;
#pragma unroll
            for (int r = 0; r < 4; ++r) {
                int rr = 4 * g + r;
                bool in = (rr >= ii) && (rr < jj);
                v0 += in ? fmaxf(acc[0][r] + t0v, 0.f) : 0.f;
                v1 += in ? fmaxf(acc[1][r] + t1v, 0.f) : 0.f;
                v2 += in ? fmaxf(acc[2][r] + t2v, 0.f) : 0.f;
                v3 += in ? fmaxf(acc[3][r] + t3v, 0.f) : 0.f;
            }
            float sA0 = hi1 ? v0 : v2;
            float sA1 = hi1 ? v1 : v3;
            float rA0 = __shfl_xor(sA0, 32);
            float rA1 = __shfl_xor(sA1, 32);
            float w0 = (hi1 ? v2 : v0) + rA0;
            float w1 = (hi1 ? v3 : v1) + rA1;
            float sB = hi0 ? w0 : w1;
            float rB = __shfl_xor(sB, 16);
            float outv = (hi0 ? w1 : w0) + rB;

            atomicAdd(&abase[(size_t)d * 64 + lane], outv);
        }
    }
}

// ---------------- fused: upd (layer 0) + tdst for layer 1 ----------------
// After computing h_new tile, round-trip through wave-private swizzled LDS
// tile to re-shape C-layout -> A-frags, then next layer's W2 GEMM -> tdb.
__global__ __launch_bounds__(256) void k_upd_tdst_mfma(unsigned short* __restrict__ hb16,
                                                       const float* __restrict__ agg,
                                                       const float* __restrict__ uw,
                                                       const float* __restrict__ ub,
                                                       const float* __restrict__ mw2,
                                                       const float* __restrict__ mb2,
                                                       unsigned short* __restrict__ tdb) {
    __shared__ unsigned short stile[4][1024];
    int lane = threadIdx.x & 63;
    int g = lane >> 4, c = lane & 15;
    int wv = threadIdx.x >> 6;
    short8 bh[4][2], ba[4][2], bt[4][2];
#pragma unroll
    for (int nt = 0; nt < 4; ++nt)
#pragma unroll
        for (int ks = 0; ks < 2; ++ks)
#pragma unroll
            for (int j = 0; j < 8; ++j) {
                bh[nt][ks][j] = (short)f2bf(uw[(ks * 32 + g * 8 + j) * 64 + nt * 16 + c]);
                ba[nt][ks][j] = (short)f2bf(uw[(64 + ks * 32 + g * 8 + j) * 64 + nt * 16 + c]);
                bt[nt][ks][j] = (short)f2bf(mw2[(64 + ks * 32 + g * 8 + j) * 64 + nt * 16 + c]);
            }
    float ubv[4], mbv[4];
#pragma unroll
    for (int nt = 0; nt < 4; ++nt) { ubv[nt] = ub[nt * 16 + c]; mbv[nt] = mb2[nt * 16 + c]; }

    int wid = blockIdx.x * 4 + wv;
    int nw = gridDim.x * 4;
    f32x4 zero = {0.f, 0.f, 0.f, 0.f};
    int xr = (c & 7) << 3;
    for (int t = wid; t < NT_; t += nw) {
        unsigned short* ap = hb16 + ((size_t)t * 16 + c) * 64;
        short8 a0 = *(const short8*)(ap + g * 8);
        short8 a1 = *(const short8*)(ap + 32 + g * 8);

        const float* gp = agg + ((size_t)t * 16 + c) * 64;
        float4 q0 = *(const float4*)(gp + g * 8);
        float4 q1 = *(const float4*)(gp + g * 8 + 4);
        float4 q2 = *(const float4*)(gp + 32 + g * 8);
        float4 q3 = *(const float4*)(gp + 32 + g * 8 + 4);
        short8 s0, s1;
        s0[0] = (short)f2bf(q0.x); s0[1] = (short)f2bf(q0.y);
        s0[2] = (short)f2bf(q0.z); s0[3] = (short)f2bf(q0.w);
        s0[4] = (short)f2bf(q1.x); s0[5] = (short)f2bf(q1.y);
        s0[6] = (short)f2bf(q1.z); s0[7] = (short)f2bf(q1.w);
        s1[0] = (short)f2bf(q2.x); s1[1] = (short)f2bf(q2.y);
        s1[2] = (short)f2bf(q2.z); s1[3] = (short)f2bf(q2.w);
        s1[4] = (short)f2bf(q3.x); s1[5] = (short)f2bf(q3.y);
        s1[6] = (short)f2bf(q3.z); s1[7] = (short)f2bf(q3.w);

        f32x4 acc[4];
#pragma unroll
        for (int nt = 0; nt < 4; ++nt) {
            acc[nt] = __builtin_amdgcn_mfma_f32_16x16x32_bf16(a0, bh[nt][0], zero, 0, 0, 0);
            acc[nt] = __builtin_amdgcn_mfma_f32_16x16x32_bf16(a1, bh[nt][1], acc[nt], 0, 0, 0);
            acc[nt] = __builtin_amdgcn_mfma_f32_16x16x32_bf16(s0, ba[nt][0], acc[nt], 0, 0, 0);
            acc[nt] = __builtin_amdgcn_mfma_f32_16x16x32_bf16(s1, ba[nt][1], acc[nt], 0, 0, 0);
        }
#pragma unroll
        for (int r = 0; r < 4; ++r) {
            size_t row = (size_t)t * 16 + 4 * g + r;
            int lrow = 4 * g + r;
#pragma unroll
            for (int nt = 0; nt < 4; ++nt) {
                size_t idx = row * 64 + nt * 16 + c;
                float v = bf2f(hb16[idx]) + fmaxf(acc[nt][r] + ubv[nt], 0.f);
                unsigned short vb = f2bf(v);
                hb16[idx] = vb;
                int col = nt * 16 + c;
                stile[wv][lrow * 64 + (col ^ ((lrow & 7) << 3))] = vb;
            }
        }
        // wave-private LDS round-trip: read A-frags of h_new
        short8 na0 = *(const short8*)&stile[wv][c * 64 + ((g * 8) ^ xr)];
        short8 na1 = *(const short8*)&stile[wv][c * 64 + ((32 + g * 8) ^ xr)];
        f32x4 tacc[4];
#pragma unroll
        for (int nt = 0; nt < 4; ++nt) {
            tacc[nt] = __builtin_amdgcn_mfma_f32_16x16x32_bf16(na0, bt[nt][0], zero, 0, 0, 0);
            tacc[nt] = __builtin_amdgcn_mfma_f32_16x16x32_bf16(na1, bt[nt][1], tacc[nt], 0, 0, 0);
        }
#pragma unroll
        for (int r = 0; r < 4; ++r) {
            size_t row = (size_t)t * 16 + 4 * g + r;
#pragma unroll
            for (int nt = 0; nt < 4; ++nt)
                tdb[row * 64 + nt * 16 + c] = f2bf(tacc[nt][r] + mbv[nt]);
        }
    }
}

// ---------------- fused: upd (layer 1) + k/v projections ----------------
__global__ __launch_bounds__(256) void k_upd_kv_mfma(unsigned short* __restrict__ hb16,
                                                     const float* __restrict__ agg,
                                                     const float* __restrict__ uw,
                                                     const float* __restrict__ ub,
                                                     const float* __restrict__ wk,
                                                     const float* __restrict__ bk,
                                                     const float* __restrict__ wv,
                                                     const float* __restrict__ bv,
                                                     unsigned short* __restrict__ kb16,
                                                     unsigned short* __restrict__ vb16) {
    __shared__ unsigned short stile[4][1024];
    int lane = threadIdx.x & 63;
    int g = lane >> 4, c = lane & 15;
    int wvv = threadIdx.x >> 6;
    short8 bh[4][2], ba[4][2], bkf[4][2], bvf[4][2];
#pragma unroll
    for (int nt = 0; nt < 4; ++nt)
#pragma unroll
        for (int ks = 0; ks < 2; ++ks)
#pragma unroll
            for (int j = 0; j < 8; ++j) {
                bh[nt][ks][j]  = (short)f2bf(uw[(ks * 32 + g * 8 + j) * 64 + nt * 16 + c]);
                ba[nt][ks][j]  = (short)f2bf(uw[(64 + ks * 32 + g * 8 + j) * 64 + nt * 16 + c]);
                bkf[nt][ks][j] = (short)f2bf(wk[(ks * 32 + g * 8 + j) * 64 + nt * 16 + c]);
                bvf[nt][ks][j] = (short)f2bf(wv[(ks * 32 + g * 8 + j) * 64 + nt * 16 + c]);
            }
    float ubv[4], bkv[4], bvv[4];
#pragma unroll
    for (int nt = 0; nt < 4; ++nt) {
        ubv[nt] = ub[nt * 16 + c];
        bkv[nt] = bk[nt * 16 + c];
        bvv[nt] = bv[nt * 16 + c];
    }

    int wid = blockIdx.x * 4 + wvv;
    int nw = gridDim.x * 4;
    f32x4 zero = {0.f, 0.f, 0.f, 0.f};
    int xr = (c & 7) << 3;
    for (int t = wid; t < NT_; t += nw) {
        unsigned short* ap = hb16 + ((size_t)t * 16 + c) * 64;
        short8 a0 = *(const short8*)(ap + g * 8);
        short8 a1 = *(const short8*)(ap + 32 + g * 8);

        const float* gp = agg + ((size_t)t * 16 + c) * 64;
        float4 q0 = *(const float4*)(gp + g * 8);
        float4 q1 = *(const float4*)(gp + g * 8 + 4);
        float4 q2 = *(const float4*)(gp + 32 + g * 8);
        float4 q3 = *(const float4*)(gp + 32 + g * 8 + 4);
        short8 s0, s1;
        s0[0] = (short)f2bf(q0.x); s0[1] = (short)f2bf(q0.y);
        s0[2] = (short)f2bf(q0.z); s0[3] = (short)f2bf(q0.w);
        s0[4] = (short)f2bf(q1.x); s0[5] = (short)f2bf(q1.y);
        s0[6] = (short)f2bf(q1.z); s0[7] = (short)f2bf(q1.w);
        s1[0] = (short)f2bf(q2.x); s1[1] = (short)f2bf(q2.y);
        s1[2] = (short)f2bf(q2.z); s1[3] = (short)f2bf(q2.w);
        s1[4] = (short)f2bf(q3.x); s1[5] = (short)f2bf(q3.y);
        s1[6] = (short)f2bf(q3.z); s1[7] = (short)f2bf(q3.w);

        f32x4 acc[4];
#pragma unroll
        for (int nt = 0; nt < 4; ++nt) {
            acc[nt] = __builtin_amdgcn_mfma_f32_16x16x32_bf16(a0, bh[nt][0], zero, 0, 0, 0);
            acc[nt] = __builtin_amdgcn_mfma_f32_16x16x32_bf16(a1, bh[nt][1], acc[nt], 0, 0, 0);
            acc[nt] = __builtin_amdgcn_mfma_f32_16x16x32_bf16(s0, ba[nt][0], acc[nt], 0, 0, 0);
            acc[nt] = __builtin_amdgcn_mfma_f32_16x16x32_bf16(s1, ba[nt][1], acc[nt], 0, 0, 0);
        }
#pragma unroll
        for (int r = 0; r < 4; ++r) {
            size_t row = (size_t)t * 16 + 4 * g + r;
            int lrow = 4 * g + r;
#pragma unroll
            for (int nt = 0; nt < 4; ++nt) {
                size_t idx = row * 64 + nt * 16 + c;
                float v = bf2f(hb16[idx]) + fmaxf(acc[nt][r] + ubv[nt], 0.f);
                unsigned short vb = f2bf(v);
                hb16[idx] = vb;
                int col = nt * 16 + c;
                stile[wvv][lrow * 64 + (col ^ ((lrow & 7) << 3))] = vb;
            }
        }
        short8 na0 = *(const short8*)&stile[wvv][c * 64 + ((g * 8) ^ xr)];
        short8 na1 = *(const short8*)&stile[wvv][c * 64 + ((32 + g * 8) ^ xr)];
        f32x4 ak[4], av[4];
#pragma unroll
        for (int nt = 0; nt < 4; ++nt) {
            ak[nt] = __builtin_amdgcn_mfma_f32_16x16x32_bf16(na0, bkf[nt][0], zero, 0, 0, 0);
            ak[nt] = __builtin_amdgcn_mfma_f32_16x16x32_bf16(na1, bkf[nt][1], ak[nt], 0, 0, 0);
            av[nt] = __builtin_amdgcn_mfma_f32_16x16x32_bf16(na0, bvf[nt][0], zero, 0, 0, 0);
            av[nt] = __builtin_amdgcn_mfma_f32_16x16x32_bf16(na1, bvf[nt][1], av[nt], 0, 0, 0);
        }
#pragma unroll
        for (int r = 0; r < 4; ++r) {
            size_t row = (size_t)t * 16 + 4 * g + r;
#pragma unroll
            for (int nt = 0; nt < 4; ++nt) {
                kb16[row * 64 + nt * 16 + c] = f2bf(ak[nt][r] + bkv[nt]);
                vb16[row * 64 + nt * 16 + c] = f2bf(av[nt][r] + bvv[nt]);
            }
        }
    }
}

// ---------------- a = relu(ad @ w_ad + b_ad); q = a @ wq + bq ----------------
__global__ __launch_bounds__(64) void k_aq(const float* __restrict__ ad,
                                           const float* __restrict__ wad,
                                           const float* __restrict__ bad,
                                           const float* __restrict__ wq,
                                           const float* __restrict__ bq,
                                           float* __restrict__ a_out,
                                           float* __restrict__ q_out) {
    int b = blockIdx.x, t = threadIdx.x;
    __shared__ float sa[64];
    float acc = bad[t];
#pragma unroll
    for (int i = 0; i < 8; ++i) acc = fmaf(ad[b * 8 + i], wad[i * 64 + t], acc);
    float av = fmaxf(acc, 0.f);
    sa[t] = av;
    a_out[b * 64 + t] = av;
    __syncthreads();
    float qa = bq[t];
    for (int i = 0; i < 64; ++i) qa = fmaf(sa[i], wq[i * 64 + t], qa);
    q_out[b * 64 + t] = qa;
}

// ---------------- attention: chunked online softmax partials (bf16 k/v) ----------------
__global__ __launch_bounds__(256) void k_attn(const float* __restrict__ q,
                                              const unsigned short* __restrict__ kb16,
                                              const unsigned short* __restrict__ vb16,
                                              float* __restrict__ part) {
    int id = blockIdx.x;
    int ch = id % NCH;
    int bh = id / NCH;
    int b = bh / HEADS_, hd = bh % HEADS_;
    float qv[16];
#pragma unroll
    for (int d = 0; d < 16; ++d) qv[d] = q[b * 64 + hd * 16 + d];
    float m = -1e30f, s = 0.f, c[16];
#pragma unroll
    for (int d = 0; d < 16; ++d) c[d] = 0.f;
    int n0 = ch * CS;
    int n1 = n0 + CS; if (n1 > N_) n1 = N_;
    for (int n = n0 + threadIdx.x; n < n1; n += 256) {
        const short8* kr = (const short8*)(kb16 + ((size_t)b * N_ + n) * 64 + hd * 16);
        short8 k0 = kr[0], k1 = kr[1];
        float dot = 0.f;
#pragma unroll
        for (int d = 0; d < 8; ++d) {
            dot = fmaf(qv[d], bf2f((unsigned short)k0[d]), dot);
            dot = fmaf(qv[8 + d], bf2f((unsigned short)k1[d]), dot);
        }
        dot *= 0.25f;
        float nm = fmaxf(m, dot);
        float p = __expf(dot - nm);
        float cor = __expf(m - nm);
        const short8* vr = (const short8*)(vb16 + ((size_t)b * N_ + n) * 64 + hd * 16);
        short8 v0 = vr[0], v1 = vr[1];
        s = s * cor + p;
#pragma unroll
        for (int d = 0; d < 8; ++d) {
            c[d] = c[d] * cor + p * bf2f((unsigned short)v0[d]);
            c[8 + d] = c[8 + d] * cor + p * bf2f((unsigned short)v1[d]);
        }
        m = nm;
    }
#pragma unroll
    for (int o = 1; o < 64; o <<= 1) {
        float m2 = __shfl_xor(m, o);
        float s2 = __shfl_xor(s, o);
        float nm = fmaxf(m, m2);
        float w1 = __expf(m - nm), w2 = __expf(m2 - nm);
        s = s * w1 + s2 * w2;
#pragma unroll
        for (int d = 0; d < 16; ++d) {
            float c2 = __shfl_xor(c[d], o);
            c[d] = c[d] * w1 + c2 * w2;
        }
        m = nm;
    }
    __shared__ float red[4][18];
    int wv_ = threadIdx.x >> 6, lane = threadIdx.x & 63;
    if (lane == 0) {
        red[wv_][0] = m; red[wv_][1] = s;
#pragma unroll
        for (int d = 0; d < 16; ++d) red[wv_][2 + d] = c[d];
    }
    __syncthreads();
    if (threadIdx.x == 0) {
        float gm = red[0][0];
        for (int w = 1; w < 4; ++w) gm = fmaxf(gm, red[w][0]);
        float gs = 0.f, gc[16];
#pragma unroll
        for (int d = 0; d < 16; ++d) gc[d] = 0.f;
        for (int w = 0; w < 4; ++w) {
            float ww = __expf(red[w][0] - gm);
            gs += red[w][1] * ww;
#pragma unroll
            for (int d = 0; d < 16; ++d) gc[d] += red[w][2 + d] * ww;
        }
        float* p = part + (size_t)id * 18;
        p[0] = gm; p[1] = gs;
#pragma unroll
        for (int d = 0; d < 16; ++d) p[2 + d] = gc[d];
    }
}

__global__ __launch_bounds__(64) void k_comb(const float* __restrict__ part,
                                             float* __restrict__ ctx) {
    int bh = blockIdx.x, t = threadIdx.x;
    int b = bh / HEADS_, hd = bh % HEADS_;
    const float* p = part + ((size_t)bh * NCH + t) * 18;
    float m = p[0], s = p[1], c[16];
#pragma unroll
    for (int d = 0; d < 16; ++d) c[d] = p[2 + d];
    float gm = m;
#pragma unroll
    for (int o = 1; o < 64; o <<= 1) gm = fmaxf(gm, __shfl_xor(gm, o));
    float w = __expf(m - gm);
    float sw = s * w;
#pragma unroll
    for (int o = 1; o < 64; o <<= 1) sw += __shfl_xor(sw, o);
    float cg[16];
#pragma unroll
    for (int d = 0; d < 16; ++d) {
        float x = c[d] * w;
#pragma unroll
        for (int o = 1; o < 64; o <<= 1) x += __shfl_xor(x, o);
        cg[d] = x;
    }
    if (t == 0) {
#pragma unroll
        for (int d = 0; d < 16; ++d) ctx[b * 64 + hd * 16 + d] = cg[d] / sw;
    }
}

// ---------------- g = LN(a + ctx@wo + bo); wcomb = g/8 + policy_w ----------------
__global__ __launch_bounds__(64) void k_g(const float* __restrict__ a,
                                          const float* __restrict__ ctx,
                                          const float* __restrict__ wo,
                                          const float* __restrict__ bo,
                                          const float* __restrict__ lng,
                                          const float* __restrict__ lnb,
                                          const float* __restrict__ pw,
                                          float* __restrict__ wcomb) {
    int b = blockIdx.x, t = threadIdx.x;
    __shared__ float sc[64];
    sc[t] = ctx[b * 64 + t];
    __syncthreads();
    float o = bo[t];
    for (int i = 0; i < 64; ++i) o = fmaf(sc[i], wo[i * 64 + t], o);
    float y = a[b * 64 + t] + o;
    float mu = y;
#pragma unroll
    for (int oo = 1; oo < 64; oo <<= 1) mu += __shfl_xor(mu, oo);
    mu *= (1.f / 64.f);
    float d = y - mu;
    float var = d * d;
#pragma unroll
    for (int oo = 1; oo < 64; oo <<= 1) var += __shfl_xor(var, oo);
    var *= (1.f / 64.f);
    float g = d * rsqrtf(var + 1e-5f) * lng[t] + lnb[t];
    wcomb[b * 64 + t] = g * 0.125f + pw[t];
}

// ---------------- logits (bf16 h) ----------------
__global__ __launch_bounds__(256) void k_final(const unsigned short* __restrict__ hb16,
                                               const float* __restrict__ wcomb,
                                               const float* __restrict__ pb,
                                               const void* __restrict__ mask,
                                               const int* __restrict__ flagp,
                                               float* __restrict__ out) {
    int idx = blockIdx.x * 256 + threadIdx.x;
    if (idx >= B_ * N_) return;
    int b = idx / N_;
    const float* wr = wcomb + b * 64;
    const short8* hr = (const short8*)(hb16 + (size_t)idx * 64);
    float acc = pb[0];
#pragma unroll
    for (int i = 0; i < 8; ++i) {
        short8 hv = hr[i];
#pragma unroll
        for (int j = 0; j < 8; ++j)
            acc = fmaf(bf2f((unsigned short)hv[j]), wr[i * 8 + j], acc);
    }
    int flag = *flagp;
    bool mv;
    if (flag == 1)      mv = ((const int*)mask)[idx] != 0;
    else if (flag == 2) mv = ((const float*)mask)[idx] != 0.f;
    else                mv = ((const unsigned char*)mask)[idx] != 0;
    out[idx] = mv ? acc : -1.0e9f;
}

extern "C" void kernel_launch(void* const* d_in, const int* in_sizes, int n_in,
                              void* d_out, int out_size, void* d_ws, size_t ws_size,
                              hipStream_t stream) {
    const float* gn   = (const float*)d_in[0];
    const float* ad   = (const float*)d_in[1];
    const float* wnod = (const float*)d_in[2];
    const float* bnod = (const float*)d_in[3];
    const float* msgw = (const float*)d_in[4];
    const float* msgb = (const float*)d_in[5];
    const float* updw = (const float*)d_in[6];
    const float* updb = (const float*)d_in[7];
    const float* wad  = (const float*)d_in[8];
    const float* bad  = (const float*)d_in[9];
    const float* wq   = (const float*)d_in[10];
    const float* bq   = (const float*)d_in[11];
    const float* wk   = (const float*)d_in[12];
    const float* bk   = (const float*)d_in[13];
    const float* wv   = (const float*)d_in[14];
    const float* bv   = (const float*)d_in[15];
    const float* wo   = (const float*)d_in[16];
    const float* bo   = (const float*)d_in[17];
    const float* lng  = (const float*)d_in[18];
    const float* lnb  = (const float*)d_in[19];
    const float* pw   = (const float*)d_in[20];
    const float* pb   = (const float*)d_in[21];
    const int*   links= (const int*)d_in[22];
    const void*  mask = d_in[23];

    char* ws = (char*)d_ws;
    unsigned short* tdb  = (unsigned short*)(ws + OFF_TDB);
    unsigned short* kb16 = (unsigned short*)(ws + OFF_TDB);
    float* agg  = (float*)(ws + OFF_AGG);
    unsigned* ebuck = (unsigned*)(ws + OFF_EBUCK);
    unsigned* epair = (unsigned*)(ws + OFF_EPAIR);
    unsigned short* hb16 = (unsigned short*)(ws + OFF_HB16);
    float* avec = (float*)(ws + OFF_AVEC);
    float* qvec = (float*)(ws + OFF_Q);
    float* ctx  = (float*)(ws + OFF_CTX);
    float* wcmb = (float*)(ws + OFF_WCMB);
    int*   flag = (int*)(ws + OFF_FLAG);
    float* part = (float*)(ws + OFF_PART);
    int*   tails= (int*)(ws + OFF_TAILS);
    int*   wbase= (int*)(ws + OFF_WBASE);
    unsigned short* vb16 = (unsigned short*)(ws + OFF_VB16);
    float* out  = (float*)d_out;

    hipMemsetAsync(tails, 0, (size_t)B_ * NWIN * TPAD * 4, stream);
    k_maskdetect<<<1, 1, 0, stream>>>((const unsigned int*)mask, flag);
    k_embed_bucket<<<6248, 256, 0, stream>>>(gn, wnod, bnod, hb16, links, tails, ebuck);
    k_scan_tails<<<B_, 1024, 0, stream>>>(tails, wbase);
    k_sortwin<<<5000, 256, 0, stream>>>(ebuck, tails, wbase, epair);

    // layer 0
    k_tdst_mfma<<<512, 256, 0, stream>>>(hb16, msgw, msgb, tdb);
    hipMemsetAsync(agg, 0, SZ_AGG, stream);
    k_edge_mfma<<<5000, 256, 0, stream>>>(hb16, tdb, epair, msgw, agg);
    k_upd_tdst_mfma<<<512, 256, 0, stream>>>(hb16, agg, updw, updb,
                                             msgw + (size_t)128 * 64, msgb + 64, tdb);
    // layer 1
    hipMemsetAsync(agg, 0, SZ_AGG, stream);
    k_edge_mfma<<<5000, 256, 0, stream>>>(hb16, tdb, epair, msgw + (size_t)128 * 64, agg);
    k_upd_kv_mfma<<<512, 256, 0, stream>>>(hb16, agg, updw + (size_t)128 * 64, updb + 64,
                                           wk, bk, wv, bv, kb16, vb16);

    k_aq<<<B_, 64, 0, stream>>>(ad, wad, bad, wq, bq, avec, qvec);
    k_attn<<<B_ * HEADS_ * NCH, 256, 0, stream>>>(qvec, kb16, vb16, part);
    k_comb<<<B_ * HEADS_, 64, 0, stream>>>(part, ctx);
    k_g<<<B_, 64, 0, stream>>>(avec, ctx, wo, bo, lng, lnb, pw, wcmb);
    k_final<<<(B_ * N_ + 255) / 256, 256, 0, stream>>>(hb16, wcmb, pb, mask, flag, out);
}

// Round 17
// 257.143 us; speedup vs baseline: 1.2125x; 1.0581x over previous
//
#include <hip/hip_runtime.h>
#include <hip/hip_bf16.h>
#include <math.h>

// Problem constants
constexpr int B_ = 4;
constexpr int N_ = 20000;
constexpr int E_ = 320000;
constexpr int HEADS_ = 4;
constexpr int NCH = 64;                       // attention chunks per (b,head)
constexpr int CS = (N_ + NCH - 1) / NCH;      // 313
constexpr int NT_ = (B_ * N_) / 16;           // 5000 node tiles
constexpr int NWIN = 1250;                    // 16-dst windows per batch
constexpr int HWIN = 625;                     // windows per XCD half
constexpr int WCAP = 512;                     // bucket capacity (mean 256, +16 sigma)
constexpr int TPAD = 16;                      // tails padding -> 1 counter/line

typedef __attribute__((ext_vector_type(8))) short short8;   // 8 bf16
typedef __attribute__((ext_vector_type(4))) float f32x4;

// Workspace layout (bytes). ~67 MB.
constexpr size_t SZ_TDB   = (size_t)B_ * N_ * 64 * 2;     // 10,240,000
constexpr size_t SZ_AGG   = (size_t)B_ * N_ * 64 * 4;     // 20,480,000
constexpr size_t SZ_EBUCK = (size_t)B_ * NWIN * WCAP * 4; // 10,240,000 (packed int)
constexpr size_t SZ_EPAIR = (size_t)B_ * E_ * 4;          // 5,120,000 (packed int)
constexpr size_t OFF_TDB  = 0;                            // tdb bf16 (transposed); later kb16
constexpr size_t OFF_AGG  = SZ_TDB;                       // agg f32
constexpr size_t OFF_EBUCK= OFF_AGG + SZ_AGG;
constexpr size_t OFF_EPAIR= OFF_EBUCK + SZ_EBUCK;
constexpr size_t OFF_HB16 = OFF_EPAIR + SZ_EPAIR;
constexpr size_t OFF_AVEC = OFF_HB16 + SZ_TDB;
constexpr size_t OFF_Q    = OFF_AVEC + 1024;
constexpr size_t OFF_CTX  = OFF_Q + 1024;
constexpr size_t OFF_WCMB = OFF_CTX + 1024;
constexpr size_t OFF_FLAG = OFF_WCMB + 1024;
constexpr size_t OFF_PART = OFF_FLAG + 64;                // 1024*18 f partials
constexpr size_t OFF_TAILS= OFF_PART + 1024 * 18 * 4 + 64;   // B*NWIN*TPAD ints
constexpr size_t OFF_WBASE= OFF_TAILS + (size_t)B_ * NWIN * TPAD * 4; // B*NWIN ints
constexpr size_t OFF_VB16 = OFF_WBASE + (size_t)B_ * NWIN * 4 + 64;   // v bf16 (own region)

static __device__ __forceinline__ unsigned short f2bf(float f) {
    union { float f; unsigned u; } v; v.f = f;
    unsigned r = v.u + 0x7fffu + ((v.u >> 16) & 1u);
    return (unsigned short)(r >> 16);
}
static __device__ __forceinline__ float bf2f(unsigned short u) {
    union { unsigned u; float f; } v; v.u = (unsigned)u << 16;
    return v.f;
}

// ---------------- mask dtype detection ----------------
__global__ void k_maskdetect(const unsigned int* __restrict__ m, int* __restrict__ flag) {
    if (blockIdx.x == 0 && threadIdx.x == 0) {
        bool alli = true, allf = true;
        for (int i = 0; i < 256; ++i) {
            unsigned v = m[i];
            alli = alli && (v <= 1u);
            allf = allf && (v == 0u || v == 0x3f800000u);
        }
        *flag = alli ? 1 : (allf ? 2 : 0);
    }
}

// ---------------- fused: embed (1/5 of groups) + XCD-partitioned bucket build ----------------
__global__ __launch_bounds__(256) void k_embed_bucket(const float* __restrict__ gn,
                                                      const float* __restrict__ wnod,
                                                      const float* __restrict__ bias,
                                                      unsigned short* __restrict__ hb16,
                                                      const int* __restrict__ links,
                                                      int* __restrict__ tails,
                                                      unsigned* __restrict__ ebuck) {
    int i = blockIdx.x;
    int g = i >> 3, r = i & 7;
    if (g % 5 == 4) {
        int eb = (g / 5) * 8 + r;             // 0..1247
        int lane = threadIdx.x & 63;
        float wc[16];
#pragma unroll
        for (int k = 0; k < 16; ++k) wc[k] = wnod[k * 64 + lane];
        float bb = bias[lane];
        int gw = eb * 4 + (threadIdx.x >> 6);
        for (int node = gw; node < B_ * N_; node += 1248 * 4) {
            const float* rr = gn + (size_t)node * 16;
            float a0 = 0.f, a1 = 0.f, a2 = 0.f, a3 = 0.f;
#pragma unroll
            for (int k = 0; k < 16; k += 4) {
                a0 = fmaf(rr[k + 0], wc[k + 0], a0);
                a1 = fmaf(rr[k + 1], wc[k + 1], a1);
                a2 = fmaf(rr[k + 2], wc[k + 2], a2);
                a3 = fmaf(rr[k + 3], wc[k + 3], a3);
            }
            float v = fmaxf(bb + ((a0 + a1) + (a2 + a3)), 0.f);
            hb16[(size_t)node * 64 + lane] = f2bf(v);
        }
    } else {
        int og = g - (g + 1) / 5;             // 0..624
        int b = r >> 1;
        int half = r & 1;
        int e0 = og * 512 + threadIdx.x;
        const int* lsrc = links + (size_t)b * 2 * E_;
#pragma unroll
        for (int ch = 0; ch < 2; ++ch) {
            int e = e0 + ch * 256;
            unsigned src = (unsigned)lsrc[e];
            unsigned dst = (unsigned)lsrc[E_ + e];
            int w = dst >> 4;                 // 0..1249
            if ((w >= HWIN) == (half == 1)) {
                int slot = atomicAdd(&tails[(b * NWIN + w) * TPAD], 1);
                if (slot < WCAP)
                    ebuck[(size_t)(b * NWIN + w) * WCAP + slot] = (dst << 16) | src;
            }
        }
    }
}

// ---------------- exclusive scan of (padded) window tails -> epair bases ----------------
__global__ __launch_bounds__(1024) void k_scan_tails(const int* __restrict__ tails,
                                                     int* __restrict__ wbase) {
    __shared__ int wsum[16];
    __shared__ int sbase;
    int b = blockIdx.x, t = threadIdx.x;
    int lane = t & 63, wv = t >> 6;
    if (t == 0) sbase = 0;
    __syncthreads();
    for (int base = 0; base < NWIN; base += 1024) {
        int idx = base + t;
        int c = 0;
        if (idx < NWIN) { c = tails[(b * NWIN + idx) * TPAD]; if (c > WCAP) c = WCAP; }
        int x = c;
#pragma unroll
        for (int o = 1; o < 64; o <<= 1) {
            int y = __shfl_up(x, o);
            if (lane >= o) x += y;
        }
        if (lane == 63) wsum[wv] = x;
        __syncthreads();
        if (wv == 0) {
            int s = (lane < 16) ? wsum[lane] : 0;
#pragma unroll
            for (int o = 1; o < 16; o <<= 1) {
                int y = __shfl_up(s, o);
                if (lane >= o) s += y;
            }
            if (lane < 16) wsum[lane] = s;
        }
        __syncthreads();
        int wpre = (wv > 0) ? wsum[wv - 1] : 0;
        int incl = x + wpre + sbase;
        if (idx < NWIN) wbase[b * NWIN + idx] = incl - c;   // exclusive
        __syncthreads();
        if (t == 1023) sbase = incl;
        __syncthreads();
    }
}

// ---------------- per-window 16-bin counting sort (LDS) -> sorted packed epair ----------------
__global__ __launch_bounds__(256) void k_sortwin(const unsigned* __restrict__ ebuck,
                                                 const int* __restrict__ tails,
                                                 const int* __restrict__ wbase,
                                                 unsigned* __restrict__ epair) {
    __shared__ int hist[16], hbase[16];
    __shared__ unsigned sbuf[WCAP];
    int i = blockIdx.x;                   // 0..4999
    int r = i & 7;
    int b = r >> 1;
    int w = (i >> 3) + HWIN * (r & 1);    // XCD-matched
    int cntw = tails[(b * NWIN + w) * TPAD];
    if (cntw > WCAP) cntw = WCAP;
    if (threadIdx.x < 16) hist[threadIdx.x] = 0;
    __syncthreads();
    const unsigned* src = ebuck + (size_t)(b * NWIN + w) * WCAP;
    int idx0 = threadIdx.x, idx1 = threadIdx.x + 256;
    bool v0 = idx0 < cntw, v1 = idx1 < cntw;
    unsigned e0 = 0, e1 = 0;
    if (v0) { e0 = src[idx0]; atomicAdd(&hist[(e0 >> 16) & 15], 1); }
    if (v1) { e1 = src[idx1]; atomicAdd(&hist[(e1 >> 16) & 15], 1); }
    __syncthreads();
    if (threadIdx.x == 0) {
        int run = 0;
#pragma unroll
        for (int p = 0; p < 16; ++p) { hbase[p] = run; run += hist[p]; }
    }
    __syncthreads();
    if (threadIdx.x < 16) hist[threadIdx.x] = 0;
    __syncthreads();
    if (v0) { int bn = (e0 >> 16) & 15; sbuf[hbase[bn] + atomicAdd(&hist[bn], 1)] = e0; }
    if (v1) { int bn = (e1 >> 16) & 15; sbuf[hbase[bn] + atomicAdd(&hist[bn], 1)] = e1; }
    __syncthreads();
    int gb = wbase[b * NWIN + w];
    unsigned* dst = epair + (size_t)b * E_ + gb;
    for (int idx = threadIdx.x; idx < cntw; idx += 256) dst[idx] = sbuf[idx];
}

// ---------------- tdst (transposed layout) = W2^T h + msg_b, layer 0 ----------------
// tdb[node*64 + c*4 + nt] so edge kernel loads one 8B chunk per (lane,row).
__global__ __launch_bounds__(256) void k_tdst_mfma(const unsigned short* __restrict__ hb16,
                                                   const float* __restrict__ mw,
                                                   const float* __restrict__ mb,
                                                   unsigned short* __restrict__ tdb) {
    int lane = threadIdx.x & 63;
    int g = lane >> 4, c = lane & 15;
    short8 bf[4][2];
#pragma unroll
    for (int nt = 0; nt < 4; ++nt)
#pragma unroll
        for (int ks = 0; ks < 2; ++ks)
#pragma unroll
            for (int j = 0; j < 8; ++j)
                bf[nt][ks][j] = (short)f2bf(mw[(64 + ks * 32 + g * 8 + j) * 64 + nt * 16 + c]);
    float mbv[4];
#pragma unroll
    for (int nt = 0; nt < 4; ++nt) mbv[nt] = mb[nt * 16 + c];

    int wid = blockIdx.x * 4 + (threadIdx.x >> 6);
    int nw = gridDim.x * 4;
    f32x4 zero = {0.f, 0.f, 0.f, 0.f};
    for (int t = wid; t < NT_; t += nw) {
        const unsigned short* ap = hb16 + ((size_t)t * 16 + c) * 64;
        short8 a0 = *(const short8*)(ap + g * 8);
        short8 a1 = *(const short8*)(ap + 32 + g * 8);
        f32x4 acc[4];
#pragma unroll
        for (int nt = 0; nt < 4; ++nt) {
            acc[nt] = __builtin_amdgcn_mfma_f32_16x16x32_bf16(a0, bf[nt][0], zero, 0, 0, 0);
            acc[nt] = __builtin_amdgcn_mfma_f32_16x16x32_bf16(a1, bf[nt][1], acc[nt], 0, 0, 0);
        }
#pragma unroll
        for (int r = 0; r < 4; ++r) {
            size_t row = (size_t)t * 16 + 4 * g + r;
            unsigned long long pk =
                (unsigned long long)f2bf(acc[0][r] + mbv[0])
              | ((unsigned long long)f2bf(acc[1][r] + mbv[1]) << 16)
              | ((unsigned long long)f2bf(acc[2][r] + mbv[2]) << 32)
              | ((unsigned long long)f2bf(acc[3][r] + mbv[3]) << 48);
            *(unsigned long long*)(tdb + row * 64 + c * 4) = pk;
        }
    }
}

// ---------------- fused MFMA edge kernel (XCD-pinned; per-row 8B tdb) ----------------
__global__ __launch_bounds__(256) void k_edge_mfma(const unsigned short* __restrict__ hb16,
                                                   const unsigned short* __restrict__ tdb,
                                                   const unsigned* __restrict__ epair,
                                                   const float* __restrict__ mw,
                                                   float* __restrict__ agg) {
    int lane = threadIdx.x & 63;
    int g = lane >> 4, c = lane & 15;
    short8 bf[4][2];
#pragma unroll
    for (int nt = 0; nt < 4; ++nt)
#pragma unroll
        for (int ks = 0; ks < 2; ++ks)
#pragma unroll
            for (int j = 0; j < 8; ++j)
                bf[nt][ks][j] = (short)f2bf(mw[(ks * 32 + g * 8 + j) * 64 + nt * 16 + c]);

    int i = blockIdx.x;                       // 0..4999
    int b = (i & 7) >> 1;                     // batch (XCD-pinned pair)
    int o = ((i >> 3) << 1) | (i & 1);        // per-batch block ordinal 0..1249
    int w = threadIdx.x >> 6;
    const unsigned* pp = epair + (size_t)b * E_;
    const unsigned short* hbase = hb16 + (size_t)(b * N_) * 64;
    const unsigned short* tbase = tdb + (size_t)(b * N_) * 64;
    float* abase = agg + (size_t)(b * N_) * 64;

    bool hi1 = (lane & 32) != 0;
    bool hi0 = (lane & 16) != 0;

    unsigned pr[4];
#pragma unroll
    for (int k = 0; k < 4; ++k) {
        int t0 = (o * 4 + w) + k * 5000;
        pr[k] = pp[t0 * 16 + c];
    }
    short8 a0[4], a1[4];
#pragma unroll
    for (int k = 0; k < 4; ++k) {
        const unsigned short* hrow = hbase + (size_t)(pr[k] & 0xFFFFu) * 64;
        a0[k] = *(const short8*)(hrow + g * 8);
        a1[k] = *(const short8*)(hrow + 32 + g * 8);
    }

    f32x4 zero = {0.f, 0.f, 0.f, 0.f};
#pragma unroll
    for (int k = 0; k < 4; ++k) {
        int dval = (int)(pr[k] >> 16);
        f32x4 acc[4];
#pragma unroll
        for (int nt = 0; nt < 4; ++nt) {
            acc[nt] = __builtin_amdgcn_mfma_f32_16x16x32_bf16(a0[k], bf[nt][0], zero, 0, 0, 0);
            acc[nt] = __builtin_amdgcn_mfma_f32_16x16x32_bf16(a1[k], bf[nt][1], acc[nt], 0, 0, 0);
        }

        // per-row tdb (transposed): one 8B load per row; relu once per tile
        float val[4][4]; // [nt][r]
#pragma unroll
        for (int r = 0; r < 4; ++r) {
            int dr = __shfl(dval, 4 * g + r);
            unsigned long long tv = *(const unsigned long long*)(tbase + (size_t)dr * 64 + c * 4);
            val[0][r] = fmaxf(acc[0][r] + bf2f((unsigned short)(tv       & 0xFFFFu)), 0.f);
            val[1][r] = fmaxf(acc[1][r] + bf2f((unsigned short)((tv >> 16) & 0xFFFFu)), 0.f);
            val[2][r] = fmaxf(acc[2][r] + bf2f((unsigned short)((tv >> 32) & 0xFFFFu)), 0.f);
            val[3][r] = fmaxf(acc[3][r] + bf2f((unsigned short)((tv >> 48) & 0xFFFFu)), 0.f);
        }

        int prev = __shfl(dval, (lane + 63) & 63);
        bool head = (c == 0) || (dval != prev);
        unsigned long long bal = __ballot(head);
        unsigned m16 = (unsigned)(bal & 0xFFFFu);

        while (m16) {
            int ii = __ffs(m16) - 1;
            unsigned rest = m16 & (m16 - 1);
            int jj = rest ? (__ffs(rest) - 1) : 16;
            m16 = rest;
            int d = __shfl(dval, ii);

            float v0 = 0.f, v1 = 0.f, v2 = 0.f, v3 = 0.f;
#pragma unroll
            for (int r = 0; r < 4; ++r) {
                int rr = 4 * g + r;
                bool in = (rr >= ii) && (rr < jj);
                v0 += in ? val[0][r] : 0.f;
                v1 += in ? val[1][r] : 0.f;
                v2 += in ? val[2][r] : 0.f;
                v3 += in ? val[3][r] : 0.f;
            }
            float sA0 = hi1 ? v0 : v2;
            float sA1 = hi1 ? v1 : v3;
            float rA0 = __shfl_xor(sA0, 32);
            float rA1 = __shfl_xor(sA1, 32);
            float w0 = (hi1 ? v2 : v0) + rA0;
            float w1 = (hi1 ? v3 : v1) + rA1;
            float sB = hi0 ? w0 : w1;
            float rB = __shfl_xor(sB, 16);
            float outv = (hi0 ? w1 : w0) + rB;

            atomicAdd(&abase[(size_t)d * 64 + lane], outv);
        }
    }
}

// ---------------- fused: upd (layer 0) + tdst for layer 1 (transposed out) ----------------
__global__ __launch_bounds__(256) void k_upd_tdst_mfma(unsigned short* __restrict__ hb16,
                                                       const float* __restrict__ agg,
                                                       const float* __restrict__ uw,
                                                       const float* __restrict__ ub,
                                                       const float* __restrict__ mw2,
                                                       const float* __restrict__ mb2,
                                                       unsigned short* __restrict__ tdb) {
    __shared__ unsigned short stile[4][1024];
    int lane = threadIdx.x & 63;
    int g = lane >> 4, c = lane & 15;
    int wv = threadIdx.x >> 6;
    short8 bh[4][2], ba[4][2], bt[4][2];
#pragma unroll
    for (int nt = 0; nt < 4; ++nt)
#pragma unroll
        for (int ks = 0; ks < 2; ++ks)
#pragma unroll
            for (int j = 0; j < 8; ++j) {
                bh[nt][ks][j] = (short)f2bf(uw[(ks * 32 + g * 8 + j) * 64 + nt * 16 + c]);
                ba[nt][ks][j] = (short)f2bf(uw[(64 + ks * 32 + g * 8 + j) * 64 + nt * 16 + c]);
                bt[nt][ks][j] = (short)f2bf(mw2[(64 + ks * 32 + g * 8 + j) * 64 + nt * 16 + c]);
            }
    float ubv[4], mbv[4];
#pragma unroll
    for (int nt = 0; nt < 4; ++nt) { ubv[nt] = ub[nt * 16 + c]; mbv[nt] = mb2[nt * 16 + c]; }

    int wid = blockIdx.x * 4 + wv;
    int nw = gridDim.x * 4;
    f32x4 zero = {0.f, 0.f, 0.f, 0.f};
    int xr = (c & 7) << 3;
    for (int t = wid; t < NT_; t += nw) {
        unsigned short* ap = hb16 + ((size_t)t * 16 + c) * 64;
        short8 a0 = *(const short8*)(ap + g * 8);
        short8 a1 = *(const short8*)(ap + 32 + g * 8);

        const float* gp = agg + ((size_t)t * 16 + c) * 64;
        float4 q0 = *(const float4*)(gp + g * 8);
        float4 q1 = *(const float4*)(gp + g * 8 + 4);
        float4 q2 = *(const float4*)(gp + 32 + g * 8);
        float4 q3 = *(const float4*)(gp + 32 + g * 8 + 4);
        short8 s0, s1;
        s0[0] = (short)f2bf(q0.x); s0[1] = (short)f2bf(q0.y);
        s0[2] = (short)f2bf(q0.z); s0[3] = (short)f2bf(q0.w);
        s0[4] = (short)f2bf(q1.x); s0[5] = (short)f2bf(q1.y);
        s0[6] = (short)f2bf(q1.z); s0[7] = (short)f2bf(q1.w);
        s1[0] = (short)f2bf(q2.x); s1[1] = (short)f2bf(q2.y);
        s1[2] = (short)f2bf(q2.z); s1[3] = (short)f2bf(q2.w);
        s1[4] = (short)f2bf(q3.x); s1[5] = (short)f2bf(q3.y);
        s1[6] = (short)f2bf(q3.z); s1[7] = (short)f2bf(q3.w);

        f32x4 acc[4];
#pragma unroll
        for (int nt = 0; nt < 4; ++nt) {
            acc[nt] = __builtin_amdgcn_mfma_f32_16x16x32_bf16(a0, bh[nt][0], zero, 0, 0, 0);
            acc[nt] = __builtin_amdgcn_mfma_f32_16x16x32_bf16(a1, bh[nt][1], acc[nt], 0, 0, 0);
            acc[nt] = __builtin_amdgcn_mfma_f32_16x16x32_bf16(s0, ba[nt][0], acc[nt], 0, 0, 0);
            acc[nt] = __builtin_amdgcn_mfma_f32_16x16x32_bf16(s1, ba[nt][1], acc[nt], 0, 0, 0);
        }
#pragma unroll
        for (int r = 0; r < 4; ++r) {
            size_t row = (size_t)t * 16 + 4 * g + r;
            int lrow = 4 * g + r;
#pragma unroll
            for (int nt = 0; nt < 4; ++nt) {
                size_t idx = row * 64 + nt * 16 + c;
                float v = bf2f(hb16[idx]) + fmaxf(acc[nt][r] + ubv[nt], 0.f);
                unsigned short vb = f2bf(v);
                hb16[idx] = vb;
                int col = nt * 16 + c;
                stile[wv][lrow * 64 + (col ^ ((lrow & 7) << 3))] = vb;
            }
        }
        // wave-private LDS round-trip: read A-frags of h_new
        short8 na0 = *(const short8*)&stile[wv][c * 64 + ((g * 8) ^ xr)];
        short8 na1 = *(const short8*)&stile[wv][c * 64 + ((32 + g * 8) ^ xr)];
        f32x4 tacc[4];
#pragma unroll
        for (int nt = 0; nt < 4; ++nt) {
            tacc[nt] = __builtin_amdgcn_mfma_f32_16x16x32_bf16(na0, bt[nt][0], zero, 0, 0, 0);
            tacc[nt] = __builtin_amdgcn_mfma_f32_16x16x32_bf16(na1, bt[nt][1], tacc[nt], 0, 0, 0);
        }
#pragma unroll
        for (int r = 0; r < 4; ++r) {
            size_t row = (size_t)t * 16 + 4 * g + r;
            unsigned long long pk =
                (unsigned long long)f2bf(tacc[0][r] + mbv[0])
              | ((unsigned long long)f2bf(tacc[1][r] + mbv[1]) << 16)
              | ((unsigned long long)f2bf(tacc[2][r] + mbv[2]) << 32)
              | ((unsigned long long)f2bf(tacc[3][r] + mbv[3]) << 48);
            *(unsigned long long*)(tdb + row * 64 + c * 4) = pk;
        }
    }
}

// ---------------- fused: upd (layer 1) + k/v projections ----------------
__global__ __launch_bounds__(256) void k_upd_kv_mfma(unsigned short* __restrict__ hb16,
                                                     const float* __restrict__ agg,
                                                     const float* __restrict__ uw,
                                                     const float* __restrict__ ub,
                                                     const float* __restrict__ wk,
                                                     const float* __restrict__ bk,
                                                     const float* __restrict__ wv,
                                                     const float* __restrict__ bv,
                                                     unsigned short* __restrict__ kb16,
                                                     unsigned short* __restrict__ vb16) {
    __shared__ unsigned short stile[4][1024];
    int lane = threadIdx.x & 63;
    int g = lane >> 4, c = lane & 15;
    int wvv = threadIdx.x >> 6;
    short8 bh[4][2], ba[4][2], bkf[4][2], bvf[4][2];
#pragma unroll
    for (int nt = 0; nt < 4; ++nt)
#pragma unroll
        for (int ks = 0; ks < 2; ++ks)
#pragma unroll
            for (int j = 0; j < 8; ++j) {
                bh[nt][ks][j]  = (short)f2bf(uw[(ks * 32 + g * 8 + j) * 64 + nt * 16 + c]);
                ba[nt][ks][j]  = (short)f2bf(uw[(64 + ks * 32 + g * 8 + j) * 64 + nt * 16 + c]);
                bkf[nt][ks][j] = (short)f2bf(wk[(ks * 32 + g * 8 + j) * 64 + nt * 16 + c]);
                bvf[nt][ks][j] = (short)f2bf(wv[(ks * 32 + g * 8 + j) * 64 + nt * 16 + c]);
            }
    float ubv[4], bkv[4], bvv[4];
#pragma unroll
    for (int nt = 0; nt < 4; ++nt) {
        ubv[nt] = ub[nt * 16 + c];
        bkv[nt] = bk[nt * 16 + c];
        bvv[nt] = bv[nt * 16 + c];
    }

    int wid = blockIdx.x * 4 + wvv;
    int nw = gridDim.x * 4;
    f32x4 zero = {0.f, 0.f, 0.f, 0.f};
    int xr = (c & 7) << 3;
    for (int t = wid; t < NT_; t += nw) {
        unsigned short* ap = hb16 + ((size_t)t * 16 + c) * 64;
        short8 a0 = *(const short8*)(ap + g * 8);
        short8 a1 = *(const short8*)(ap + 32 + g * 8);

        const float* gp = agg + ((size_t)t * 16 + c) * 64;
        float4 q0 = *(const float4*)(gp + g * 8);
        float4 q1 = *(const float4*)(gp + g * 8 + 4);
        float4 q2 = *(const float4*)(gp + 32 + g * 8);
        float4 q3 = *(const float4*)(gp + 32 + g * 8 + 4);
        short8 s0, s1;
        s0[0] = (short)f2bf(q0.x); s0[1] = (short)f2bf(q0.y);
        s0[2] = (short)f2bf(q0.z); s0[3] = (short)f2bf(q0.w);
        s0[4] = (short)f2bf(q1.x); s0[5] = (short)f2bf(q1.y);
        s0[6] = (short)f2bf(q1.z); s0[7] = (short)f2bf(q1.w);
        s1[0] = (short)f2bf(q2.x); s1[1] = (short)f2bf(q2.y);
        s1[2] = (short)f2bf(q2.z); s1[3] = (short)f2bf(q2.w);
        s1[4] = (short)f2bf(q3.x); s1[5] = (short)f2bf(q3.y);
        s1[6] = (short)f2bf(q3.z); s1[7] = (short)f2bf(q3.w);

        f32x4 acc[4];
#pragma unroll
        for (int nt = 0; nt < 4; ++nt) {
            acc[nt] = __builtin_amdgcn_mfma_f32_16x16x32_bf16(a0, bh[nt][0], zero, 0, 0, 0);
            acc[nt] = __builtin_amdgcn_mfma_f32_16x16x32_bf16(a1, bh[nt][1], acc[nt], 0, 0, 0);
            acc[nt] = __builtin_amdgcn_mfma_f32_16x16x32_bf16(s0, ba[nt][0], acc[nt], 0, 0, 0);
            acc[nt] = __builtin_amdgcn_mfma_f32_16x16x32_bf16(s1, ba[nt][1], acc[nt], 0, 0, 0);
        }
#pragma unroll
        for (int r = 0; r < 4; ++r) {
            size_t row = (size_t)t * 16 + 4 * g + r;
            int lrow = 4 * g + r;
#pragma unroll
            for (int nt = 0; nt < 4; ++nt) {
                size_t idx = row * 64 + nt * 16 + c;
                float v = bf2f(hb16[idx]) + fmaxf(acc[nt][r] + ubv[nt], 0.f);
                unsigned short vb = f2bf(v);
                hb16[idx] = vb;
                int col = nt * 16 + c;
                stile[wvv][lrow * 64 + (col ^ ((lrow & 7) << 3))] = vb;
            }
        }
        short8 na0 = *(const short8*)&stile[wvv][c * 64 + ((g * 8) ^ xr)];
        short8 na1 = *(const short8*)&stile[wvv][c * 64 + ((32 + g * 8) ^ xr)];
        f32x4 ak[4], av[4];
#pragma unroll
        for (int nt = 0; nt < 4; ++nt) {
            ak[nt] = __builtin_amdgcn_mfma_f32_16x16x32_bf16(na0, bkf[nt][0], zero, 0, 0, 0);
            ak[nt] = __builtin_amdgcn_mfma_f32_16x16x32_bf16(na1, bkf[nt][1], ak[nt], 0, 0, 0);
            av[nt] = __builtin_amdgcn_mfma_f32_16x16x32_bf16(na0, bvf[nt][0], zero, 0, 0, 0);
            av[nt] = __builtin_amdgcn_mfma_f32_16x16x32_bf16(na1, bvf[nt][1], av[nt], 0, 0, 0);
        }
#pragma unroll
        for (int r = 0; r < 4; ++r) {
            size_t row = (size_t)t * 16 + 4 * g + r;
#pragma unroll
            for (int nt = 0; nt < 4; ++nt) {
                kb16[row * 64 + nt * 16 + c] = f2bf(ak[nt][r] + bkv[nt]);
                vb16[row * 64 + nt * 16 + c] = f2bf(av[nt][r] + bvv[nt]);
            }
        }
    }
}

// ---------------- a = relu(ad @ w_ad + b_ad); q = a @ wq + bq ----------------
__global__ __launch_bounds__(64) void k_aq(const float* __restrict__ ad,
                                           const float* __restrict__ wad,
                                           const float* __restrict__ bad,
                                           const float* __restrict__ wq,
                                           const float* __restrict__ bq,
                                           float* __restrict__ a_out,
                                           float* __restrict__ q_out) {
    int b = blockIdx.x, t = threadIdx.x;
    __shared__ float sa[64];
    float acc = bad[t];
#pragma unroll
    for (int i = 0; i < 8; ++i) acc = fmaf(ad[b * 8 + i], wad[i * 64 + t], acc);
    float av = fmaxf(acc, 0.f);
    sa[t] = av;
    a_out[b * 64 + t] = av;
    __syncthreads();
    float qa = bq[t];
    for (int i = 0; i < 64; ++i) qa = fmaf(sa[i], wq[i * 64 + t], qa);
    q_out[b * 64 + t] = qa;
}

// ---------------- attention: chunked online softmax partials (bf16 k/v) ----------------
__global__ __launch_bounds__(256) void k_attn(const float* __restrict__ q,
                                              const unsigned short* __restrict__ kb16,
                                              const unsigned short* __restrict__ vb16,
                                              float* __restrict__ part) {
    int id = blockIdx.x;
    int ch = id % NCH;
    int bh = id / NCH;
    int b = bh / HEADS_, hd = bh % HEADS_;
    float qv[16];
#pragma unroll
    for (int d = 0; d < 16; ++d) qv[d] = q[b * 64 + hd * 16 + d];
    float m = -1e30f, s = 0.f, c[16];
#pragma unroll
    for (int d = 0; d < 16; ++d) c[d] = 0.f;
    int n0 = ch * CS;
    int n1 = n0 + CS; if (n1 > N_) n1 = N_;
    for (int n = n0 + threadIdx.x; n < n1; n += 256) {
        const short8* kr = (const short8*)(kb16 + ((size_t)b * N_ + n) * 64 + hd * 16);
        short8 k0 = kr[0], k1 = kr[1];
        float dot = 0.f;
#pragma unroll
        for (int d = 0; d < 8; ++d) {
            dot = fmaf(qv[d], bf2f((unsigned short)k0[d]), dot);
            dot = fmaf(qv[8 + d], bf2f((unsigned short)k1[d]), dot);
        }
        dot *= 0.25f;
        float nm = fmaxf(m, dot);
        float p = __expf(dot - nm);
        float cor = __expf(m - nm);
        const short8* vr = (const short8*)(vb16 + ((size_t)b * N_ + n) * 64 + hd * 16);
        short8 v0 = vr[0], v1 = vr[1];
        s = s * cor + p;
#pragma unroll
        for (int d = 0; d < 8; ++d) {
            c[d] = c[d] * cor + p * bf2f((unsigned short)v0[d]);
            c[8 + d] = c[8 + d] * cor + p * bf2f((unsigned short)v1[d]);
        }
        m = nm;
    }
#pragma unroll
    for (int o = 1; o < 64; o <<= 1) {
        float m2 = __shfl_xor(m, o);
        float s2 = __shfl_xor(s, o);
        float nm = fmaxf(m, m2);
        float w1 = __expf(m - nm), w2 = __expf(m2 - nm);
        s = s * w1 + s2 * w2;
#pragma unroll
        for (int d = 0; d < 16; ++d) {
            float c2 = __shfl_xor(c[d], o);
            c[d] = c[d] * w1 + c2 * w2;
        }
        m = nm;
    }
    __shared__ float red[4][18];
    int wv_ = threadIdx.x >> 6, lane = threadIdx.x & 63;
    if (lane == 0) {
        red[wv_][0] = m; red[wv_][1] = s;
#pragma unroll
        for (int d = 0; d < 16; ++d) red[wv_][2 + d] = c[d];
    }
    __syncthreads();
    if (threadIdx.x == 0) {
        float gm = red[0][0];
        for (int w = 1; w < 4; ++w) gm = fmaxf(gm, red[w][0]);
        float gs = 0.f, gc[16];
#pragma unroll
        for (int d = 0; d < 16; ++d) gc[d] = 0.f;
        for (int w = 0; w < 4; ++w) {
            float ww = __expf(red[w][0] - gm);
            gs += red[w][1] * ww;
#pragma unroll
            for (int d = 0; d < 16; ++d) gc[d] += red[w][2 + d] * ww;
        }
        float* p = part + (size_t)id * 18;
        p[0] = gm; p[1] = gs;
#pragma unroll
        for (int d = 0; d < 16; ++d) p[2 + d] = gc[d];
    }
}

__global__ __launch_bounds__(64) void k_comb(const float* __restrict__ part,
                                             float* __restrict__ ctx) {
    int bh = blockIdx.x, t = threadIdx.x;
    int b = bh / HEADS_, hd = bh % HEADS_;
    const float* p = part + ((size_t)bh * NCH + t) * 18;
    float m = p[0], s = p[1], c[16];
#pragma unroll
    for (int d = 0; d < 16; ++d) c[d] = p[2 + d];
    float gm = m;
#pragma unroll
    for (int o = 1; o < 64; o <<= 1) gm = fmaxf(gm, __shfl_xor(gm, o));
    float w = __expf(m - gm);
    float sw = s * w;
#pragma unroll
    for (int o = 1; o < 64; o <<= 1) sw += __shfl_xor(sw, o);
    float cg[16];
#pragma unroll
    for (int d = 0; d < 16; ++d) {
        float x = c[d] * w;
#pragma unroll
        for (int o = 1; o < 64; o <<= 1) x += __shfl_xor(x, o);
        cg[d] = x;
    }
    if (t == 0) {
#pragma unroll
        for (int d = 0; d < 16; ++d) ctx[b * 64 + hd * 16 + d] = cg[d] / sw;
    }
}

// ---------------- g = LN(a + ctx@wo + bo); wcomb = g/8 + policy_w ----------------
__global__ __launch_bounds__(64) void k_g(const float* __restrict__ a,
                                          const float* __restrict__ ctx,
                                          const float* __restrict__ wo,
                                          const float* __restrict__ bo,
                                          const float* __restrict__ lng,
                                          const float* __restrict__ lnb,
                                          const float* __restrict__ pw,
                                          float* __restrict__ wcomb) {
    int b = blockIdx.x, t = threadIdx.x;
    __shared__ float sc[64];
    sc[t] = ctx[b * 64 + t];
    __syncthreads();
    float o = bo[t];
    for (int i = 0; i < 64; ++i) o = fmaf(sc[i], wo[i * 64 + t], o);
    float y = a[b * 64 + t] + o;
    float mu = y;
#pragma unroll
    for (int oo = 1; oo < 64; oo <<= 1) mu += __shfl_xor(mu, oo);
    mu *= (1.f / 64.f);
    float d = y - mu;
    float var = d * d;
#pragma unroll
    for (int oo = 1; oo < 64; oo <<= 1) var += __shfl_xor(var, oo);
    var *= (1.f / 64.f);
    float g = d * rsqrtf(var + 1e-5f) * lng[t] + lnb[t];
    wcomb[b * 64 + t] = g * 0.125f + pw[t];
}

// ---------------- logits (bf16 h) ----------------
__global__ __launch_bounds__(256) void k_final(const unsigned short* __restrict__ hb16,
                                               const float* __restrict__ wcomb,
                                               const float* __restrict__ pb,
                                               const void* __restrict__ mask,
                                               const int* __restrict__ flagp,
                                               float* __restrict__ out) {
    int idx = blockIdx.x * 256 + threadIdx.x;
    if (idx >= B_ * N_) return;
    int b = idx / N_;
    const float* wr = wcomb + b * 64;
    const short8* hr = (const short8*)(hb16 + (size_t)idx * 64);
    float acc = pb[0];
#pragma unroll
    for (int i = 0; i < 8; ++i) {
        short8 hv = hr[i];
#pragma unroll
        for (int j = 0; j < 8; ++j)
            acc = fmaf(bf2f((unsigned short)hv[j]), wr[i * 8 + j], acc);
    }
    int flag = *flagp;
    bool mv;
    if (flag == 1)      mv = ((const int*)mask)[idx] != 0;
    else if (flag == 2) mv = ((const float*)mask)[idx] != 0.f;
    else                mv = ((const unsigned char*)mask)[idx] != 0;
    out[idx] = mv ? acc : -1.0e9f;
}

extern "C" void kernel_launch(void* const* d_in, const int* in_sizes, int n_in,
                              void* d_out, int out_size, void* d_ws, size_t ws_size,
                              hipStream_t stream) {
    const float* gn   = (const float*)d_in[0];
    const float* ad   = (const float*)d_in[1];
    const float* wnod = (const float*)d_in[2];
    const float* bnod = (const float*)d_in[3];
    const float* msgw = (const float*)d_in[4];
    const float* msgb = (const float*)d_in[5];
    const float* updw = (const float*)d_in[6];
    const float* updb = (const float*)d_in[7];
    const float* wad  = (const float*)d_in[8];
    const float* bad  = (const float*)d_in[9];
    const float* wq   = (const float*)d_in[10];
    const float* bq   = (const float*)d_in[11];
    const float* wk   = (const float*)d_in[12];
    const float* bk   = (const float*)d_in[13];
    const float* wv   = (const float*)d_in[14];
    const float* bv   = (const float*)d_in[15];
    const float* wo   = (const float*)d_in[16];
    const float* bo   = (const float*)d_in[17];
    const float* lng  = (const float*)d_in[18];
    const float* lnb  = (const float*)d_in[19];
    const float* pw   = (const float*)d_in[20];
    const float* pb   = (const float*)d_in[21];
    const int*   links= (const int*)d_in[22];
    const void*  mask = d_in[23];

    char* ws = (char*)d_ws;
    unsigned short* tdb  = (unsigned short*)(ws + OFF_TDB);
    unsigned short* kb16 = (unsigned short*)(ws + OFF_TDB);
    float* agg  = (float*)(ws + OFF_AGG);
    unsigned* ebuck = (unsigned*)(ws + OFF_EBUCK);
    unsigned* epair = (unsigned*)(ws + OFF_EPAIR);
    unsigned short* hb16 = (unsigned short*)(ws + OFF_HB16);
    float* avec = (float*)(ws + OFF_AVEC);
    float* qvec = (float*)(ws + OFF_Q);
    float* ctx  = (float*)(ws + OFF_CTX);
    float* wcmb = (float*)(ws + OFF_WCMB);
    int*   flag = (int*)(ws + OFF_FLAG);
    float* part = (float*)(ws + OFF_PART);
    int*   tails= (int*)(ws + OFF_TAILS);
    int*   wbase= (int*)(ws + OFF_WBASE);
    unsigned short* vb16 = (unsigned short*)(ws + OFF_VB16);
    float* out  = (float*)d_out;

    hipMemsetAsync(tails, 0, (size_t)B_ * NWIN * TPAD * 4, stream);
    k_maskdetect<<<1, 1, 0, stream>>>((const unsigned int*)mask, flag);
    k_embed_bucket<<<6248, 256, 0, stream>>>(gn, wnod, bnod, hb16, links, tails, ebuck);
    k_scan_tails<<<B_, 1024, 0, stream>>>(tails, wbase);
    k_sortwin<<<5000, 256, 0, stream>>>(ebuck, tails, wbase, epair);

    // layer 0
    k_tdst_mfma<<<512, 256, 0, stream>>>(hb16, msgw, msgb, tdb);
    hipMemsetAsync(agg, 0, SZ_AGG, stream);
    k_edge_mfma<<<5000, 256, 0, stream>>>(hb16, tdb, epair, msgw, agg);
    k_upd_tdst_mfma<<<512, 256, 0, stream>>>(hb16, agg, updw, updb,
                                             msgw + (size_t)128 * 64, msgb + 64, tdb);
    // layer 1
    hipMemsetAsync(agg, 0, SZ_AGG, stream);
    k_edge_mfma<<<5000, 256, 0, stream>>>(hb16, tdb, epair, msgw + (size_t)128 * 64, agg);
    k_upd_kv_mfma<<<512, 256, 0, stream>>>(hb16, agg, updw + (size_t)128 * 64, updb + 64,
                                           wk, bk, wv, bv, kb16, vb16);

    k_aq<<<B_, 64, 0, stream>>>(ad, wad, bad, wq, bq, avec, qvec);
    k_attn<<<B_ * HEADS_ * NCH, 256, 0, stream>>>(qvec, kb16, vb16, part);
    k_comb<<<B_ * HEADS_, 64, 0, stream>>>(part, ctx);
    k_g<<<B_, 64, 0, stream>>>(avec, ctx, wo, bo, lng, lnb, pw, wcmb);
    k_final<<<(B_ * N_ + 255) / 256, 256, 0, stream>>>(hb16, wcmb, pb, mask, flag, out);
}

// Round 18
// 254.556 us; speedup vs baseline: 1.2248x; 1.0102x over previous
//
#include <hip/hip_runtime.h>
#include <hip/hip_bf16.h>
#include <math.h>

// Problem constants
constexpr int B_ = 4;
constexpr int N_ = 20000;
constexpr int E_ = 320000;
constexpr int HEADS_ = 4;
constexpr int NCH = 64;                       // attention chunks per (b,head)
constexpr int CS = (N_ + NCH - 1) / NCH;      // 313
constexpr int NT_ = (B_ * N_) / 16;           // 5000 node tiles
constexpr int NWIN = 1250;                    // 16-dst windows per batch
constexpr int HWIN = 625;                     // windows per XCD half
constexpr int WCAP = 512;                     // bucket capacity (mean 256, +16 sigma)
constexpr int TPAD = 16;                      // tails padding -> 1 counter/line

typedef __attribute__((ext_vector_type(8))) short short8;   // 8 bf16
typedef __attribute__((ext_vector_type(4))) float f32x4;

// Workspace layout (bytes). ~67 MB.
constexpr size_t SZ_TDB   = (size_t)B_ * N_ * 64 * 2;     // 10,240,000
constexpr size_t SZ_AGG   = (size_t)B_ * N_ * 64 * 4;     // 20,480,000
constexpr size_t SZ_EBUCK = (size_t)B_ * NWIN * WCAP * 4; // 10,240,000 (packed int)
constexpr size_t SZ_EPAIR = (size_t)B_ * E_ * 4;          // 5,120,000 (packed int)
constexpr size_t OFF_TDB  = 0;                            // tdb bf16 (transposed); later kb16
constexpr size_t OFF_AGG  = SZ_TDB;                       // agg f32
constexpr size_t OFF_EBUCK= OFF_AGG + SZ_AGG;
constexpr size_t OFF_EPAIR= OFF_EBUCK + SZ_EBUCK;
constexpr size_t OFF_HB16 = OFF_EPAIR + SZ_EPAIR;
constexpr size_t OFF_AVEC = OFF_HB16 + SZ_TDB;
constexpr size_t OFF_Q    = OFF_AVEC + 1024;
constexpr size_t OFF_CTX  = OFF_Q + 1024;
constexpr size_t OFF_WCMB = OFF_CTX + 1024;
constexpr size_t OFF_FLAG = OFF_WCMB + 1024;
constexpr size_t OFF_PART = OFF_FLAG + 64;                // 1024*18 f partials
constexpr size_t OFF_TAILS= OFF_PART + 1024 * 18 * 4 + 64;   // B*NWIN*TPAD ints
constexpr size_t OFF_WBASE= OFF_TAILS + (size_t)B_ * NWIN * TPAD * 4; // B*NWIN ints
constexpr size_t OFF_VB16 = OFF_WBASE + (size_t)B_ * NWIN * 4 + 64;   // v bf16 (own region)

static __device__ __forceinline__ unsigned short f2bf(float f) {
    union { float f; unsigned u; } v; v.f = f;
    unsigned r = v.u + 0x7fffu + ((v.u >> 16) & 1u);
    return (unsigned short)(r >> 16);
}
static __device__ __forceinline__ float bf2f(unsigned short u) {
    union { unsigned u; float f; } v; v.u = (unsigned)u << 16;
    return v.f;
}

// ---------------- mask dtype detection ----------------
__global__ void k_maskdetect(const unsigned int* __restrict__ m, int* __restrict__ flag) {
    if (blockIdx.x == 0 && threadIdx.x == 0) {
        bool alli = true, allf = true;
        for (int i = 0; i < 256; ++i) {
            unsigned v = m[i];
            alli = alli && (v <= 1u);
            allf = allf && (v == 0u || v == 0x3f800000u);
        }
        *flag = alli ? 1 : (allf ? 2 : 0);
    }
}

// ---------------- fused: embed (1/5 of groups) + XCD-partitioned bucket build ----------------
__global__ __launch_bounds__(256) void k_embed_bucket(const float* __restrict__ gn,
                                                      const float* __restrict__ wnod,
                                                      const float* __restrict__ bias,
                                                      unsigned short* __restrict__ hb16,
                                                      const int* __restrict__ links,
                                                      int* __restrict__ tails,
                                                      unsigned* __restrict__ ebuck) {
    int i = blockIdx.x;
    int g = i >> 3, r = i & 7;
    if (g % 5 == 4) {
        int eb = (g / 5) * 8 + r;             // 0..1247
        int lane = threadIdx.x & 63;
        float wc[16];
#pragma unroll
        for (int k = 0; k < 16; ++k) wc[k] = wnod[k * 64 + lane];
        float bb = bias[lane];
        int gw = eb * 4 + (threadIdx.x >> 6);
        for (int node = gw; node < B_ * N_; node += 1248 * 4) {
            const float* rr = gn + (size_t)node * 16;
            float a0 = 0.f, a1 = 0.f, a2 = 0.f, a3 = 0.f;
#pragma unroll
            for (int k = 0; k < 16; k += 4) {
                a0 = fmaf(rr[k + 0], wc[k + 0], a0);
                a1 = fmaf(rr[k + 1], wc[k + 1], a1);
                a2 = fmaf(rr[k + 2], wc[k + 2], a2);
                a3 = fmaf(rr[k + 3], wc[k + 3], a3);
            }
            float v = fmaxf(bb + ((a0 + a1) + (a2 + a3)), 0.f);
            hb16[(size_t)node * 64 + lane] = f2bf(v);
        }
    } else {
        int og = g - (g + 1) / 5;             // 0..624
        int b = r >> 1;
        int half = r & 1;
        int e0 = og * 512 + threadIdx.x;
        const int* lsrc = links + (size_t)b * 2 * E_;
#pragma unroll
        for (int ch = 0; ch < 2; ++ch) {
            int e = e0 + ch * 256;
            unsigned src = (unsigned)lsrc[e];
            unsigned dst = (unsigned)lsrc[E_ + e];
            int w = dst >> 4;                 // 0..1249
            if ((w >= HWIN) == (half == 1)) {
                int slot = atomicAdd(&tails[(b * NWIN + w) * TPAD], 1);
                if (slot < WCAP)
                    ebuck[(size_t)(b * NWIN + w) * WCAP + slot] = (dst << 16) | src;
            }
        }
    }
}

// ---------------- exclusive scan of (padded) window tails -> epair bases ----------------
__global__ __launch_bounds__(1024) void k_scan_tails(const int* __restrict__ tails,
                                                     int* __restrict__ wbase) {
    __shared__ int wsum[16];
    __shared__ int sbase;
    int b = blockIdx.x, t = threadIdx.x;
    int lane = t & 63, wv = t >> 6;
    if (t == 0) sbase = 0;
    __syncthreads();
    for (int base = 0; base < NWIN; base += 1024) {
        int idx = base + t;
        int c = 0;
        if (idx < NWIN) { c = tails[(b * NWIN + idx) * TPAD]; if (c > WCAP) c = WCAP; }
        int x = c;
#pragma unroll
        for (int o = 1; o < 64; o <<= 1) {
            int y = __shfl_up(x, o);
            if (lane >= o) x += y;
        }
        if (lane == 63) wsum[wv] = x;
        __syncthreads();
        if (wv == 0) {
            int s = (lane < 16) ? wsum[lane] : 0;
#pragma unroll
            for (int o = 1; o < 16; o <<= 1) {
                int y = __shfl_up(s, o);
                if (lane >= o) s += y;
            }
            if (lane < 16) wsum[lane] = s;
        }
        __syncthreads();
        int wpre = (wv > 0) ? wsum[wv - 1] : 0;
        int incl = x + wpre + sbase;
        if (idx < NWIN) wbase[b * NWIN + idx] = incl - c;   // exclusive
        __syncthreads();
        if (t == 1023) sbase = incl;
        __syncthreads();
    }
}

// ---------------- per-window 16-bin counting sort (LDS) -> sorted packed epair ----------------
__global__ __launch_bounds__(256) void k_sortwin(const unsigned* __restrict__ ebuck,
                                                 const int* __restrict__ tails,
                                                 const int* __restrict__ wbase,
                                                 unsigned* __restrict__ epair) {
    __shared__ int hist[16], hbase[16];
    __shared__ unsigned sbuf[WCAP];
    int i = blockIdx.x;                   // 0..4999
    int r = i & 7;
    int b = r >> 1;
    int w = (i >> 3) + HWIN * (r & 1);    // XCD-matched
    int cntw = tails[(b * NWIN + w) * TPAD];
    if (cntw > WCAP) cntw = WCAP;
    if (threadIdx.x < 16) hist[threadIdx.x] = 0;
    __syncthreads();
    const unsigned* src = ebuck + (size_t)(b * NWIN + w) * WCAP;
    int idx0 = threadIdx.x, idx1 = threadIdx.x + 256;
    bool v0 = idx0 < cntw, v1 = idx1 < cntw;
    unsigned e0 = 0, e1 = 0;
    if (v0) { e0 = src[idx0]; atomicAdd(&hist[(e0 >> 16) & 15], 1); }
    if (v1) { e1 = src[idx1]; atomicAdd(&hist[(e1 >> 16) & 15], 1); }
    __syncthreads();
    if (threadIdx.x == 0) {
        int run = 0;
#pragma unroll
        for (int p = 0; p < 16; ++p) { hbase[p] = run; run += hist[p]; }
    }
    __syncthreads();
    if (threadIdx.x < 16) hist[threadIdx.x] = 0;
    __syncthreads();
    if (v0) { int bn = (e0 >> 16) & 15; sbuf[hbase[bn] + atomicAdd(&hist[bn], 1)] = e0; }
    if (v1) { int bn = (e1 >> 16) & 15; sbuf[hbase[bn] + atomicAdd(&hist[bn], 1)] = e1; }
    __syncthreads();
    int gb = wbase[b * NWIN + w];
    unsigned* dst = epair + (size_t)b * E_ + gb;
    for (int idx = threadIdx.x; idx < cntw; idx += 256) dst[idx] = sbuf[idx];
}

// ---------------- tdst (transposed) = W2^T h + msg_b, layer 0; zeroes agg ----------------
__global__ __launch_bounds__(256) void k_tdst_mfma(const unsigned short* __restrict__ hb16,
                                                   const float* __restrict__ mw,
                                                   const float* __restrict__ mb,
                                                   unsigned short* __restrict__ tdb,
                                                   float* __restrict__ agg) {
    int lane = threadIdx.x & 63;
    int g = lane >> 4, c = lane & 15;
    short8 bf[4][2];
#pragma unroll
    for (int nt = 0; nt < 4; ++nt)
#pragma unroll
        for (int ks = 0; ks < 2; ++ks)
#pragma unroll
            for (int j = 0; j < 8; ++j)
                bf[nt][ks][j] = (short)f2bf(mw[(64 + ks * 32 + g * 8 + j) * 64 + nt * 16 + c]);
    float mbv[4];
#pragma unroll
    for (int nt = 0; nt < 4; ++nt) mbv[nt] = mb[nt * 16 + c];

    int wid = blockIdx.x * 4 + (threadIdx.x >> 6);
    int nw = gridDim.x * 4;
    f32x4 zero = {0.f, 0.f, 0.f, 0.f};
    for (int t = wid; t < NT_; t += nw) {
        const unsigned short* ap = hb16 + ((size_t)t * 16 + c) * 64;
        short8 a0 = *(const short8*)(ap + g * 8);
        short8 a1 = *(const short8*)(ap + 32 + g * 8);
        f32x4 acc[4];
#pragma unroll
        for (int nt = 0; nt < 4; ++nt) {
            acc[nt] = __builtin_amdgcn_mfma_f32_16x16x32_bf16(a0, bf[nt][0], zero, 0, 0, 0);
            acc[nt] = __builtin_amdgcn_mfma_f32_16x16x32_bf16(a1, bf[nt][1], acc[nt], 0, 0, 0);
        }
#pragma unroll
        for (int r = 0; r < 4; ++r) {
            size_t row = (size_t)t * 16 + 4 * g + r;
            unsigned long long pk =
                (unsigned long long)f2bf(acc[0][r] + mbv[0])
              | ((unsigned long long)f2bf(acc[1][r] + mbv[1]) << 16)
              | ((unsigned long long)f2bf(acc[2][r] + mbv[2]) << 32)
              | ((unsigned long long)f2bf(acc[3][r] + mbv[3]) << 48);
            *(unsigned long long*)(tdb + row * 64 + c * 4) = pk;
            *(f32x4*)(agg + row * 64 + c * 4) = zero;     // agg zeroing folded in
        }
    }
}

// ---------------- fused MFMA edge kernel: 32-edge tiles, td-as-C-init ----------------
__global__ __launch_bounds__(256) void k_edge_mfma(const unsigned short* __restrict__ hb16,
                                                   const unsigned short* __restrict__ tdb,
                                                   const unsigned* __restrict__ epair,
                                                   const float* __restrict__ mw,
                                                   float* __restrict__ agg) {
    int lane = threadIdx.x & 63;
    int g = lane >> 4, c = lane & 15;
    short8 bf[4][2];
#pragma unroll
    for (int nt = 0; nt < 4; ++nt)
#pragma unroll
        for (int ks = 0; ks < 2; ++ks)
#pragma unroll
            for (int j = 0; j < 8; ++j)
                bf[nt][ks][j] = (short)f2bf(mw[(ks * 32 + g * 8 + j) * 64 + nt * 16 + c]);

    int i = blockIdx.x;                       // 0..4999
    int b = (i & 7) >> 1;                     // batch (XCD-pinned pair)
    int o = ((i >> 3) << 1) | (i & 1);        // per-batch block ordinal 0..1249
    int w = threadIdx.x >> 6;
    const unsigned* pp = epair + (size_t)b * E_;
    const unsigned short* hbase = hb16 + (size_t)(b * N_) * 64;
    const unsigned short* tbase = tdb + (size_t)(b * N_) * 64;
    float* abase = agg + (size_t)(b * N_) * 64;

    bool hi1 = (lane & 32) != 0;
    bool hi0 = (lane & 16) != 0;

    // 2 pair-tiles (32 edges each) per wave; hoist all epair + h gathers
    unsigned prA[2], prB[2];
#pragma unroll
    for (int k = 0; k < 2; ++k) {
        int s0 = ((o * 4 + w) + k * 5000) * 32;
        prA[k] = pp[s0 + c];
        prB[k] = pp[s0 + 16 + c];
    }
    short8 a0A[2], a1A[2], a0B[2], a1B[2];
#pragma unroll
    for (int k = 0; k < 2; ++k) {
        const unsigned short* hrA = hbase + (size_t)(prA[k] & 0xFFFFu) * 64;
        a0A[k] = *(const short8*)(hrA + g * 8);
        a1A[k] = *(const short8*)(hrA + 32 + g * 8);
        const unsigned short* hrB = hbase + (size_t)(prB[k] & 0xFFFFu) * 64;
        a0B[k] = *(const short8*)(hrB + g * 8);
        a1B[k] = *(const short8*)(hrB + 32 + g * 8);
    }

#pragma unroll
    for (int k = 0; k < 2; ++k) {
        int dA = (int)(prA[k] >> 16);
        int dB = (int)(prB[k] >> 16);

        // td rows as MFMA C-init (transposed tdb: one 8B load per row)
        unsigned long long tvA[4], tvB[4];
#pragma unroll
        for (int r = 0; r < 4; ++r) {
            int drA = __shfl(dA, 4 * g + r);
            tvA[r] = *(const unsigned long long*)(tbase + (size_t)drA * 64 + c * 4);
            int drB = __shfl(dB, 4 * g + r);
            tvB[r] = *(const unsigned long long*)(tbase + (size_t)drB * 64 + c * 4);
        }
        f32x4 accA[4], accB[4];
#pragma unroll
        for (int nt = 0; nt < 4; ++nt) {
#pragma unroll
            for (int r = 0; r < 4; ++r) {
                accA[nt][r] = bf2f((unsigned short)((tvA[r] >> (16 * nt)) & 0xFFFFu));
                accB[nt][r] = bf2f((unsigned short)((tvB[r] >> (16 * nt)) & 0xFFFFu));
            }
        }
#pragma unroll
        for (int nt = 0; nt < 4; ++nt) {
            accA[nt] = __builtin_amdgcn_mfma_f32_16x16x32_bf16(a0A[k], bf[nt][0], accA[nt], 0, 0, 0);
            accA[nt] = __builtin_amdgcn_mfma_f32_16x16x32_bf16(a1A[k], bf[nt][1], accA[nt], 0, 0, 0);
            accB[nt] = __builtin_amdgcn_mfma_f32_16x16x32_bf16(a0B[k], bf[nt][0], accB[nt], 0, 0, 0);
            accB[nt] = __builtin_amdgcn_mfma_f32_16x16x32_bf16(a1B[k], bf[nt][1], accB[nt], 0, 0, 0);
        }
        float valA[4][4], valB[4][4];
#pragma unroll
        for (int nt = 0; nt < 4; ++nt)
#pragma unroll
            for (int r = 0; r < 4; ++r) {
                valA[nt][r] = fmaxf(accA[nt][r], 0.f);
                valB[nt][r] = fmaxf(accB[nt][r], 0.f);
            }

        // 32-row segment head mask (sorted dst)
        int prevA = __shfl(dA, (lane + 63) & 63);
        bool headA = (c == 0) || (dA != prevA);
        int lastA = __shfl(dA, 15);
        int prevB = __shfl(dB, (lane + 63) & 63);
        bool headB = (c == 0) ? (dB != lastA) : (dB != prevB);
        unsigned long long balA = __ballot(headA);
        unsigned long long balB = __ballot(headB);
        unsigned m32 = (unsigned)(balA & 0xFFFFu) | ((unsigned)(balB & 0xFFFFu) << 16);

        while (m32) {
            int ii = __ffs(m32) - 1;
            unsigned rest = m32 & (m32 - 1);
            int jj = rest ? (__ffs(rest) - 1) : 32;
            m32 = rest;
            int d = (ii < 16) ? __shfl(dA, ii) : __shfl(dB, ii - 16);

            float v0 = 0.f, v1 = 0.f, v2 = 0.f, v3 = 0.f;
#pragma unroll
            for (int r = 0; r < 4; ++r) {
                int rrA = 4 * g + r;
                bool inA = (rrA >= ii) && (rrA < jj);
                v0 += inA ? valA[0][r] : 0.f;
                v1 += inA ? valA[1][r] : 0.f;
                v2 += inA ? valA[2][r] : 0.f;
                v3 += inA ? valA[3][r] : 0.f;
                int rrB = 16 + 4 * g + r;
                bool inB = (rrB >= ii) && (rrB < jj);
                v0 += inB ? valB[0][r] : 0.f;
                v1 += inB ? valB[1][r] : 0.f;
                v2 += inB ? valB[2][r] : 0.f;
                v3 += inB ? valB[3][r] : 0.f;
            }
            float sA0 = hi1 ? v0 : v2;
            float sA1 = hi1 ? v1 : v3;
            float rA0 = __shfl_xor(sA0, 32);
            float rA1 = __shfl_xor(sA1, 32);
            float w0 = (hi1 ? v2 : v0) + rA0;
            float w1 = (hi1 ? v3 : v1) + rA1;
            float sB = hi0 ? w0 : w1;
            float rB = __shfl_xor(sB, 16);
            float outv = (hi0 ? w1 : w0) + rB;

            atomicAdd(&abase[(size_t)d * 64 + lane], outv);
        }
    }
}

// ---------------- fused: upd (layer 0) + tdst for layer 1; re-zeroes agg ----------------
__global__ __launch_bounds__(256) void k_upd_tdst_mfma(unsigned short* __restrict__ hb16,
                                                       float* __restrict__ agg,
                                                       const float* __restrict__ uw,
                                                       const float* __restrict__ ub,
                                                       const float* __restrict__ mw2,
                                                       const float* __restrict__ mb2,
                                                       unsigned short* __restrict__ tdb) {
    __shared__ unsigned short stile[4][1024];
    int lane = threadIdx.x & 63;
    int g = lane >> 4, c = lane & 15;
    int wv = threadIdx.x >> 6;
    short8 bh[4][2], ba[4][2], bt[4][2];
#pragma unroll
    for (int nt = 0; nt < 4; ++nt)
#pragma unroll
        for (int ks = 0; ks < 2; ++ks)
#pragma unroll
            for (int j = 0; j < 8; ++j) {
                bh[nt][ks][j] = (short)f2bf(uw[(ks * 32 + g * 8 + j) * 64 + nt * 16 + c]);
                ba[nt][ks][j] = (short)f2bf(uw[(64 + ks * 32 + g * 8 + j) * 64 + nt * 16 + c]);
                bt[nt][ks][j] = (short)f2bf(mw2[(64 + ks * 32 + g * 8 + j) * 64 + nt * 16 + c]);
            }
    float ubv[4], mbv[4];
#pragma unroll
    for (int nt = 0; nt < 4; ++nt) { ubv[nt] = ub[nt * 16 + c]; mbv[nt] = mb2[nt * 16 + c]; }

    int wid = blockIdx.x * 4 + wv;
    int nw = gridDim.x * 4;
    f32x4 zero = {0.f, 0.f, 0.f, 0.f};
    int xr = (c & 7) << 3;
    for (int t = wid; t < NT_; t += nw) {
        unsigned short* ap = hb16 + ((size_t)t * 16 + c) * 64;
        short8 a0 = *(const short8*)(ap + g * 8);
        short8 a1 = *(const short8*)(ap + 32 + g * 8);

        float* gp = agg + ((size_t)t * 16 + c) * 64;
        float4 q0 = *(const float4*)(gp + g * 8);
        float4 q1 = *(const float4*)(gp + g * 8 + 4);
        float4 q2 = *(const float4*)(gp + 32 + g * 8);
        float4 q3 = *(const float4*)(gp + 32 + g * 8 + 4);
        // re-zero agg in place for layer 1 (stream-ordered before next edge pass)
        *(f32x4*)(gp + g * 8) = zero;
        *(f32x4*)(gp + g * 8 + 4) = zero;
        *(f32x4*)(gp + 32 + g * 8) = zero;
        *(f32x4*)(gp + 32 + g * 8 + 4) = zero;
        short8 s0, s1;
        s0[0] = (short)f2bf(q0.x); s0[1] = (short)f2bf(q0.y);
        s0[2] = (short)f2bf(q0.z); s0[3] = (short)f2bf(q0.w);
        s0[4] = (short)f2bf(q1.x); s0[5] = (short)f2bf(q1.y);
        s0[6] = (short)f2bf(q1.z); s0[7] = (short)f2bf(q1.w);
        s1[0] = (short)f2bf(q2.x); s1[1] = (short)f2bf(q2.y);
        s1[2] = (short)f2bf(q2.z); s1[3] = (short)f2bf(q2.w);
        s1[4] = (short)f2bf(q3.x); s1[5] = (short)f2bf(q3.y);
        s1[6] = (short)f2bf(q3.z); s1[7] = (short)f2bf(q3.w);

        f32x4 acc[4];
#pragma unroll
        for (int nt = 0; nt < 4; ++nt) {
            acc[nt] = __builtin_amdgcn_mfma_f32_16x16x32_bf16(a0, bh[nt][0], zero, 0, 0, 0);
            acc[nt] = __builtin_amdgcn_mfma_f32_16x16x32_bf16(a1, bh[nt][1], acc[nt], 0, 0, 0);
            acc[nt] = __builtin_amdgcn_mfma_f32_16x16x32_bf16(s0, ba[nt][0], acc[nt], 0, 0, 0);
            acc[nt] = __builtin_amdgcn_mfma_f32_16x16x32_bf16(s1, ba[nt][1], acc[nt], 0, 0, 0);
        }
#pragma unroll
        for (int r = 0; r < 4; ++r) {
            size_t row = (size_t)t * 16 + 4 * g + r;
            int lrow = 4 * g + r;
#pragma unroll
            for (int nt = 0; nt < 4; ++nt) {
                size_t idx = row * 64 + nt * 16 + c;
                float v = bf2f(hb16[idx]) + fmaxf(acc[nt][r] + ubv[nt], 0.f);
                unsigned short vb = f2bf(v);
                hb16[idx] = vb;
                int col = nt * 16 + c;
                stile[wv][lrow * 64 + (col ^ ((lrow & 7) << 3))] = vb;
            }
        }
        // wave-private LDS round-trip: read A-frags of h_new
        short8 na0 = *(const short8*)&stile[wv][c * 64 + ((g * 8) ^ xr)];
        short8 na1 = *(const short8*)&stile[wv][c * 64 + ((32 + g * 8) ^ xr)];
        f32x4 tacc[4];
#pragma unroll
        for (int nt = 0; nt < 4; ++nt) {
            tacc[nt] = __builtin_amdgcn_mfma_f32_16x16x32_bf16(na0, bt[nt][0], zero, 0, 0, 0);
            tacc[nt] = __builtin_amdgcn_mfma_f32_16x16x32_bf16(na1, bt[nt][1], tacc[nt], 0, 0, 0);
        }
#pragma unroll
        for (int r = 0; r < 4; ++r) {
            size_t row = (size_t)t * 16 + 4 * g + r;
            unsigned long long pk =
                (unsigned long long)f2bf(tacc[0][r] + mbv[0])
              | ((unsigned long long)f2bf(tacc[1][r] + mbv[1]) << 16)
              | ((unsigned long long)f2bf(tacc[2][r] + mbv[2]) << 32)
              | ((unsigned long long)f2bf(tacc[3][r] + mbv[3]) << 48);
            *(unsigned long long*)(tdb + row * 64 + c * 4) = pk;
        }
    }
}

// ---------------- fused: upd (layer 1) + k/v projections ----------------
__global__ __launch_bounds__(256) void k_upd_kv_mfma(unsigned short* __restrict__ hb16,
                                                     const float* __restrict__ agg,
                                                     const float* __restrict__ uw,
                                                     const float* __restrict__ ub,
                                                     const float* __restrict__ wk,
                                                     const float* __restrict__ bk,
                                                     const float* __restrict__ wv,
                                                     const float* __restrict__ bv,
                                                     unsigned short* __restrict__ kb16,
                                                     unsigned short* __restrict__ vb16) {
    __shared__ unsigned short stile[4][1024];
    int lane = threadIdx.x & 63;
    int g = lane >> 4, c = lane & 15;
    int wvv = threadIdx.x >> 6;
    short8 bh[4][2], ba[4][2], bkf[4][2], bvf[4][2];
#pragma unroll
    for (int nt = 0; nt < 4; ++nt)
#pragma unroll
        for (int ks = 0; ks < 2; ++ks)
#pragma unroll
            for (int j = 0; j < 8; ++j) {
                bh[nt][ks][j]  = (short)f2bf(uw[(ks * 32 + g * 8 + j) * 64 + nt * 16 + c]);
                ba[nt][ks][j]  = (short)f2bf(uw[(64 + ks * 32 + g * 8 + j) * 64 + nt * 16 + c]);
                bkf[nt][ks][j] = (short)f2bf(wk[(ks * 32 + g * 8 + j) * 64 + nt * 16 + c]);
                bvf[nt][ks][j] = (short)f2bf(wv[(ks * 32 + g * 8 + j) * 64 + nt * 16 + c]);
            }
    float ubv[4], bkv[4], bvv[4];
#pragma unroll
    for (int nt = 0; nt < 4; ++nt) {
        ubv[nt] = ub[nt * 16 + c];
        bkv[nt] = bk[nt * 16 + c];
        bvv[nt] = bv[nt * 16 + c];
    }

    int wid = blockIdx.x * 4 + wvv;
    int nw = gridDim.x * 4;
    f32x4 zero = {0.f, 0.f, 0.f, 0.f};
    int xr = (c & 7) << 3;
    for (int t = wid; t < NT_; t += nw) {
        unsigned short* ap = hb16 + ((size_t)t * 16 + c) * 64;
        short8 a0 = *(const short8*)(ap + g * 8);
        short8 a1 = *(const short8*)(ap + 32 + g * 8);

        const float* gp = agg + ((size_t)t * 16 + c) * 64;
        float4 q0 = *(const float4*)(gp + g * 8);
        float4 q1 = *(const float4*)(gp + g * 8 + 4);
        float4 q2 = *(const float4*)(gp + 32 + g * 8);
        float4 q3 = *(const float4*)(gp + 32 + g * 8 + 4);
        short8 s0, s1;
        s0[0] = (short)f2bf(q0.x); s0[1] = (short)f2bf(q0.y);
        s0[2] = (short)f2bf(q0.z); s0[3] = (short)f2bf(q0.w);
        s0[4] = (short)f2bf(q1.x); s0[5] = (short)f2bf(q1.y);
        s0[6] = (short)f2bf(q1.z); s0[7] = (short)f2bf(q1.w);
        s1[0] = (short)f2bf(q2.x); s1[1] = (short)f2bf(q2.y);
        s1[2] = (short)f2bf(q2.z); s1[3] = (short)f2bf(q2.w);
        s1[4] = (short)f2bf(q3.x); s1[5] = (short)f2bf(q3.y);
        s1[6] = (short)f2bf(q3.z); s1[7] = (short)f2bf(q3.w);

        f32x4 acc[4];
#pragma unroll
        for (int nt = 0; nt < 4; ++nt) {
            acc[nt] = __builtin_amdgcn_mfma_f32_16x16x32_bf16(a0, bh[nt][0], zero, 0, 0, 0);
            acc[nt] = __builtin_amdgcn_mfma_f32_16x16x32_bf16(a1, bh[nt][1], acc[nt], 0, 0, 0);
            acc[nt] = __builtin_amdgcn_mfma_f32_16x16x32_bf16(s0, ba[nt][0], acc[nt], 0, 0, 0);
            acc[nt] = __builtin_amdgcn_mfma_f32_16x16x32_bf16(s1, ba[nt][1], acc[nt], 0, 0, 0);
        }
#pragma unroll
        for (int r = 0; r < 4; ++r) {
            size_t row = (size_t)t * 16 + 4 * g + r;
            int lrow = 4 * g + r;
#pragma unroll
            for (int nt = 0; nt < 4; ++nt) {
                size_t idx = row * 64 + nt * 16 + c;
                float v = bf2f(hb16[idx]) + fmaxf(acc[nt][r] + ubv[nt], 0.f);
                unsigned short vb = f2bf(v);
                hb16[idx] = vb;
                int col = nt * 16 + c;
                stile[wvv][lrow * 64 + (col ^ ((lrow & 7) << 3))] = vb;
            }
        }
        short8 na0 = *(const short8*)&stile[wvv][c * 64 + ((g * 8) ^ xr)];
        short8 na1 = *(const short8*)&stile[wvv][c * 64 + ((32 + g * 8) ^ xr)];
        f32x4 ak[4], av[4];
#pragma unroll
        for (int nt = 0; nt < 4; ++nt) {
            ak[nt] = __builtin_amdgcn_mfma_f32_16x16x32_bf16(na0, bkf[nt][0], zero, 0, 0, 0);
            ak[nt] = __builtin_amdgcn_mfma_f32_16x16x32_bf16(na1, bkf[nt][1], ak[nt], 0, 0, 0);
            av[nt] = __builtin_amdgcn_mfma_f32_16x16x32_bf16(na0, bvf[nt][0], zero, 0, 0, 0);
            av[nt] = __builtin_amdgcn_mfma_f32_16x16x32_bf16(na1, bvf[nt][1], av[nt], 0, 0, 0);
        }
#pragma unroll
        for (int r = 0; r < 4; ++r) {
            size_t row = (size_t)t * 16 + 4 * g + r;
#pragma unroll
            for (int nt = 0; nt < 4; ++nt) {
                kb16[row * 64 + nt * 16 + c] = f2bf(ak[nt][r] + bkv[nt]);
                vb16[row * 64 + nt * 16 + c] = f2bf(av[nt][r] + bvv[nt]);
            }
        }
    }
}

// ---------------- a = relu(ad @ w_ad + b_ad); q = a @ wq + bq ----------------
__global__ __launch_bounds__(64) void k_aq(const float* __restrict__ ad,
                                           const float* __restrict__ wad,
                                           const float* __restrict__ bad,
                                           const float* __restrict__ wq,
                                           const float* __restrict__ bq,
                                           float* __restrict__ a_out,
                                           float* __restrict__ q_out) {
    int b = blockIdx.x, t = threadIdx.x;
    __shared__ float sa[64];
    float acc = bad[t];
#pragma unroll
    for (int i = 0; i < 8; ++i) acc = fmaf(ad[b * 8 + i], wad[i * 64 + t], acc);
    float av = fmaxf(acc, 0.f);
    sa[t] = av;
    a_out[b * 64 + t] = av;
    __syncthreads();
    float qa = bq[t];
    for (int i = 0; i < 64; ++i) qa = fmaf(sa[i], wq[i * 64 + t], qa);
    q_out[b * 64 + t] = qa;
}

// ---------------- attention: chunked online softmax partials (bf16 k/v) ----------------
__global__ __launch_bounds__(256) void k_attn(const float* __restrict__ q,
                                              const unsigned short* __restrict__ kb16,
                                              const unsigned short* __restrict__ vb16,
                                              float* __restrict__ part) {
    int id = blockIdx.x;
    int ch = id % NCH;
    int bh = id / NCH;
    int b = bh / HEADS_, hd = bh % HEADS_;
    float qv[16];
#pragma unroll
    for (int d = 0; d < 16; ++d) qv[d] = q[b * 64 + hd * 16 + d];
    float m = -1e30f, s = 0.f, c[16];
#pragma unroll
    for (int d = 0; d < 16; ++d) c[d] = 0.f;
    int n0 = ch * CS;
    int n1 = n0 + CS; if (n1 > N_) n1 = N_;
    for (int n = n0 + threadIdx.x; n < n1; n += 256) {
        const short8* kr = (const short8*)(kb16 + ((size_t)b * N_ + n) * 64 + hd * 16);
        short8 k0 = kr[0], k1 = kr[1];
        float dot = 0.f;
#pragma unroll
        for (int d = 0; d < 8; ++d) {
            dot = fmaf(qv[d], bf2f((unsigned short)k0[d]), dot);
            dot = fmaf(qv[8 + d], bf2f((unsigned short)k1[d]), dot);
        }
        dot *= 0.25f;
        float nm = fmaxf(m, dot);
        float p = __expf(dot - nm);
        float cor = __expf(m - nm);
        const short8* vr = (const short8*)(vb16 + ((size_t)b * N_ + n) * 64 + hd * 16);
        short8 v0 = vr[0], v1 = vr[1];
        s = s * cor + p;
#pragma unroll
        for (int d = 0; d < 8; ++d) {
            c[d] = c[d] * cor + p * bf2f((unsigned short)v0[d]);
            c[8 + d] = c[8 + d] * cor + p * bf2f((unsigned short)v1[d]);
        }
        m = nm;
    }
#pragma unroll
    for (int o = 1; o < 64; o <<= 1) {
        float m2 = __shfl_xor(m, o);
        float s2 = __shfl_xor(s, o);
        float nm = fmaxf(m, m2);
        float w1 = __expf(m - nm), w2 = __expf(m2 - nm);
        s = s * w1 + s2 * w2;
#pragma unroll
        for (int d = 0; d < 16; ++d) {
            float c2 = __shfl_xor(c[d], o);
            c[d] = c[d] * w1 + c2 * w2;
        }
        m = nm;
    }
    __shared__ float red[4][18];
    int wv_ = threadIdx.x >> 6, lane = threadIdx.x & 63;
    if (lane == 0) {
        red[wv_][0] = m; red[wv_][1] = s;
#pragma unroll
        for (int d = 0; d < 16; ++d) red[wv_][2 + d] = c[d];
    }
    __syncthreads();
    if (threadIdx.x == 0) {
        float gm = red[0][0];
        for (int w = 1; w < 4; ++w) gm = fmaxf(gm, red[w][0]);
        float gs = 0.f, gc[16];
#pragma unroll
        for (int d = 0; d < 16; ++d) gc[d] = 0.f;
        for (int w = 0; w < 4; ++w) {
            float ww = __expf(red[w][0] - gm);
            gs += red[w][1] * ww;
#pragma unroll
            for (int d = 0; d < 16; ++d) gc[d] += red[w][2 + d] * ww;
        }
        float* p = part + (size_t)id * 18;
        p[0] = gm; p[1] = gs;
#pragma unroll
        for (int d = 0; d < 16; ++d) p[2 + d] = gc[d];
    }
}

__global__ __launch_bounds__(64) void k_comb(const float* __restrict__ part,
                                             float* __restrict__ ctx) {
    int bh = blockIdx.x, t = threadIdx.x;
    int b = bh / HEADS_, hd = bh % HEADS_;
    const float* p = part + ((size_t)bh * NCH + t) * 18;
    float m = p[0], s = p[1], c[16];
#pragma unroll
    for (int d = 0; d < 16; ++d) c[d] = p[2 + d];
    float gm = m;
#pragma unroll
    for (int o = 1; o < 64; o <<= 1) gm = fmaxf(gm, __shfl_xor(gm, o));
    float w = __expf(m - gm);
    float sw = s * w;
#pragma unroll
    for (int o = 1; o < 64; o <<= 1) sw += __shfl_xor(sw, o);
    float cg[16];
#pragma unroll
    for (int d = 0; d < 16; ++d) {
        float x = c[d] * w;
#pragma unroll
        for (int o = 1; o < 64; o <<= 1) x += __shfl_xor(x, o);
        cg[d] = x;
    }
    if (t == 0) {
#pragma unroll
        for (int d = 0; d < 16; ++d) ctx[b * 64 + hd * 16 + d] = cg[d] / sw;
    }
}

// ---------------- g = LN(a + ctx@wo + bo); wcomb = g/8 + policy_w ----------------
__global__ __launch_bounds__(64) void k_g(const float* __restrict__ a,
                                          const float* __restrict__ ctx,
                                          const float* __restrict__ wo,
                                          const float* __restrict__ bo,
                                          const float* __restrict__ lng,
                                          const float* __restrict__ lnb,
                                          const float* __restrict__ pw,
                                          float* __restrict__ wcomb) {
    int b = blockIdx.x, t = threadIdx.x;
    __shared__ float sc[64];
    sc[t] = ctx[b * 64 + t];
    __syncthreads();
    float o = bo[t];
    for (int i = 0; i < 64; ++i) o = fmaf(sc[i], wo[i * 64 + t], o);
    float y = a[b * 64 + t] + o;
    float mu = y;
#pragma unroll
    for (int oo = 1; oo < 64; oo <<= 1) mu += __shfl_xor(mu, oo);
    mu *= (1.f / 64.f);
    float d = y - mu;
    float var = d * d;
#pragma unroll
    for (int oo = 1; oo < 64; oo <<= 1) var += __shfl_xor(var, oo);
    var *= (1.f / 64.f);
    float g = d * rsqrtf(var + 1e-5f) * lng[t] + lnb[t];
    wcomb[b * 64 + t] = g * 0.125f + pw[t];
}

// ---------------- logits (bf16 h) ----------------
__global__ __launch_bounds__(256) void k_final(const unsigned short* __restrict__ hb16,
                                               const float* __restrict__ wcomb,
                                               const float* __restrict__ pb,
                                               const void* __restrict__ mask,
                                               const int* __restrict__ flagp,
                                               float* __restrict__ out) {
    int idx = blockIdx.x * 256 + threadIdx.x;
    if (idx >= B_ * N_) return;
    int b = idx / N_;
    const float* wr = wcomb + b * 64;
    const short8* hr = (const short8*)(hb16 + (size_t)idx * 64);
    float acc = pb[0];
#pragma unroll
    for (int i = 0; i < 8; ++i) {
        short8 hv = hr[i];
#pragma unroll
        for (int j = 0; j < 8; ++j)
            acc = fmaf(bf2f((unsigned short)hv[j]), wr[i * 8 + j], acc);
    }
    int flag = *flagp;
    bool mv;
    if (flag == 1)      mv = ((const int*)mask)[idx] != 0;
    else if (flag == 2) mv = ((const float*)mask)[idx] != 0.f;
    else                mv = ((const unsigned char*)mask)[idx] != 0;
    out[idx] = mv ? acc : -1.0e9f;
}

extern "C" void kernel_launch(void* const* d_in, const int* in_sizes, int n_in,
                              void* d_out, int out_size, void* d_ws, size_t ws_size,
                              hipStream_t stream) {
    const float* gn   = (const float*)d_in[0];
    const float* ad   = (const float*)d_in[1];
    const float* wnod = (const float*)d_in[2];
    const float* bnod = (const float*)d_in[3];
    const float* msgw = (const float*)d_in[4];
    const float* msgb = (const float*)d_in[5];
    const float* updw = (const float*)d_in[6];
    const float* updb = (const float*)d_in[7];
    const float* wad  = (const float*)d_in[8];
    const float* bad  = (const float*)d_in[9];
    const float* wq   = (const float*)d_in[10];
    const float* bq   = (const float*)d_in[11];
    const float* wk   = (const float*)d_in[12];
    const float* bk   = (const float*)d_in[13];
    const float* wv   = (const float*)d_in[14];
    const float* bv   = (const float*)d_in[15];
    const float* wo   = (const float*)d_in[16];
    const float* bo   = (const float*)d_in[17];
    const float* lng  = (const float*)d_in[18];
    const float* lnb  = (const float*)d_in[19];
    const float* pw   = (const float*)d_in[20];
    const float* pb   = (const float*)d_in[21];
    const int*   links= (const int*)d_in[22];
    const void*  mask = d_in[23];

    char* ws = (char*)d_ws;
    unsigned short* tdb  = (unsigned short*)(ws + OFF_TDB);
    unsigned short* kb16 = (unsigned short*)(ws + OFF_TDB);
    float* agg  = (float*)(ws + OFF_AGG);
    unsigned* ebuck = (unsigned*)(ws + OFF_EBUCK);
    unsigned* epair = (unsigned*)(ws + OFF_EPAIR);
    unsigned short* hb16 = (unsigned short*)(ws + OFF_HB16);
    float* avec = (float*)(ws + OFF_AVEC);
    float* qvec = (float*)(ws + OFF_Q);
    float* ctx  = (float*)(ws + OFF_CTX);
    float* wcmb = (float*)(ws + OFF_WCMB);
    int*   flag = (int*)(ws + OFF_FLAG);
    float* part = (float*)(ws + OFF_PART);
    int*   tails= (int*)(ws + OFF_TAILS);
    int*   wbase= (int*)(ws + OFF_WBASE);
    unsigned short* vb16 = (unsigned short*)(ws + OFF_VB16);
    float* out  = (float*)d_out;

    hipMemsetAsync(tails, 0, (size_t)B_ * NWIN * TPAD * 4, stream);
    k_maskdetect<<<1, 1, 0, stream>>>((const unsigned int*)mask, flag);
    k_embed_bucket<<<6248, 256, 0, stream>>>(gn, wnod, bnod, hb16, links, tails, ebuck);
    k_scan_tails<<<B_, 1024, 0, stream>>>(tails, wbase);
    k_sortwin<<<5000, 256, 0, stream>>>(ebuck, tails, wbase, epair);

    // layer 0 (tdst also zeroes agg)
    k_tdst_mfma<<<512, 256, 0, stream>>>(hb16, msgw, msgb, tdb, agg);
    k_edge_mfma<<<5000, 256, 0, stream>>>(hb16, tdb, epair, msgw, agg);
    k_upd_tdst_mfma<<<512, 256, 0, stream>>>(hb16, agg, updw, updb,
                                             msgw + (size_t)128 * 64, msgb + 64, tdb);
    // layer 1 (upd_tdst re-zeroed agg)
    k_edge_mfma<<<5000, 256, 0, stream>>>(hb16, tdb, epair, msgw + (size_t)128 * 64, agg);
    k_upd_kv_mfma<<<512, 256, 0, stream>>>(hb16, agg, updw + (size_t)128 * 64, updb + 64,
                                           wk, bk, wv, bv, kb16, vb16);

    k_aq<<<B_, 64, 0, stream>>>(ad, wad, bad, wq, bq, avec, qvec);
    k_attn<<<B_ * HEADS_ * NCH, 256, 0, stream>>>(qvec, kb16, vb16, part);
    k_comb<<<B_ * HEADS_, 64, 0, stream>>>(part, ctx);
    k_g<<<B_, 64, 0, stream>>>(avec, ctx, wo, bo, lng, lnb, pw, wcmb);
    k_final<<<(B_ * N_ + 255) / 256, 256, 0, stream>>>(hb16, wcmb, pb, mask, flag, out);
}

// Round 19
// 241.562 us; speedup vs baseline: 1.2907x; 1.0538x over previous
//
#include <hip/hip_runtime.h>
#include <hip/hip_bf16.h>
#include <math.h>

// Problem constants
constexpr int B_ = 4;
constexpr int N_ = 20000;
constexpr int E_ = 320000;
constexpr int HEADS_ = 4;
constexpr int NCH = 64;                       // attention chunks per (b,head)
constexpr int CS = (N_ + NCH - 1) / NCH;      // 313
constexpr int NT_ = (B_ * N_) / 16;           // 5000 node tiles
constexpr int NWIN = 1250;                    // 16-dst windows per batch
constexpr int HWIN = 625;                     // windows per XCD half
constexpr int WCAP = 512;                     // bucket capacity (mean 256, +16 sigma)
constexpr int TPAD = 16;                      // tails padding -> 1 counter/line

typedef __attribute__((ext_vector_type(8))) short short8;   // 8 bf16
typedef __attribute__((ext_vector_type(4))) float f32x4;

// Workspace layout (bytes). ~67 MB.
constexpr size_t SZ_TDB   = (size_t)B_ * N_ * 64 * 2;     // 10,240,000
constexpr size_t SZ_AGG   = (size_t)B_ * N_ * 64 * 4;     // 20,480,000
constexpr size_t SZ_EBUCK = (size_t)B_ * NWIN * WCAP * 4; // 10,240,000 (packed int)
constexpr size_t SZ_EPAIR = (size_t)B_ * E_ * 4;          // 5,120,000 (packed int)
constexpr size_t OFF_TDB  = 0;                            // tdb bf16 (transposed); later kb16
constexpr size_t OFF_AGG  = SZ_TDB;                       // agg f32
constexpr size_t OFF_EBUCK= OFF_AGG + SZ_AGG;
constexpr size_t OFF_EPAIR= OFF_EBUCK + SZ_EBUCK;
constexpr size_t OFF_HB16 = OFF_EPAIR + SZ_EPAIR;
constexpr size_t OFF_AVEC = OFF_HB16 + SZ_TDB;
constexpr size_t OFF_Q    = OFF_AVEC + 1024;
constexpr size_t OFF_CTX  = OFF_Q + 1024;
constexpr size_t OFF_WCMB = OFF_CTX + 1024;
constexpr size_t OFF_FLAG = OFF_WCMB + 1024;
constexpr size_t OFF_PART = OFF_FLAG + 64;                // 1024*18 f partials
constexpr size_t OFF_TAILS= OFF_PART + 1024 * 18 * 4 + 64;   // B*NWIN*TPAD ints
constexpr size_t OFF_WBASE= OFF_TAILS + (size_t)B_ * NWIN * TPAD * 4; // B*NWIN ints
constexpr size_t OFF_VB16 = OFF_WBASE + (size_t)B_ * NWIN * 4 + 64;   // v bf16 (own region)

static __device__ __forceinline__ unsigned short f2bf(float f) {
    union { float f; unsigned u; } v; v.f = f;
    unsigned r = v.u + 0x7fffu + ((v.u >> 16) & 1u);
    return (unsigned short)(r >> 16);
}
static __device__ __forceinline__ float bf2f(unsigned short u) {
    union { unsigned u; float f; } v; v.u = (unsigned)u << 16;
    return v.f;
}

// ---------------- mask dtype detection ----------------
__global__ void k_maskdetect(const unsigned int* __restrict__ m, int* __restrict__ flag) {
    if (blockIdx.x == 0 && threadIdx.x == 0) {
        bool alli = true, allf = true;
        for (int i = 0; i < 256; ++i) {
            unsigned v = m[i];
            alli = alli && (v <= 1u);
            allf = allf && (v == 0u || v == 0x3f800000u);
        }
        *flag = alli ? 1 : (allf ? 2 : 0);
    }
}

// ---------------- fused: embed (1/5 of groups) + XCD-partitioned bucket build ----------------
__global__ __launch_bounds__(256) void k_embed_bucket(const float* __restrict__ gn,
                                                      const float* __restrict__ wnod,
                                                      const float* __restrict__ bias,
                                                      unsigned short* __restrict__ hb16,
                                                      const int* __restrict__ links,
                                                      int* __restrict__ tails,
                                                      unsigned* __restrict__ ebuck) {
    int i = blockIdx.x;
    int g = i >> 3, r = i & 7;
    if (g % 5 == 4) {
        int eb = (g / 5) * 8 + r;             // 0..1247
        int lane = threadIdx.x & 63;
        float wc[16];
#pragma unroll
        for (int k = 0; k < 16; ++k) wc[k] = wnod[k * 64 + lane];
        float bb = bias[lane];
        int gw = eb * 4 + (threadIdx.x >> 6);
        for (int node = gw; node < B_ * N_; node += 1248 * 4) {
            const float* rr = gn + (size_t)node * 16;
            float a0 = 0.f, a1 = 0.f, a2 = 0.f, a3 = 0.f;
#pragma unroll
            for (int k = 0; k < 16; k += 4) {
                a0 = fmaf(rr[k + 0], wc[k + 0], a0);
                a1 = fmaf(rr[k + 1], wc[k + 1], a1);
                a2 = fmaf(rr[k + 2], wc[k + 2], a2);
                a3 = fmaf(rr[k + 3], wc[k + 3], a3);
            }
            float v = fmaxf(bb + ((a0 + a1) + (a2 + a3)), 0.f);
            hb16[(size_t)node * 64 + lane] = f2bf(v);
        }
    } else {
        int og = g - (g + 1) / 5;             // 0..624
        int b = r >> 1;
        int half = r & 1;
        int e0 = og * 512 + threadIdx.x;
        const int* lsrc = links + (size_t)b * 2 * E_;
#pragma unroll
        for (int ch = 0; ch < 2; ++ch) {
            int e = e0 + ch * 256;
            unsigned src = (unsigned)lsrc[e];
            unsigned dst = (unsigned)lsrc[E_ + e];
            int w = dst >> 4;                 // 0..1249
            if ((w >= HWIN) == (half == 1)) {
                int slot = atomicAdd(&tails[(b * NWIN + w) * TPAD], 1);
                if (slot < WCAP)
                    ebuck[(size_t)(b * NWIN + w) * WCAP + slot] = (dst << 16) | src;
            }
        }
    }
}

// ---------------- exclusive scan of (padded) window tails -> epair bases ----------------
__global__ __launch_bounds__(1024) void k_scan_tails(const int* __restrict__ tails,
                                                     int* __restrict__ wbase) {
    __shared__ int wsum[16];
    __shared__ int sbase;
    int b = blockIdx.x, t = threadIdx.x;
    int lane = t & 63, wv = t >> 6;
    if (t == 0) sbase = 0;
    __syncthreads();
    for (int base = 0; base < NWIN; base += 1024) {
        int idx = base + t;
        int c = 0;
        if (idx < NWIN) { c = tails[(b * NWIN + idx) * TPAD]; if (c > WCAP) c = WCAP; }
        int x = c;
#pragma unroll
        for (int o = 1; o < 64; o <<= 1) {
            int y = __shfl_up(x, o);
            if (lane >= o) x += y;
        }
        if (lane == 63) wsum[wv] = x;
        __syncthreads();
        if (wv == 0) {
            int s = (lane < 16) ? wsum[lane] : 0;
#pragma unroll
            for (int o = 1; o < 16; o <<= 1) {
                int y = __shfl_up(s, o);
                if (lane >= o) s += y;
            }
            if (lane < 16) wsum[lane] = s;
        }
        __syncthreads();
        int wpre = (wv > 0) ? wsum[wv - 1] : 0;
        int incl = x + wpre + sbase;
        if (idx < NWIN) wbase[b * NWIN + idx] = incl - c;   // exclusive
        __syncthreads();
        if (t == 1023) sbase = incl;
        __syncthreads();
    }
}

// ---------------- per-window 16-bin counting sort (LDS) -> sorted packed epair ----------------
__global__ __launch_bounds__(256) void k_sortwin(const unsigned* __restrict__ ebuck,
                                                 const int* __restrict__ tails,
                                                 const int* __restrict__ wbase,
                                                 unsigned* __restrict__ epair) {
    __shared__ int hist[16], hbase[16];
    __shared__ unsigned sbuf[WCAP];
    int i = blockIdx.x;                   // 0..4999
    int r = i & 7;
    int b = r >> 1;
    int w = (i >> 3) + HWIN * (r & 1);    // XCD-matched
    int cntw = tails[(b * NWIN + w) * TPAD];
    if (cntw > WCAP) cntw = WCAP;
    if (threadIdx.x < 16) hist[threadIdx.x] = 0;
    __syncthreads();
    const unsigned* src = ebuck + (size_t)(b * NWIN + w) * WCAP;
    int idx0 = threadIdx.x, idx1 = threadIdx.x + 256;
    bool v0 = idx0 < cntw, v1 = idx1 < cntw;
    unsigned e0 = 0, e1 = 0;
    if (v0) { e0 = src[idx0]; atomicAdd(&hist[(e0 >> 16) & 15], 1); }
    if (v1) { e1 = src[idx1]; atomicAdd(&hist[(e1 >> 16) & 15], 1); }
    __syncthreads();
    if (threadIdx.x == 0) {
        int run = 0;
#pragma unroll
        for (int p = 0; p < 16; ++p) { hbase[p] = run; run += hist[p]; }
    }
    __syncthreads();
    if (threadIdx.x < 16) hist[threadIdx.x] = 0;
    __syncthreads();
    if (v0) { int bn = (e0 >> 16) & 15; sbuf[hbase[bn] + atomicAdd(&hist[bn], 1)] = e0; }
    if (v1) { int bn = (e1 >> 16) & 15; sbuf[hbase[bn] + atomicAdd(&hist[bn], 1)] = e1; }
    __syncthreads();
    int gb = wbase[b * NWIN + w];
    unsigned* dst = epair + (size_t)b * E_ + gb;
    for (int idx = threadIdx.x; idx < cntw; idx += 256) dst[idx] = sbuf[idx];
}

// ---------------- tdst (transposed) = W2^T h + msg_b, layer 0; zeroes agg ----------------
__global__ __launch_bounds__(256) void k_tdst_mfma(const unsigned short* __restrict__ hb16,
                                                   const float* __restrict__ mw,
                                                   const float* __restrict__ mb,
                                                   unsigned short* __restrict__ tdb,
                                                   float* __restrict__ agg) {
    int lane = threadIdx.x & 63;
    int g = lane >> 4, c = lane & 15;
    short8 bf[4][2];
#pragma unroll
    for (int nt = 0; nt < 4; ++nt)
#pragma unroll
        for (int ks = 0; ks < 2; ++ks)
#pragma unroll
            for (int j = 0; j < 8; ++j)
                bf[nt][ks][j] = (short)f2bf(mw[(64 + ks * 32 + g * 8 + j) * 64 + nt * 16 + c]);
    float mbv[4];
#pragma unroll
    for (int nt = 0; nt < 4; ++nt) mbv[nt] = mb[nt * 16 + c];

    int wid = blockIdx.x * 4 + (threadIdx.x >> 6);
    int nw = gridDim.x * 4;
    f32x4 zero = {0.f, 0.f, 0.f, 0.f};
    for (int t = wid; t < NT_; t += nw) {
        const unsigned short* ap = hb16 + ((size_t)t * 16 + c) * 64;
        short8 a0 = *(const short8*)(ap + g * 8);
        short8 a1 = *(const short8*)(ap + 32 + g * 8);
        f32x4 acc[4];
#pragma unroll
        for (int nt = 0; nt < 4; ++nt) {
            acc[nt] = __builtin_amdgcn_mfma_f32_16x16x32_bf16(a0, bf[nt][0], zero, 0, 0, 0);
            acc[nt] = __builtin_amdgcn_mfma_f32_16x16x32_bf16(a1, bf[nt][1], acc[nt], 0, 0, 0);
        }
#pragma unroll
        for (int r = 0; r < 4; ++r) {
            size_t row = (size_t)t * 16 + 4 * g + r;
            unsigned long long pk =
                (unsigned long long)f2bf(acc[0][r] + mbv[0])
              | ((unsigned long long)f2bf(acc[1][r] + mbv[1]) << 16)
              | ((unsigned long long)f2bf(acc[2][r] + mbv[2]) << 32)
              | ((unsigned long long)f2bf(acc[3][r] + mbv[3]) << 48);
            *(unsigned long long*)(tdb + row * 64 + c * 4) = pk;
            *(f32x4*)(agg + row * 64 + c * 4) = zero;     // agg zeroing folded in
        }
    }
}

// ---------------- fused MFMA edge kernel: 4x16-edge tiles, td-as-C-init ----------------
__global__ __launch_bounds__(256) void k_edge_mfma(const unsigned short* __restrict__ hb16,
                                                   const unsigned short* __restrict__ tdb,
                                                   const unsigned* __restrict__ epair,
                                                   const float* __restrict__ mw,
                                                   float* __restrict__ agg) {
    int lane = threadIdx.x & 63;
    int g = lane >> 4, c = lane & 15;
    short8 bf[4][2];
#pragma unroll
    for (int nt = 0; nt < 4; ++nt)
#pragma unroll
        for (int ks = 0; ks < 2; ++ks)
#pragma unroll
            for (int j = 0; j < 8; ++j)
                bf[nt][ks][j] = (short)f2bf(mw[(ks * 32 + g * 8 + j) * 64 + nt * 16 + c]);

    int i = blockIdx.x;                       // 0..4999
    int b = (i & 7) >> 1;                     // batch (XCD-pinned pair)
    int o = ((i >> 3) << 1) | (i & 1);        // per-batch block ordinal 0..1249
    int w = threadIdx.x >> 6;
    const unsigned* pp = epair + (size_t)b * E_;
    const unsigned short* hbase = hb16 + (size_t)(b * N_) * 64;
    const unsigned short* tbase = tdb + (size_t)(b * N_) * 64;
    float* abase = agg + (size_t)(b * N_) * 64;

    bool hi1 = (lane & 32) != 0;
    bool hi0 = (lane & 16) != 0;

    unsigned pr[4];
#pragma unroll
    for (int k = 0; k < 4; ++k) {
        int t0 = (o * 4 + w) + k * 5000;
        pr[k] = pp[t0 * 16 + c];
    }
    short8 a0[4], a1[4];
#pragma unroll
    for (int k = 0; k < 4; ++k) {
        const unsigned short* hrow = hbase + (size_t)(pr[k] & 0xFFFFu) * 64;
        a0[k] = *(const short8*)(hrow + g * 8);
        a1[k] = *(const short8*)(hrow + 32 + g * 8);
    }

#pragma unroll
    for (int k = 0; k < 4; ++k) {
        int dval = (int)(pr[k] >> 16);

        // td rows as MFMA C-init (transposed tdb: one 8B load per row)
        unsigned long long tv[4];
#pragma unroll
        for (int r = 0; r < 4; ++r) {
            int dr = __shfl(dval, 4 * g + r);
            tv[r] = *(const unsigned long long*)(tbase + (size_t)dr * 64 + c * 4);
        }
        f32x4 acc[4];
#pragma unroll
        for (int nt = 0; nt < 4; ++nt)
#pragma unroll
            for (int r = 0; r < 4; ++r)
                acc[nt][r] = bf2f((unsigned short)((tv[r] >> (16 * nt)) & 0xFFFFu));
#pragma unroll
        for (int nt = 0; nt < 4; ++nt) {
            acc[nt] = __builtin_amdgcn_mfma_f32_16x16x32_bf16(a0[k], bf[nt][0], acc[nt], 0, 0, 0);
            acc[nt] = __builtin_amdgcn_mfma_f32_16x16x32_bf16(a1[k], bf[nt][1], acc[nt], 0, 0, 0);
        }
        float val[4][4];
#pragma unroll
        for (int nt = 0; nt < 4; ++nt)
#pragma unroll
            for (int r = 0; r < 4; ++r)
                val[nt][r] = fmaxf(acc[nt][r], 0.f);

        int prev = __shfl(dval, (lane + 63) & 63);
        bool head = (c == 0) || (dval != prev);
        unsigned long long bal = __ballot(head);
        unsigned m16 = (unsigned)(bal & 0xFFFFu);

        while (m16) {
            int ii = __ffs(m16) - 1;
            unsigned rest = m16 & (m16 - 1);
            int jj = rest ? (__ffs(rest) - 1) : 16;
            m16 = rest;
            int d = __shfl(dval, ii);

            float v0 = 0.f, v1 = 0.f, v2 = 0.f, v3 = 0.f;
#pragma unroll
            for (int r = 0; r < 4; ++r) {
                int rr = 4 * g + r;
                bool in = (rr >= ii) && (rr < jj);
                v0 += in ? val[0][r] : 0.f;
                v1 += in ? val[1][r] : 0.f;
                v2 += in ? val[2][r] : 0.f;
                v3 += in ? val[3][r] : 0.f;
            }
            float sA0 = hi1 ? v0 : v2;
            float sA1 = hi1 ? v1 : v3;
            float rA0 = __shfl_xor(sA0, 32);
            float rA1 = __shfl_xor(sA1, 32);
            float w0 = (hi1 ? v2 : v0) + rA0;
            float w1 = (hi1 ? v3 : v1) + rA1;
            float sB = hi0 ? w0 : w1;
            float rB = __shfl_xor(sB, 16);
            float outv = (hi0 ? w1 : w0) + rB;

            atomicAdd(&abase[(size_t)d * 64 + lane], outv);
        }
    }
}

// ---------------- fused: upd (layer 0) + tdst for layer 1; re-zeroes agg ----------------
__global__ __launch_bounds__(256) void k_upd_tdst_mfma(unsigned short* __restrict__ hb16,
                                                       float* __restrict__ agg,
                                                       const float* __restrict__ uw,
                                                       const float* __restrict__ ub,
                                                       const float* __restrict__ mw2,
                                                       const float* __restrict__ mb2,
                                                       unsigned short* __restrict__ tdb) {
    __shared__ unsigned short stile[4][1024];
    int lane = threadIdx.x & 63;
    int g = lane >> 4, c = lane & 15;
    int wv = threadIdx.x >> 6;
    short8 bh[4][2], ba[4][2], bt[4][2];
#pragma unroll
    for (int nt = 0; nt < 4; ++nt)
#pragma unroll
        for (int ks = 0; ks < 2; ++ks)
#pragma unroll
            for (int j = 0; j < 8; ++j) {
                bh[nt][ks][j] = (short)f2bf(uw[(ks * 32 + g * 8 + j) * 64 + nt * 16 + c]);
                ba[nt][ks][j] = (short)f2bf(uw[(64 + ks * 32 + g * 8 + j) * 64 + nt * 16 + c]);
                bt[nt][ks][j] = (short)f2bf(mw2[(64 + ks * 32 + g * 8 + j) * 64 + nt * 16 + c]);
            }
    float ubv[4], mbv[4];
#pragma unroll
    for (int nt = 0; nt < 4; ++nt) { ubv[nt] = ub[nt * 16 + c]; mbv[nt] = mb2[nt * 16 + c]; }

    int wid = blockIdx.x * 4 + wv;
    int nw = gridDim.x * 4;
    f32x4 zero = {0.f, 0.f, 0.f, 0.f};
    int xr = (c & 7) << 3;
    for (int t = wid; t < NT_; t += nw) {
        unsigned short* ap = hb16 + ((size_t)t * 16 + c) * 64;
        short8 a0 = *(const short8*)(ap + g * 8);
        short8 a1 = *(const short8*)(ap + 32 + g * 8);

        float* gp = agg + ((size_t)t * 16 + c) * 64;
        float4 q0 = *(const float4*)(gp + g * 8);
        float4 q1 = *(const float4*)(gp + g * 8 + 4);
        float4 q2 = *(const float4*)(gp + 32 + g * 8);
        float4 q3 = *(const float4*)(gp + 32 + g * 8 + 4);
        // re-zero agg in place for layer 1 (stream-ordered before next edge pass)
        *(f32x4*)(gp + g * 8) = zero;
        *(f32x4*)(gp + g * 8 + 4) = zero;
        *(f32x4*)(gp + 32 + g * 8) = zero;
        *(f32x4*)(gp + 32 + g * 8 + 4) = zero;
        short8 s0, s1;
        s0[0] = (short)f2bf(q0.x); s0[1] = (short)f2bf(q0.y);
        s0[2] = (short)f2bf(q0.z); s0[3] = (short)f2bf(q0.w);
        s0[4] = (short)f2bf(q1.x); s0[5] = (short)f2bf(q1.y);
        s0[6] = (short)f2bf(q1.z); s0[7] = (short)f2bf(q1.w);
        s1[0] = (short)f2bf(q2.x); s1[1] = (short)f2bf(q2.y);
        s1[2] = (short)f2bf(q2.z); s1[3] = (short)f2bf(q2.w);
        s1[4] = (short)f2bf(q3.x); s1[5] = (short)f2bf(q3.y);
        s1[6] = (short)f2bf(q3.z); s1[7] = (short)f2bf(q3.w);

        f32x4 acc[4];
#pragma unroll
        for (int nt = 0; nt < 4; ++nt) {
            acc[nt] = __builtin_amdgcn_mfma_f32_16x16x32_bf16(a0, bh[nt][0], zero, 0, 0, 0);
            acc[nt] = __builtin_amdgcn_mfma_f32_16x16x32_bf16(a1, bh[nt][1], acc[nt], 0, 0, 0);
            acc[nt] = __builtin_amdgcn_mfma_f32_16x16x32_bf16(s0, ba[nt][0], acc[nt], 0, 0, 0);
            acc[nt] = __builtin_amdgcn_mfma_f32_16x16x32_bf16(s1, ba[nt][1], acc[nt], 0, 0, 0);
        }
#pragma unroll
        for (int r = 0; r < 4; ++r) {
            size_t row = (size_t)t * 16 + 4 * g + r;
            int lrow = 4 * g + r;
#pragma unroll
            for (int nt = 0; nt < 4; ++nt) {
                size_t idx = row * 64 + nt * 16 + c;
                float v = bf2f(hb16[idx]) + fmaxf(acc[nt][r] + ubv[nt], 0.f);
                unsigned short vb = f2bf(v);
                hb16[idx] = vb;
                int col = nt * 16 + c;
                stile[wv][lrow * 64 + (col ^ ((lrow & 7) << 3))] = vb;
            }
        }
        // wave-private LDS round-trip: read A-frags of h_new
        short8 na0 = *(const short8*)&stile[wv][c * 64 + ((g * 8) ^ xr)];
        short8 na1 = *(const short8*)&stile[wv][c * 64 + ((32 + g * 8) ^ xr)];
        f32x4 tacc[4];
#pragma unroll
        for (int nt = 0; nt < 4; ++nt) {
            tacc[nt] = __builtin_amdgcn_mfma_f32_16x16x32_bf16(na0, bt[nt][0], zero, 0, 0, 0);
            tacc[nt] = __builtin_amdgcn_mfma_f32_16x16x32_bf16(na1, bt[nt][1], tacc[nt], 0, 0, 0);
        }
#pragma unroll
        for (int r = 0; r < 4; ++r) {
            size_t row = (size_t)t * 16 + 4 * g + r;
            unsigned long long pk =
                (unsigned long long)f2bf(tacc[0][r] + mbv[0])
              | ((unsigned long long)f2bf(tacc[1][r] + mbv[1]) << 16)
              | ((unsigned long long)f2bf(tacc[2][r] + mbv[2]) << 32)
              | ((unsigned long long)f2bf(tacc[3][r] + mbv[3]) << 48);
            *(unsigned long long*)(tdb + row * 64 + c * 4) = pk;
        }
    }
}

// ---------------- fused: upd (layer 1) + k/v projections ----------------
__global__ __launch_bounds__(256) void k_upd_kv_mfma(unsigned short* __restrict__ hb16,
                                                     const float* __restrict__ agg,
                                                     const float* __restrict__ uw,
                                                     const float* __restrict__ ub,
                                                     const float* __restrict__ wk,
                                                     const float* __restrict__ bk,
                                                     const float* __restrict__ wv,
                                                     const float* __restrict__ bv,
                                                     unsigned short* __restrict__ kb16,
                                                     unsigned short* __restrict__ vb16) {
    __shared__ unsigned short stile[4][1024];
    int lane = threadIdx.x & 63;
    int g = lane >> 4, c = lane & 15;
    int wvv = threadIdx.x >> 6;
    short8 bh[4][2], ba[4][2], bkf[4][2], bvf[4][2];
#pragma unroll
    for (int nt = 0; nt < 4; ++nt)
#pragma unroll
        for (int ks = 0; ks < 2; ++ks)
#pragma unroll
            for (int j = 0; j < 8; ++j) {
                bh[nt][ks][j]  = (short)f2bf(uw[(ks * 32 + g * 8 + j) * 64 + nt * 16 + c]);
                ba[nt][ks][j]  = (short)f2bf(uw[(64 + ks * 32 + g * 8 + j) * 64 + nt * 16 + c]);
                bkf[nt][ks][j] = (short)f2bf(wk[(ks * 32 + g * 8 + j) * 64 + nt * 16 + c]);
                bvf[nt][ks][j] = (short)f2bf(wv[(ks * 32 + g * 8 + j) * 64 + nt * 16 + c]);
            }
    float ubv[4], bkv[4], bvv[4];
#pragma unroll
    for (int nt = 0; nt < 4; ++nt) {
        ubv[nt] = ub[nt * 16 + c];
        bkv[nt] = bk[nt * 16 + c];
        bvv[nt] = bv[nt * 16 + c];
    }

    int wid = blockIdx.x * 4 + wvv;
    int nw = gridDim.x * 4;
    f32x4 zero = {0.f, 0.f, 0.f, 0.f};
    int xr = (c & 7) << 3;
    for (int t = wid; t < NT_; t += nw) {
        unsigned short* ap = hb16 + ((size_t)t * 16 + c) * 64;
        short8 a0 = *(const short8*)(ap + g * 8);
        short8 a1 = *(const short8*)(ap + 32 + g * 8);

        const float* gp = agg + ((size_t)t * 16 + c) * 64;
        float4 q0 = *(const float4*)(gp + g * 8);
        float4 q1 = *(const float4*)(gp + g * 8 + 4);
        float4 q2 = *(const float4*)(gp + 32 + g * 8);
        float4 q3 = *(const float4*)(gp + 32 + g * 8 + 4);
        short8 s0, s1;
        s0[0] = (short)f2bf(q0.x); s0[1] = (short)f2bf(q0.y);
        s0[2] = (short)f2bf(q0.z); s0[3] = (short)f2bf(q0.w);
        s0[4] = (short)f2bf(q1.x); s0[5] = (short)f2bf(q1.y);
        s0[6] = (short)f2bf(q1.z); s0[7] = (short)f2bf(q1.w);
        s1[0] = (short)f2bf(q2.x); s1[1] = (short)f2bf(q2.y);
        s1[2] = (short)f2bf(q2.z); s1[3] = (short)f2bf(q2.w);
        s1[4] = (short)f2bf(q3.x); s1[5] = (short)f2bf(q3.y);
        s1[6] = (short)f2bf(q3.z); s1[7] = (short)f2bf(q3.w);

        f32x4 acc[4];
#pragma unroll
        for (int nt = 0; nt < 4; ++nt) {
            acc[nt] = __builtin_amdgcn_mfma_f32_16x16x32_bf16(a0, bh[nt][0], zero, 0, 0, 0);
            acc[nt] = __builtin_amdgcn_mfma_f32_16x16x32_bf16(a1, bh[nt][1], acc[nt], 0, 0, 0);
            acc[nt] = __builtin_amdgcn_mfma_f32_16x16x32_bf16(s0, ba[nt][0], acc[nt], 0, 0, 0);
            acc[nt] = __builtin_amdgcn_mfma_f32_16x16x32_bf16(s1, ba[nt][1], acc[nt], 0, 0, 0);
        }
#pragma unroll
        for (int r = 0; r < 4; ++r) {
            size_t row = (size_t)t * 16 + 4 * g + r;
            int lrow = 4 * g + r;
#pragma unroll
            for (int nt = 0; nt < 4; ++nt) {
                size_t idx = row * 64 + nt * 16 + c;
                float v = bf2f(hb16[idx]) + fmaxf(acc[nt][r] + ubv[nt], 0.f);
                unsigned short vb = f2bf(v);
                hb16[idx] = vb;
                int col = nt * 16 + c;
                stile[wvv][lrow * 64 + (col ^ ((lrow & 7) << 3))] = vb;
            }
        }
        short8 na0 = *(const short8*)&stile[wvv][c * 64 + ((g * 8) ^ xr)];
        short8 na1 = *(const short8*)&stile[wvv][c * 64 + ((32 + g * 8) ^ xr)];
        f32x4 ak[4], av[4];
#pragma unroll
        for (int nt = 0; nt < 4; ++nt) {
            ak[nt] = __builtin_amdgcn_mfma_f32_16x16x32_bf16(na0, bkf[nt][0], zero, 0, 0, 0);
            ak[nt] = __builtin_amdgcn_mfma_f32_16x16x32_bf16(na1, bkf[nt][1], ak[nt], 0, 0, 0);
            av[nt] = __builtin_amdgcn_mfma_f32_16x16x32_bf16(na0, bvf[nt][0], zero, 0, 0, 0);
            av[nt] = __builtin_amdgcn_mfma_f32_16x16x32_bf16(na1, bvf[nt][1], av[nt], 0, 0, 0);
        }
#pragma unroll
        for (int r = 0; r < 4; ++r) {
            size_t row = (size_t)t * 16 + 4 * g + r;
#pragma unroll
            for (int nt = 0; nt < 4; ++nt) {
                kb16[row * 64 + nt * 16 + c] = f2bf(ak[nt][r] + bkv[nt]);
                vb16[row * 64 + nt * 16 + c] = f2bf(av[nt][r] + bvv[nt]);
            }
        }
    }
}

// ---------------- a = relu(ad @ w_ad + b_ad); q = a @ wq + bq ----------------
__global__ __launch_bounds__(64) void k_aq(const float* __restrict__ ad,
                                           const float* __restrict__ wad,
                                           const float* __restrict__ bad,
                                           const float* __restrict__ wq,
                                           const float* __restrict__ bq,
                                           float* __restrict__ a_out,
                                           float* __restrict__ q_out) {
    int b = blockIdx.x, t = threadIdx.x;
    __shared__ float sa[64];
    float acc = bad[t];
#pragma unroll
    for (int i = 0; i < 8; ++i) acc = fmaf(ad[b * 8 + i], wad[i * 64 + t], acc);
    float av = fmaxf(acc, 0.f);
    sa[t] = av;
    a_out[b * 64 + t] = av;
    __syncthreads();
    float qa = bq[t];
    for (int i = 0; i < 64; ++i) qa = fmaf(sa[i], wq[i * 64 + t], qa);
    q_out[b * 64 + t] = qa;
}

// ---------------- attention: chunked online softmax partials (bf16 k/v) ----------------
__global__ __launch_bounds__(256) void k_attn(const float* __restrict__ q,
                                              const unsigned short* __restrict__ kb16,
                                              const unsigned short* __restrict__ vb16,
                                              float* __restrict__ part) {
    int id = blockIdx.x;
    int ch = id % NCH;
    int bh = id / NCH;
    int b = bh / HEADS_, hd = bh % HEADS_;
    float qv[16];
#pragma unroll
    for (int d = 0; d < 16; ++d) qv[d] = q[b * 64 + hd * 16 + d];
    float m = -1e30f, s = 0.f, c[16];
#pragma unroll
    for (int d = 0; d < 16; ++d) c[d] = 0.f;
    int n0 = ch * CS;
    int n1 = n0 + CS; if (n1 > N_) n1 = N_;
    for (int n = n0 + threadIdx.x; n < n1; n += 256) {
        const short8* kr = (const short8*)(kb16 + ((size_t)b * N_ + n) * 64 + hd * 16);
        short8 k0 = kr[0], k1 = kr[1];
        float dot = 0.f;
#pragma unroll
        for (int d = 0; d < 8; ++d) {
            dot = fmaf(qv[d], bf2f((unsigned short)k0[d]), dot);
            dot = fmaf(qv[8 + d], bf2f((unsigned short)k1[d]), dot);
        }
        dot *= 0.25f;
        float nm = fmaxf(m, dot);
        float p = __expf(dot - nm);
        float cor = __expf(m - nm);
        const short8* vr = (const short8*)(vb16 + ((size_t)b * N_ + n) * 64 + hd * 16);
        short8 v0 = vr[0], v1 = vr[1];
        s = s * cor + p;
#pragma unroll
        for (int d = 0; d < 8; ++d) {
            c[d] = c[d] * cor + p * bf2f((unsigned short)v0[d]);
            c[8 + d] = c[8 + d] * cor + p * bf2f((unsigned short)v1[d]);
        }
        m = nm;
    }
#pragma unroll
    for (int o = 1; o < 64; o <<= 1) {
        float m2 = __shfl_xor(m, o);
        float s2 = __shfl_xor(s, o);
        float nm = fmaxf(m, m2);
        float w1 = __expf(m - nm), w2 = __expf(m2 - nm);
        s = s * w1 + s2 * w2;
#pragma unroll
        for (int d = 0; d < 16; ++d) {
            float c2 = __shfl_xor(c[d], o);
            c[d] = c[d] * w1 + c2 * w2;
        }
        m = nm;
    }
    __shared__ float red[4][18];
    int wv_ = threadIdx.x >> 6, lane = threadIdx.x & 63;
    if (lane == 0) {
        red[wv_][0] = m; red[wv_][1] = s;
#pragma unroll
        for (int d = 0; d < 16; ++d) red[wv_][2 + d] = c[d];
    }
    __syncthreads();
    if (threadIdx.x == 0) {
        float gm = red[0][0];
        for (int w = 1; w < 4; ++w) gm = fmaxf(gm, red[w][0]);
        float gs = 0.f, gc[16];
#pragma unroll
        for (int d = 0; d < 16; ++d) gc[d] = 0.f;
        for (int w = 0; w < 4; ++w) {
            float ww = __expf(red[w][0] - gm);
            gs += red[w][1] * ww;
#pragma unroll
            for (int d = 0; d < 16; ++d) gc[d] += red[w][2 + d] * ww;
        }
        float* p = part + (size_t)id * 18;
        p[0] = gm; p[1] = gs;
#pragma unroll
        for (int d = 0; d < 16; ++d) p[2 + d] = gc[d];
    }
}

__global__ __launch_bounds__(64) void k_comb(const float* __restrict__ part,
                                             float* __restrict__ ctx) {
    int bh = blockIdx.x, t = threadIdx.x;
    int b = bh / HEADS_, hd = bh % HEADS_;
    const float* p = part + ((size_t)bh * NCH + t) * 18;
    float m = p[0], s = p[1], c[16];
#pragma unroll
    for (int d = 0; d < 16; ++d) c[d] = p[2 + d];
    float gm = m;
#pragma unroll
    for (int o = 1; o < 64; o <<= 1) gm = fmaxf(gm, __shfl_xor(gm, o));
    float w = __expf(m - gm);
    float sw = s * w;
#pragma unroll
    for (int o = 1; o < 64; o <<= 1) sw += __shfl_xor(sw, o);
    float cg[16];
#pragma unroll
    for (int d = 0; d < 16; ++d) {
        float x = c[d] * w;
#pragma unroll
        for (int o = 1; o < 64; o <<= 1) x += __shfl_xor(x, o);
        cg[d] = x;
    }
    if (t == 0) {
#pragma unroll
        for (int d = 0; d < 16; ++d) ctx[b * 64 + hd * 16 + d] = cg[d] / sw;
    }
}

// ---------------- g = LN(a + ctx@wo + bo); wcomb = g/8 + policy_w ----------------
__global__ __launch_bounds__(64) void k_g(const float* __restrict__ a,
                                          const float* __restrict__ ctx,
                                          const float* __restrict__ wo,
                                          const float* __restrict__ bo,
                                          const float* __restrict__ lng,
                                          const float* __restrict__ lnb,
                                          const float* __restrict__ pw,
                                          float* __restrict__ wcomb) {
    int b = blockIdx.x, t = threadIdx.x;
    __shared__ float sc[64];
    sc[t] = ctx[b * 64 + t];
    __syncthreads();
    float o = bo[t];
    for (int i = 0; i < 64; ++i) o = fmaf(sc[i], wo[i * 64 + t], o);
    float y = a[b * 64 + t] + o;
    float mu = y;
#pragma unroll
    for (int oo = 1; oo < 64; oo <<= 1) mu += __shfl_xor(mu, oo);
    mu *= (1.f / 64.f);
    float d = y - mu;
    float var = d * d;
#pragma unroll
    for (int oo = 1; oo < 64; oo <<= 1) var += __shfl_xor(var, oo);
    var *= (1.f / 64.f);
    float g = d * rsqrtf(var + 1e-5f) * lng[t] + lnb[t];
    wcomb[b * 64 + t] = g * 0.125f + pw[t];
}

// ---------------- logits (bf16 h) ----------------
__global__ __launch_bounds__(256) void k_final(const unsigned short* __restrict__ hb16,
                                               const float* __restrict__ wcomb,
                                               const float* __restrict__ pb,
                                               const void* __restrict__ mask,
                                               const int* __restrict__ flagp,
                                               float* __restrict__ out) {
    int idx = blockIdx.x * 256 + threadIdx.x;
    if (idx >= B_ * N_) return;
    int b = idx / N_;
    const float* wr = wcomb + b * 64;
    const short8* hr = (const short8*)(hb16 + (size_t)idx * 64);
    float acc = pb[0];
#pragma unroll
    for (int i = 0; i < 8; ++i) {
        short8 hv = hr[i];
#pragma unroll
        for (int j = 0; j < 8; ++j)
            acc = fmaf(bf2f((unsigned short)hv[j]), wr[i * 8 + j], acc);
    }
    int flag = *flagp;
    bool mv;
    if (flag == 1)      mv = ((const int*)mask)[idx] != 0;
    else if (flag == 2) mv = ((const float*)mask)[idx] != 0.f;
    else                mv = ((const unsigned char*)mask)[idx] != 0;
    out[idx] = mv ? acc : -1.0e9f;
}

extern "C" void kernel_launch(void* const* d_in, const int* in_sizes, int n_in,
                              void* d_out, int out_size, void* d_ws, size_t ws_size,
                              hipStream_t stream) {
    const float* gn   = (const float*)d_in[0];
    const float* ad   = (const float*)d_in[1];
    const float* wnod = (const float*)d_in[2];
    const float* bnod = (const float*)d_in[3];
    const float* msgw = (const float*)d_in[4];
    const float* msgb = (const float*)d_in[5];
    const float* updw = (const float*)d_in[6];
    const float* updb = (const float*)d_in[7];
    const float* wad  = (const float*)d_in[8];
    const float* bad  = (const float*)d_in[9];
    const float* wq   = (const float*)d_in[10];
    const float* bq   = (const float*)d_in[11];
    const float* wk   = (const float*)d_in[12];
    const float* bk   = (const float*)d_in[13];
    const float* wv   = (const float*)d_in[14];
    const float* bv   = (const float*)d_in[15];
    const float* wo   = (const float*)d_in[16];
    const float* bo   = (const float*)d_in[17];
    const float* lng  = (const float*)d_in[18];
    const float* lnb  = (const float*)d_in[19];
    const float* pw   = (const float*)d_in[20];
    const float* pb   = (const float*)d_in[21];
    const int*   links= (const int*)d_in[22];
    const void*  mask = d_in[23];

    char* ws = (char*)d_ws;
    unsigned short* tdb  = (unsigned short*)(ws + OFF_TDB);
    unsigned short* kb16 = (unsigned short*)(ws + OFF_TDB);
    float* agg  = (float*)(ws + OFF_AGG);
    unsigned* ebuck = (unsigned*)(ws + OFF_EBUCK);
    unsigned* epair = (unsigned*)(ws + OFF_EPAIR);
    unsigned short* hb16 = (unsigned short*)(ws + OFF_HB16);
    float* avec = (float*)(ws + OFF_AVEC);
    float* qvec = (float*)(ws + OFF_Q);
    float* ctx  = (float*)(ws + OFF_CTX);
    float* wcmb = (float*)(ws + OFF_WCMB);
    int*   flag = (int*)(ws + OFF_FLAG);
    float* part = (float*)(ws + OFF_PART);
    int*   tails= (int*)(ws + OFF_TAILS);
    int*   wbase= (int*)(ws + OFF_WBASE);
    unsigned short* vb16 = (unsigned short*)(ws + OFF_VB16);
    float* out  = (float*)d_out;

    hipMemsetAsync(tails, 0, (size_t)B_ * NWIN * TPAD * 4, stream);
    k_maskdetect<<<1, 1, 0, stream>>>((const unsigned int*)mask, flag);
    k_embed_bucket<<<6248, 256, 0, stream>>>(gn, wnod, bnod, hb16, links, tails, ebuck);
    k_scan_tails<<<B_, 1024, 0, stream>>>(tails, wbase);
    k_sortwin<<<5000, 256, 0, stream>>>(ebuck, tails, wbase, epair);

    // layer 0 (tdst also zeroes agg)
    k_tdst_mfma<<<512, 256, 0, stream>>>(hb16, msgw, msgb, tdb, agg);
    k_edge_mfma<<<5000, 256, 0, stream>>>(hb16, tdb, epair, msgw, agg);
    k_upd_tdst_mfma<<<512, 256, 0, stream>>>(hb16, agg, updw, updb,
                                             msgw + (size_t)128 * 64, msgb + 64, tdb);
    // layer 1 (upd_tdst re-zeroed agg)
    k_edge_mfma<<<5000, 256, 0, stream>>>(hb16, tdb, epair, msgw + (size_t)128 * 64, agg);
    k_upd_kv_mfma<<<512, 256, 0, stream>>>(hb16, agg, updw + (size_t)128 * 64, updb + 64,
                                           wk, bk, wv, bv, kb16, vb16);

    k_aq<<<B_, 64, 0, stream>>>(ad, wad, bad, wq, bq, avec, qvec);
    k_attn<<<B_ * HEADS_ * NCH, 256, 0, stream>>>(qvec, kb16, vb16, part);
    k_comb<<<B_ * HEADS_, 64, 0, stream>>>(part, ctx);
    k_g<<<B_, 64, 0, stream>>>(avec, ctx, wo, bo, lng, lnb, pw, wcmb);
    k_final<<<(B_ * N_ + 255) / 256, 256, 0, stream>>>(hb16, wcmb, pb, mask, flag, out);
}